// Round 1
// baseline (740.529 us; speedup 1.0000x reference)
//
#include <hip/hip_runtime.h>
#include <hip/hip_bf16.h>
#include <math.h>

#define IN_DIM 256
#define HID 128
#define HEADS 2
#define EPS_BN 1e-5f

__device__ __forceinline__ float lrelu(float v) { return v > 0.f ? v : 0.2f * v; }

// ---------- edge-index dtype detection (int32 vs int64) ----------
__global__ void detect_kernel(const unsigned int* __restrict__ w, int* __restrict__ flag,
                              long long nwords) {
    __shared__ int nz;
    if (threadIdx.x == 0) nz = 0;
    __syncthreads();
    int cnt = 0;
    for (int i = 0; i < 4; i++) {
        long long idx = 2LL * (threadIdx.x + i * 256) + 1;  // odd 32-bit words
        if (idx < nwords && w[idx] != 0u) cnt++;
    }
    if (cnt) atomicAdd(&nz, 1);
    __syncthreads();
    if (threadIdx.x == 0) flag[0] = (nz == 0) ? 1 : 0;  // all-zero odd words -> int64
}

__device__ __forceinline__ int edge_at(const void* ei, int is64, long long i) {
    if (is64) return (int)((const long long*)ei)[i];
    return ((const int*)ei)[i];
}

// ---------- CSR build ----------
__global__ void count_deg_kernel(const void* __restrict__ ei, const int* __restrict__ flag,
                                 int* __restrict__ deg, int E_) {
    int is64 = flag[0];
    int i = blockIdx.x * 256 + threadIdx.x;
    if (i < E_) {
        int d = edge_at(ei, is64, (long long)E_ + i);
        atomicAdd(&deg[d], 1);
    }
}

__global__ __launch_bounds__(1024) void scan_kernel(const int* __restrict__ deg,
                                                    int* __restrict__ rowptr,
                                                    int* __restrict__ ctr, int n) {
    __shared__ int part[1024];
    int t = threadIdx.x;
    int chunk = (n + 1023) / 1024;
    int lo = t * chunk;
    int hi = lo + chunk; if (hi > n) hi = n;
    int s = 0;
    for (int i = lo; i < hi; i++) s += deg[i];
    part[t] = s;
    __syncthreads();
    for (int off = 1; off < 1024; off <<= 1) {
        int v = (t >= off) ? part[t - off] : 0;
        __syncthreads();
        part[t] += v;
        __syncthreads();
    }
    int base = (t == 0) ? 0 : part[t - 1];
    for (int i = lo; i < hi; i++) {
        rowptr[i] = base; ctr[i] = base;
        base += deg[i];
    }
    if (t == 1023) rowptr[n] = part[1023];
}

__global__ void scatter_kernel(const void* __restrict__ ei, const int* __restrict__ flag,
                               int* __restrict__ ctr, int* __restrict__ srcs, int E_) {
    int is64 = flag[0];
    int i = blockIdx.x * 256 + threadIdx.x;
    if (i < E_) {
        int s = edge_at(ei, is64, i);
        int d = edge_at(ei, is64, (long long)E_ + i);
        int pos = atomicAdd(&ctr[d], 1);
        srcs[pos] = s;
    }
}

// ---------- f32 tiled GEMM: C[M,NCOL] = A[M,KDIM] @ W[KDIM,NCOL] ----------
template <int KDIM, int NCOL>
__global__ __launch_bounds__(256) void gemm_kernel(const float* __restrict__ A,
                                                   const float* __restrict__ W,
                                                   float* __restrict__ C, int M) {
    __shared__ float As[16][68];
    __shared__ float Bs[16][64];
    const int row0 = blockIdx.x * 64;
    const int col0 = blockIdx.y * 64;
    const int t = threadIdx.x;
    const int tx = t & 15, ty = t >> 4;
    float acc[4][4] = {};
    for (int kk = 0; kk < KDIM; kk += 16) {
#pragma unroll
        for (int i = 0; i < 4; i++) {
            int idx = t + i * 256;
            int k = idx & 15, m = idx >> 4;
            int gr = row0 + m;
            As[k][m] = (gr < M) ? A[(long long)gr * KDIM + kk + k] : 0.f;
        }
#pragma unroll
        for (int i = 0; i < 4; i++) {
            int idx = t + i * 256;
            int c = idx & 63, k = idx >> 6;
            Bs[k][c] = W[(long long)(kk + k) * NCOL + col0 + c];
        }
        __syncthreads();
#pragma unroll
        for (int k = 0; k < 16; k++) {
            float4 a = *(const float4*)&As[k][ty * 4];
            float4 b = *(const float4*)&Bs[k][tx * 4];
            acc[0][0] += a.x * b.x; acc[0][1] += a.x * b.y; acc[0][2] += a.x * b.z; acc[0][3] += a.x * b.w;
            acc[1][0] += a.y * b.x; acc[1][1] += a.y * b.y; acc[1][2] += a.y * b.z; acc[1][3] += a.y * b.w;
            acc[2][0] += a.z * b.x; acc[2][1] += a.z * b.y; acc[2][2] += a.z * b.z; acc[2][3] += a.z * b.w;
            acc[3][0] += a.w * b.x; acc[3][1] += a.w * b.y; acc[3][2] += a.w * b.z; acc[3][3] += a.w * b.w;
        }
        __syncthreads();
    }
#pragma unroll
    for (int i = 0; i < 4; i++) {
        int gr = row0 + ty * 4 + i;
        if (gr < M) {
            float4 v = make_float4(acc[i][0], acc[i][1], acc[i][2], acc[i][3]);
            *(float4*)&C[(long long)gr * NCOL + col0 + tx * 4] = v;
        }
    }
}

// ---------- attention coefficients ----------
// layer1: h is [N,256] = [N,2,128]; att_* are [2,128]
__global__ __launch_bounds__(256) void attn_coef1_kernel(const float* __restrict__ h,
                                                         const float* __restrict__ att_src,
                                                         const float* __restrict__ att_dst,
                                                         float* __restrict__ a_s,
                                                         float* __restrict__ a_d, int Nn) {
    int wid = threadIdx.x >> 6, lane = threadIdx.x & 63;
    int n = blockIdx.x * 4 + wid;
    if (n >= Nn) return;
    int col = lane * 4;
    float4 hv = *(const float4*)&h[(long long)n * 256 + col];
    float4 as = *(const float4*)&att_src[col];
    float4 ad = *(const float4*)&att_dst[col];
    float ps = hv.x * as.x + hv.y * as.y + hv.z * as.z + hv.w * as.w;
    float pd = hv.x * ad.x + hv.y * ad.y + hv.z * ad.z + hv.w * ad.w;
    for (int off = 16; off >= 1; off >>= 1) {
        ps += __shfl_xor(ps, off);
        pd += __shfl_xor(pd, off);
    }
    if ((lane & 31) == 0) {
        int hh = lane >> 5;
        a_s[n * 2 + hh] = ps;
        a_d[n * 2 + hh] = pd;
    }
}

// layer2: h is [N,128]; att_* are [1,128]
__global__ __launch_bounds__(256) void attn_coef2_kernel(const float* __restrict__ h,
                                                         const float* __restrict__ att_src,
                                                         const float* __restrict__ att_dst,
                                                         float* __restrict__ a_s,
                                                         float* __restrict__ a_d, int Nn) {
    int wid = threadIdx.x >> 6, lane = threadIdx.x & 63;
    int n = blockIdx.x * 4 + wid;
    if (n >= Nn) return;
    int col = lane * 2;
    float2 hv = *(const float2*)&h[(long long)n * 128 + col];
    float2 as = *(const float2*)&att_src[col];
    float2 ad = *(const float2*)&att_dst[col];
    float ps = hv.x * as.x + hv.y * as.y;
    float pd = hv.x * ad.x + hv.y * ad.y;
    for (int off = 32; off >= 1; off >>= 1) {
        ps += __shfl_xor(ps, off);
        pd += __shfl_xor(pd, off);
    }
    if (lane == 0) { a_s[n] = ps; a_d[n] = pd; }
}

// ---------- softmax + aggregation (one wave per dst node) ----------
__global__ __launch_bounds__(256) void aggregate1_kernel(const float* __restrict__ h,
                                                         const int* __restrict__ rowptr,
                                                         const int* __restrict__ srcs,
                                                         const float* __restrict__ a_s,
                                                         const float* __restrict__ a_d,
                                                         const float* __restrict__ bias,
                                                         float* __restrict__ out, int Nn) {
    int wid = threadIdx.x >> 6, lane = threadIdx.x & 63;
    int n = blockIdx.x * 4 + wid;
    if (n >= Nn) return;
    int beg = rowptr[n], end = rowptr[n + 1];
    float ad0 = a_d[n * 2 + 0], ad1 = a_d[n * 2 + 1];
    // pass A: per-head max over incoming edges (lane-parallel)
    float m0 = -1e30f, m1 = -1e30f;
    for (int j = beg + lane; j < end; j += 64) {
        int s = srcs[j];
        m0 = fmaxf(m0, lrelu(a_s[s * 2 + 0] + ad0));
        m1 = fmaxf(m1, lrelu(a_s[s * 2 + 1] + ad1));
    }
    for (int off = 32; off >= 1; off >>= 1) {
        m0 = fmaxf(m0, __shfl_xor(m0, off));
        m1 = fmaxf(m1, __shfl_xor(m1, off));
    }
    int hh = lane >> 5;
    float mh = hh ? m1 : m0;
    float adh = hh ? ad1 : ad0;
    int col = (hh << 7) + (lane & 31) * 4;
    float4 acc = make_float4(0.f, 0.f, 0.f, 0.f);
    float denom = 0.f;
    // pass B: weighted sum; divide once at the end
    for (int j = beg; j < end; j++) {
        int s = srcs[j];
        float w = __expf(lrelu(a_s[s * 2 + hh] + adh) - mh);
        denom += w;
        float4 hv = *(const float4*)&h[(long long)s * 256 + col];
        acc.x += w * hv.x; acc.y += w * hv.y; acc.z += w * hv.z; acc.w += w * hv.w;
    }
    float inv = 1.f / (denom + 1e-16f);
    float4 bv = *(const float4*)&bias[col];
    float4 o = make_float4(acc.x * inv + bv.x, acc.y * inv + bv.y,
                           acc.z * inv + bv.z, acc.w * inv + bv.w);
    *(float4*)&out[(long long)n * 256 + col] = o;
}

__global__ __launch_bounds__(256) void aggregate2_kernel(const float* __restrict__ h,
                                                         const int* __restrict__ rowptr,
                                                         const int* __restrict__ srcs,
                                                         const float* __restrict__ a_s,
                                                         const float* __restrict__ a_d,
                                                         const float* __restrict__ bias,
                                                         float* __restrict__ out, int Nn) {
    int wid = threadIdx.x >> 6, lane = threadIdx.x & 63;
    int n = blockIdx.x * 4 + wid;
    if (n >= Nn) return;
    int beg = rowptr[n], end = rowptr[n + 1];
    float ad = a_d[n];
    float m = -1e30f;
    for (int j = beg + lane; j < end; j += 64) {
        int s = srcs[j];
        m = fmaxf(m, lrelu(a_s[s] + ad));
    }
    for (int off = 32; off >= 1; off >>= 1) m = fmaxf(m, __shfl_xor(m, off));
    int col = lane * 2;
    float2 acc = make_float2(0.f, 0.f);
    float denom = 0.f;
    for (int j = beg; j < end; j++) {
        int s = srcs[j];
        float w = __expf(lrelu(a_s[s] + ad) - m);
        denom += w;
        float2 hv = *(const float2*)&h[(long long)s * 128 + col];
        acc.x += w * hv.x; acc.y += w * hv.y;
    }
    float inv = 1.f / (denom + 1e-16f);
    out[(long long)n * 128 + col]     = acc.x * inv + bias[col];
    out[(long long)n * 128 + col + 1] = acc.y * inv + bias[col + 1];
}

// ---------- batchnorm ----------
template <int CW>
__global__ __launch_bounds__(256) void bn_stats_kernel(const float* __restrict__ x,
                                                       float* __restrict__ sums, int Nn) {
    int t = threadIdx.x;
    int col = t % CW;
    int rpb = 256 / CW;
    int r0 = blockIdx.x * rpb + t / CW;
    int rs = gridDim.x * rpb;
    float s = 0.f, q = 0.f;
    for (int r = r0; r < Nn; r += rs) {
        float v = x[(long long)r * CW + col];
        s += v; q += v * v;
    }
    atomicAdd(&sums[col], s);
    atomicAdd(&sums[CW + col], q);
}

template <int CW>
__global__ __launch_bounds__(256) void bn_apply_kernel(float* __restrict__ x,
                                                       const float* __restrict__ sums,
                                                       const float* __restrict__ gamma,
                                                       const float* __restrict__ beta, int Nn) {
    int t = threadIdx.x;
    int col = t % CW;
    float mu = sums[col] / (float)Nn;
    float var = sums[CW + col] / (float)Nn - mu * mu;
    float sc = rsqrtf(var + EPS_BN) * gamma[col];
    float sh = beta[col] - mu * sc;
    int rpb = 256 / CW;
    int r0 = blockIdx.x * rpb + t / CW;
    int rs = gridDim.x * rpb;
    for (int r = r0; r < Nn; r += rs) {
        long long idx = (long long)r * CW + col;
        float v = x[idx] * sc + sh;
        x[idx] = fmaxf(v, 0.f);
    }
}

extern "C" void kernel_launch(void* const* d_in, const int* in_sizes, int n_in,
                              void* d_out, int out_size, void* d_ws, size_t ws_size,
                              hipStream_t stream) {
    const float* x        = (const float*)d_in[0];
    const void*  ei       = d_in[1];
    const float* W1       = (const float*)d_in[2];
    const float* att_src1 = (const float*)d_in[3];
    const float* att_dst1 = (const float*)d_in[4];
    const float* b1       = (const float*)d_in[5];
    const float* g1       = (const float*)d_in[6];
    const float* be1      = (const float*)d_in[7];
    const float* W2       = (const float*)d_in[8];
    const float* att_src2 = (const float*)d_in[9];
    const float* att_dst2 = (const float*)d_in[10];
    const float* b2       = (const float*)d_in[11];
    const float* g2       = (const float*)d_in[12];
    const float* be2      = (const float*)d_in[13];

    const int Nn = in_sizes[0] / IN_DIM;  // 50000
    const int E_ = in_sizes[1] / 2;       // 800000

    char* ws = (char*)d_ws;
    size_t o = 0;
    auto alloc = [&](size_t bytes) {
        size_t r = o;
        o += (bytes + 255) & ~(size_t)255;
        return r;
    };
    int*   flag   = (int*)(ws + alloc(4));
    int*   deg    = (int*)(ws + alloc((size_t)Nn * 4));
    int*   rowptr = (int*)(ws + alloc((size_t)(Nn + 1) * 4));
    int*   ctr    = (int*)(ws + alloc((size_t)Nn * 4));
    int*   srcs   = (int*)(ws + alloc((size_t)E_ * 4));
    float* as1    = (float*)(ws + alloc((size_t)Nn * 2 * 4));
    float* ad1    = (float*)(ws + alloc((size_t)Nn * 2 * 4));
    float* as2    = (float*)(ws + alloc((size_t)Nn * 4));
    float* ad2    = (float*)(ws + alloc((size_t)Nn * 4));
    float* bn1    = (float*)(ws + alloc(512 * 4));
    float* bn2    = (float*)(ws + alloc(256 * 4));
    float* h1     = (float*)(ws + alloc((size_t)Nn * 256 * 4));
    float* x2     = (float*)(ws + alloc((size_t)Nn * 256 * 4));
    float* h2     = (float*)(ws + alloc((size_t)Nn * 128 * 4));
    float* outf   = (float*)d_out;

    hipMemsetAsync(deg, 0, (size_t)Nn * 4, stream);
    hipMemsetAsync(bn1, 0, 512 * 4, stream);
    hipMemsetAsync(bn2, 0, 256 * 4, stream);

    detect_kernel<<<1, 256, 0, stream>>>((const unsigned int*)ei, flag, (long long)2 * E_);

    int eb = (E_ + 255) / 256;
    count_deg_kernel<<<eb, 256, 0, stream>>>(ei, flag, deg, E_);
    scan_kernel<<<1, 1024, 0, stream>>>(deg, rowptr, ctr, Nn);
    scatter_kernel<<<eb, 256, 0, stream>>>(ei, flag, ctr, srcs, E_);

    int nb4 = (Nn + 3) / 4;

    // layer 1
    gemm_kernel<256, 256><<<dim3((Nn + 63) / 64, 4), 256, 0, stream>>>(x, W1, h1, Nn);
    attn_coef1_kernel<<<nb4, 256, 0, stream>>>(h1, att_src1, att_dst1, as1, ad1, Nn);
    aggregate1_kernel<<<nb4, 256, 0, stream>>>(h1, rowptr, srcs, as1, ad1, b1, x2, Nn);
    bn_stats_kernel<256><<<256, 256, 0, stream>>>(x2, bn1, Nn);
    bn_apply_kernel<256><<<512, 256, 0, stream>>>(x2, bn1, g1, be1, Nn);

    // layer 2
    gemm_kernel<256, 128><<<dim3((Nn + 63) / 64, 2), 256, 0, stream>>>(x2, W2, h2, Nn);
    attn_coef2_kernel<<<nb4, 256, 0, stream>>>(h2, att_src2, att_dst2, as2, ad2, Nn);
    aggregate2_kernel<<<nb4, 256, 0, stream>>>(h2, rowptr, srcs, as2, ad2, b2, outf, Nn);
    bn_stats_kernel<128><<<256, 256, 0, stream>>>(outf, bn2, Nn);
    bn_apply_kernel<128><<<512, 256, 0, stream>>>(outf, bn2, g2, be2, Nn);
}

// Round 2
// 613.475 us; speedup vs baseline: 1.2071x; 1.2071x over previous
//
#include <hip/hip_runtime.h>
#include <math.h>

#define IN_DIM 256
#define HID 128
#define HEADS 2
#define EPS_BN 1e-5f

__device__ __forceinline__ float lrelu(float v) { return v > 0.f ? v : 0.2f * v; }

// bf16 <-> f32 helpers (RNE pack, deterministic, no type-punning headaches)
__device__ __forceinline__ unsigned short f2bf(float f) {
    unsigned int u = __float_as_uint(f);
    u += 0x7fffu + ((u >> 16) & 1u);
    return (unsigned short)(u >> 16);
}
__device__ __forceinline__ float bf2f(unsigned short s) {
    return __uint_as_float((unsigned int)s << 16);
}

// ---------- edge-index dtype detection (int32 vs int64) ----------
__global__ void detect_kernel(const unsigned int* __restrict__ w, int* __restrict__ flag,
                              long long nwords) {
    __shared__ int nz;
    if (threadIdx.x == 0) nz = 0;
    __syncthreads();
    int cnt = 0;
    for (int i = 0; i < 4; i++) {
        long long idx = 2LL * (threadIdx.x + i * 256) + 1;  // odd 32-bit words
        if (idx < nwords && w[idx] != 0u) cnt++;
    }
    if (cnt) atomicAdd(&nz, 1);
    __syncthreads();
    if (threadIdx.x == 0) flag[0] = (nz == 0) ? 1 : 0;  // all-zero odd words -> int64
}

__device__ __forceinline__ int edge_at(const void* ei, int is64, long long i) {
    if (is64) return (int)((const long long*)ei)[i];
    return ((const int*)ei)[i];
}

// ---------- CSR build ----------
__global__ void count_deg_kernel(const void* __restrict__ ei, const int* __restrict__ flag,
                                 int* __restrict__ deg, int E_) {
    int is64 = flag[0];
    int i = blockIdx.x * 256 + threadIdx.x;
    if (i < E_) {
        int d = edge_at(ei, is64, (long long)E_ + i);
        atomicAdd(&deg[d], 1);
    }
}

__global__ __launch_bounds__(1024) void scan_kernel(const int* __restrict__ deg,
                                                    int* __restrict__ rowptr,
                                                    int* __restrict__ ctr, int n) {
    __shared__ int part[1024];
    int t = threadIdx.x;
    int chunk = (n + 1023) / 1024;
    int lo = t * chunk;
    int hi = lo + chunk; if (hi > n) hi = n;
    int s = 0;
    for (int i = lo; i < hi; i++) s += deg[i];
    part[t] = s;
    __syncthreads();
    for (int off = 1; off < 1024; off <<= 1) {
        int v = (t >= off) ? part[t - off] : 0;
        __syncthreads();
        part[t] += v;
        __syncthreads();
    }
    int base = (t == 0) ? 0 : part[t - 1];
    for (int i = lo; i < hi; i++) {
        rowptr[i] = base; ctr[i] = base;
        base += deg[i];
    }
    if (t == 1023) rowptr[n] = part[1023];
}

__global__ void scatter_kernel(const void* __restrict__ ei, const int* __restrict__ flag,
                               int* __restrict__ ctr, int* __restrict__ srcs, int E_) {
    int is64 = flag[0];
    int i = blockIdx.x * 256 + threadIdx.x;
    if (i < E_) {
        int s = edge_at(ei, is64, i);
        int d = edge_at(ei, is64, (long long)E_ + i);
        int pos = atomicAdd(&ctr[d], 1);
        srcs[pos] = s;
    }
}

// ---------- f32 tiled GEMM -> bf16 output: C[M,NCOL] = A[M,KDIM] @ W[KDIM,NCOL] ----------
// FUSEBN: apply BatchNorm+ReLU (from column sums) to A while staging the tile.
template <int KDIM, int NCOL, bool FUSEBN>
__global__ __launch_bounds__(256) void gemm_kernel(const float* __restrict__ A,
                                                   const float* __restrict__ W,
                                                   const float* __restrict__ bnsum,
                                                   const float* __restrict__ gamma,
                                                   const float* __restrict__ beta,
                                                   unsigned short* __restrict__ C, int M) {
    __shared__ float As[16][68];
    __shared__ float Bs[16][64];
    __shared__ float scs[FUSEBN ? KDIM : 1];
    __shared__ float shs[FUSEBN ? KDIM : 1];
    const int t = threadIdx.x;
    if (FUSEBN) {
        float invN = 1.f / (float)M;
        for (int c = t; c < KDIM; c += 256) {
            float mu = bnsum[c] * invN;
            float var = bnsum[KDIM + c] * invN - mu * mu;
            float s = rsqrtf(var + EPS_BN) * gamma[c];
            scs[c] = s;
            shs[c] = beta[c] - mu * s;
        }
        __syncthreads();
    }
    const int row0 = blockIdx.x * 64;
    const int col0 = blockIdx.y * 64;
    const int tx = t & 15, ty = t >> 4;
    float acc[4][4] = {};
    for (int kk = 0; kk < KDIM; kk += 16) {
#pragma unroll
        for (int i = 0; i < 4; i++) {
            int idx = t + i * 256;
            int k = idx & 15, m = idx >> 4;
            int gr = row0 + m;
            float v = (gr < M) ? A[(long long)gr * KDIM + kk + k] : 0.f;
            if (FUSEBN) v = fmaxf(v * scs[kk + k] + shs[kk + k], 0.f);
            As[k][m] = v;
        }
#pragma unroll
        for (int i = 0; i < 4; i++) {
            int idx = t + i * 256;
            int c = idx & 63, k = idx >> 6;
            Bs[k][c] = W[(long long)(kk + k) * NCOL + col0 + c];
        }
        __syncthreads();
#pragma unroll
        for (int k = 0; k < 16; k++) {
            float4 a = *(const float4*)&As[k][ty * 4];
            float4 b = *(const float4*)&Bs[k][tx * 4];
            acc[0][0] += a.x * b.x; acc[0][1] += a.x * b.y; acc[0][2] += a.x * b.z; acc[0][3] += a.x * b.w;
            acc[1][0] += a.y * b.x; acc[1][1] += a.y * b.y; acc[1][2] += a.y * b.z; acc[1][3] += a.y * b.w;
            acc[2][0] += a.z * b.x; acc[2][1] += a.z * b.y; acc[2][2] += a.z * b.z; acc[2][3] += a.z * b.w;
            acc[3][0] += a.w * b.x; acc[3][1] += a.w * b.y; acc[3][2] += a.w * b.z; acc[3][3] += a.w * b.w;
        }
        __syncthreads();
    }
#pragma unroll
    for (int i = 0; i < 4; i++) {
        int gr = row0 + ty * 4 + i;
        if (gr < M) {
            ushort4 o;
            o.x = f2bf(acc[i][0]); o.y = f2bf(acc[i][1]);
            o.z = f2bf(acc[i][2]); o.w = f2bf(acc[i][3]);
            *(ushort4*)&C[(long long)gr * NCOL + col0 + tx * 4] = o;
        }
    }
}

// ---------- attention coefficients (bf16 h) ----------
// layer1: h is [N,256] = [N,2,128]; att_* are [2,128]
__global__ __launch_bounds__(256) void attn_coef1_kernel(const unsigned short* __restrict__ h,
                                                         const float* __restrict__ att_src,
                                                         const float* __restrict__ att_dst,
                                                         float* __restrict__ a_s,
                                                         float* __restrict__ a_d, int Nn) {
    int wid = threadIdx.x >> 6, lane = threadIdx.x & 63;
    int n = blockIdx.x * 4 + wid;
    if (n >= Nn) return;
    int col = lane * 4;
    ushort4 hv = *(const ushort4*)&h[(long long)n * 256 + col];
    float h0 = bf2f(hv.x), h1 = bf2f(hv.y), h2 = bf2f(hv.z), h3 = bf2f(hv.w);
    float4 as = *(const float4*)&att_src[col];
    float4 ad = *(const float4*)&att_dst[col];
    float ps = h0 * as.x + h1 * as.y + h2 * as.z + h3 * as.w;
    float pd = h0 * ad.x + h1 * ad.y + h2 * ad.z + h3 * ad.w;
    for (int off = 16; off >= 1; off >>= 1) {
        ps += __shfl_xor(ps, off);
        pd += __shfl_xor(pd, off);
    }
    if ((lane & 31) == 0) {
        int hh = lane >> 5;
        a_s[n * 2 + hh] = ps;
        a_d[n * 2 + hh] = pd;
    }
}

// layer2: h is [N,128]; att_* are [1,128]
__global__ __launch_bounds__(256) void attn_coef2_kernel(const unsigned short* __restrict__ h,
                                                         const float* __restrict__ att_src,
                                                         const float* __restrict__ att_dst,
                                                         float* __restrict__ a_s,
                                                         float* __restrict__ a_d, int Nn) {
    int wid = threadIdx.x >> 6, lane = threadIdx.x & 63;
    int n = blockIdx.x * 4 + wid;
    if (n >= Nn) return;
    int col = lane * 2;
    unsigned int hv = *(const unsigned int*)&h[(long long)n * 128 + col];
    float h0 = bf2f((unsigned short)(hv & 0xffffu));
    float h1 = bf2f((unsigned short)(hv >> 16));
    float2 as = *(const float2*)&att_src[col];
    float2 ad = *(const float2*)&att_dst[col];
    float ps = h0 * as.x + h1 * as.y;
    float pd = h0 * ad.x + h1 * ad.y;
    for (int off = 32; off >= 1; off >>= 1) {
        ps += __shfl_xor(ps, off);
        pd += __shfl_xor(pd, off);
    }
    if (lane == 0) { a_s[n] = ps; a_d[n] = pd; }
}

// ---------- softmax + aggregation (one wave per dst node, bf16 h gather) ----------
__global__ __launch_bounds__(256) void aggregate1_kernel(const unsigned short* __restrict__ h,
                                                         const int* __restrict__ rowptr,
                                                         const int* __restrict__ srcs,
                                                         const float* __restrict__ a_s,
                                                         const float* __restrict__ a_d,
                                                         const float* __restrict__ bias,
                                                         float* __restrict__ out, int Nn) {
    int wid = threadIdx.x >> 6, lane = threadIdx.x & 63;
    int n = blockIdx.x * 4 + wid;
    if (n >= Nn) return;
    int beg = rowptr[n], end = rowptr[n + 1];
    float ad0 = a_d[n * 2 + 0], ad1 = a_d[n * 2 + 1];
    // pass A: per-head max over incoming edges (lane-parallel)
    float m0 = -1e30f, m1 = -1e30f;
    for (int j = beg + lane; j < end; j += 64) {
        int s = srcs[j];
        m0 = fmaxf(m0, lrelu(a_s[s * 2 + 0] + ad0));
        m1 = fmaxf(m1, lrelu(a_s[s * 2 + 1] + ad1));
    }
    for (int off = 32; off >= 1; off >>= 1) {
        m0 = fmaxf(m0, __shfl_xor(m0, off));
        m1 = fmaxf(m1, __shfl_xor(m1, off));
    }
    int hh = lane >> 5;
    float mh = hh ? m1 : m0;
    float adh = hh ? ad1 : ad0;
    int col = (hh << 7) + (lane & 31) * 4;
    float4 acc = make_float4(0.f, 0.f, 0.f, 0.f);
    float denom = 0.f;
    // pass B: weighted sum (x2-unrolled for more outstanding gathers)
    int j = beg;
    for (; j + 2 <= end; j += 2) {
        int s0 = srcs[j], s1 = srcs[j + 1];
        float w0 = __expf(lrelu(a_s[s0 * 2 + hh] + adh) - mh);
        float w1 = __expf(lrelu(a_s[s1 * 2 + hh] + adh) - mh);
        ushort4 p0 = *(const ushort4*)&h[(long long)s0 * 256 + col];
        ushort4 p1 = *(const ushort4*)&h[(long long)s1 * 256 + col];
        denom += w0 + w1;
        acc.x += w0 * bf2f(p0.x) + w1 * bf2f(p1.x);
        acc.y += w0 * bf2f(p0.y) + w1 * bf2f(p1.y);
        acc.z += w0 * bf2f(p0.z) + w1 * bf2f(p1.z);
        acc.w += w0 * bf2f(p0.w) + w1 * bf2f(p1.w);
    }
    if (j < end) {
        int s0 = srcs[j];
        float w0 = __expf(lrelu(a_s[s0 * 2 + hh] + adh) - mh);
        ushort4 p0 = *(const ushort4*)&h[(long long)s0 * 256 + col];
        denom += w0;
        acc.x += w0 * bf2f(p0.x);
        acc.y += w0 * bf2f(p0.y);
        acc.z += w0 * bf2f(p0.z);
        acc.w += w0 * bf2f(p0.w);
    }
    float inv = 1.f / (denom + 1e-16f);
    float4 bv = *(const float4*)&bias[col];
    float4 o = make_float4(acc.x * inv + bv.x, acc.y * inv + bv.y,
                           acc.z * inv + bv.z, acc.w * inv + bv.w);
    *(float4*)&out[(long long)n * 256 + col] = o;
}

__global__ __launch_bounds__(256) void aggregate2_kernel(const unsigned short* __restrict__ h,
                                                         const int* __restrict__ rowptr,
                                                         const int* __restrict__ srcs,
                                                         const float* __restrict__ a_s,
                                                         const float* __restrict__ a_d,
                                                         const float* __restrict__ bias,
                                                         float* __restrict__ out, int Nn) {
    int wid = threadIdx.x >> 6, lane = threadIdx.x & 63;
    int n = blockIdx.x * 4 + wid;
    if (n >= Nn) return;
    int beg = rowptr[n], end = rowptr[n + 1];
    float ad = a_d[n];
    float m = -1e30f;
    for (int j = beg + lane; j < end; j += 64) {
        int s = srcs[j];
        m = fmaxf(m, lrelu(a_s[s] + ad));
    }
    for (int off = 32; off >= 1; off >>= 1) m = fmaxf(m, __shfl_xor(m, off));
    int col = lane * 2;
    float2 acc = make_float2(0.f, 0.f);
    float denom = 0.f;
    int j = beg;
    for (; j + 2 <= end; j += 2) {
        int s0 = srcs[j], s1 = srcs[j + 1];
        float w0 = __expf(lrelu(a_s[s0] + ad) - m);
        float w1 = __expf(lrelu(a_s[s1] + ad) - m);
        unsigned int p0 = *(const unsigned int*)&h[(long long)s0 * 128 + col];
        unsigned int p1 = *(const unsigned int*)&h[(long long)s1 * 128 + col];
        denom += w0 + w1;
        acc.x += w0 * bf2f((unsigned short)(p0 & 0xffffu)) + w1 * bf2f((unsigned short)(p1 & 0xffffu));
        acc.y += w0 * bf2f((unsigned short)(p0 >> 16)) + w1 * bf2f((unsigned short)(p1 >> 16));
    }
    if (j < end) {
        int s0 = srcs[j];
        float w0 = __expf(lrelu(a_s[s0] + ad) - m);
        unsigned int p0 = *(const unsigned int*)&h[(long long)s0 * 128 + col];
        denom += w0;
        acc.x += w0 * bf2f((unsigned short)(p0 & 0xffffu));
        acc.y += w0 * bf2f((unsigned short)(p0 >> 16));
    }
    float inv = 1.f / (denom + 1e-16f);
    out[(long long)n * 128 + col]     = acc.x * inv + bias[col];
    out[(long long)n * 128 + col + 1] = acc.y * inv + bias[col + 1];
}

// ---------- batchnorm ----------
template <int CW>
__global__ __launch_bounds__(256) void bn_stats_kernel(const float* __restrict__ x,
                                                       float* __restrict__ sums, int Nn) {
    int t = threadIdx.x;
    int col = t % CW;
    int rpb = 256 / CW;
    int r0 = blockIdx.x * rpb + t / CW;
    int rs = gridDim.x * rpb;
    float s = 0.f, q = 0.f;
    for (int r = r0; r < Nn; r += rs) {
        float v = x[(long long)r * CW + col];
        s += v; q += v * v;
    }
    atomicAdd(&sums[col], s);
    atomicAdd(&sums[CW + col], q);
}

template <int CW>
__global__ __launch_bounds__(256) void bn_apply_kernel(float* __restrict__ x,
                                                       const float* __restrict__ sums,
                                                       const float* __restrict__ gamma,
                                                       const float* __restrict__ beta, int Nn) {
    int t = threadIdx.x;
    int col = t % CW;
    float mu = sums[col] / (float)Nn;
    float var = sums[CW + col] / (float)Nn - mu * mu;
    float sc = rsqrtf(var + EPS_BN) * gamma[col];
    float sh = beta[col] - mu * sc;
    int rpb = 256 / CW;
    int r0 = blockIdx.x * rpb + t / CW;
    int rs = gridDim.x * rpb;
    for (int r = r0; r < Nn; r += rs) {
        long long idx = (long long)r * CW + col;
        float v = x[idx] * sc + sh;
        x[idx] = fmaxf(v, 0.f);
    }
}

extern "C" void kernel_launch(void* const* d_in, const int* in_sizes, int n_in,
                              void* d_out, int out_size, void* d_ws, size_t ws_size,
                              hipStream_t stream) {
    const float* x        = (const float*)d_in[0];
    const void*  ei       = d_in[1];
    const float* W1       = (const float*)d_in[2];
    const float* att_src1 = (const float*)d_in[3];
    const float* att_dst1 = (const float*)d_in[4];
    const float* b1       = (const float*)d_in[5];
    const float* g1       = (const float*)d_in[6];
    const float* be1      = (const float*)d_in[7];
    const float* W2       = (const float*)d_in[8];
    const float* att_src2 = (const float*)d_in[9];
    const float* att_dst2 = (const float*)d_in[10];
    const float* b2       = (const float*)d_in[11];
    const float* g2       = (const float*)d_in[12];
    const float* be2      = (const float*)d_in[13];

    const int Nn = in_sizes[0] / IN_DIM;  // 50000
    const int E_ = in_sizes[1] / 2;       // 800000

    char* ws = (char*)d_ws;
    size_t o = 0;
    auto alloc = [&](size_t bytes) {
        size_t r = o;
        o += (bytes + 255) & ~(size_t)255;
        return r;
    };
    int*   flag   = (int*)(ws + alloc(4));
    int*   deg    = (int*)(ws + alloc((size_t)Nn * 4));
    int*   rowptr = (int*)(ws + alloc((size_t)(Nn + 1) * 4));
    int*   ctr    = (int*)(ws + alloc((size_t)Nn * 4));
    int*   srcs   = (int*)(ws + alloc((size_t)E_ * 4));
    float* as1    = (float*)(ws + alloc((size_t)Nn * 2 * 4));
    float* ad1    = (float*)(ws + alloc((size_t)Nn * 2 * 4));
    float* as2    = (float*)(ws + alloc((size_t)Nn * 4));
    float* ad2    = (float*)(ws + alloc((size_t)Nn * 4));
    float* bn1    = (float*)(ws + alloc(512 * 4));
    float* bn2    = (float*)(ws + alloc(256 * 4));
    unsigned short* h1b = (unsigned short*)(ws + alloc((size_t)Nn * 256 * 2));
    unsigned short* h2b = (unsigned short*)(ws + alloc((size_t)Nn * 128 * 2));
    float* x2     = (float*)(ws + alloc((size_t)Nn * 256 * 4));
    float* outf   = (float*)d_out;

    hipMemsetAsync(deg, 0, (size_t)Nn * 4, stream);
    hipMemsetAsync(bn1, 0, 512 * 4, stream);
    hipMemsetAsync(bn2, 0, 256 * 4, stream);

    detect_kernel<<<1, 256, 0, stream>>>((const unsigned int*)ei, flag, (long long)2 * E_);

    int eb = (E_ + 255) / 256;
    count_deg_kernel<<<eb, 256, 0, stream>>>(ei, flag, deg, E_);
    scan_kernel<<<1, 1024, 0, stream>>>(deg, rowptr, ctr, Nn);
    scatter_kernel<<<eb, 256, 0, stream>>>(ei, flag, ctr, srcs, E_);

    int nb4 = (Nn + 3) / 4;

    // layer 1
    gemm_kernel<256, 256, false><<<dim3((Nn + 63) / 64, 4), 256, 0, stream>>>(
        x, W1, nullptr, nullptr, nullptr, h1b, Nn);
    attn_coef1_kernel<<<nb4, 256, 0, stream>>>(h1b, att_src1, att_dst1, as1, ad1, Nn);
    aggregate1_kernel<<<nb4, 256, 0, stream>>>(h1b, rowptr, srcs, as1, ad1, b1, x2, Nn);
    bn_stats_kernel<256><<<256, 256, 0, stream>>>(x2, bn1, Nn);

    // layer 2 (BN1-apply fused into GEMM2's A-tile staging)
    gemm_kernel<256, 128, true><<<dim3((Nn + 63) / 64, 2), 256, 0, stream>>>(
        x2, W2, bn1, g1, be1, h2b, Nn);
    attn_coef2_kernel<<<nb4, 256, 0, stream>>>(h2b, att_src2, att_dst2, as2, ad2, Nn);
    aggregate2_kernel<<<nb4, 256, 0, stream>>>(h2b, rowptr, srcs, as2, ad2, b2, outf, Nn);
    bn_stats_kernel<128><<<256, 256, 0, stream>>>(outf, bn2, Nn);
    bn_apply_kernel<128><<<512, 256, 0, stream>>>(outf, bn2, g2, be2, Nn);
}

// Round 3
// 478.718 us; speedup vs baseline: 1.5469x; 1.2815x over previous
//
#include <hip/hip_runtime.h>
#include <math.h>

#define IN_DIM 256
#define HID 128
#define HEADS 2
#define EPS_BN 1e-5f

typedef __attribute__((ext_vector_type(8))) short short8v;  // 8 bf16 (4 VGPRs)
typedef __attribute__((ext_vector_type(4))) float f32x4;    // MFMA C/D

__device__ __forceinline__ float lrelu(float v) { return v > 0.f ? v : 0.2f * v; }

// bf16 <-> f32 helpers (RNE pack)
__device__ __forceinline__ unsigned short f2bf(float f) {
    unsigned int u = __float_as_uint(f);
    u += 0x7fffu + ((u >> 16) & 1u);
    return (unsigned short)(u >> 16);
}
__device__ __forceinline__ float bf2f(unsigned short s) {
    return __uint_as_float((unsigned int)s << 16);
}

// ---------- edge-index dtype detection (int32 vs int64) ----------
__global__ void detect_kernel(const unsigned int* __restrict__ w, int* __restrict__ flag,
                              long long nwords) {
    __shared__ int nz;
    if (threadIdx.x == 0) nz = 0;
    __syncthreads();
    int cnt = 0;
    for (int i = 0; i < 4; i++) {
        long long idx = 2LL * (threadIdx.x + i * 256) + 1;  // odd 32-bit words
        if (idx < nwords && w[idx] != 0u) cnt++;
    }
    if (cnt) atomicAdd(&nz, 1);
    __syncthreads();
    if (threadIdx.x == 0) flag[0] = (nz == 0) ? 1 : 0;  // all-zero odd words -> int64
}

__device__ __forceinline__ int edge_at(const void* ei, int is64, long long i) {
    if (is64) return (int)((const long long*)ei)[i];
    return ((const int*)ei)[i];
}

// ---------- CSR build ----------
__global__ void count_deg_kernel(const void* __restrict__ ei, const int* __restrict__ flag,
                                 int* __restrict__ deg, int E_) {
    int is64 = flag[0];
    int i = blockIdx.x * 256 + threadIdx.x;
    if (i < E_) {
        int d = edge_at(ei, is64, (long long)E_ + i);
        atomicAdd(&deg[d], 1);
    }
}

// 3-phase parallel exclusive scan over deg[0..n) -> rowptr/ctr (n <= 256*256)
__global__ __launch_bounds__(256) void scan_partial_kernel(const int* __restrict__ deg,
                                                           int* __restrict__ bsum, int n) {
    __shared__ int sh[256];
    int t = threadIdx.x;
    int i = blockIdx.x * 256 + t;
    sh[t] = (i < n) ? deg[i] : 0;
    __syncthreads();
    for (int off = 128; off >= 1; off >>= 1) {
        if (t < off) sh[t] += sh[t + off];
        __syncthreads();
    }
    if (t == 0) bsum[blockIdx.x] = sh[0];
}

__global__ __launch_bounds__(256) void scan_bsum_kernel(int* __restrict__ bsum,
                                                        int* __restrict__ bofs,
                                                        int* __restrict__ rowptr,
                                                        int nb, int n) {
    __shared__ int sh[256];
    int t = threadIdx.x;
    int v = (t < nb) ? bsum[t] : 0;
    sh[t] = v;
    __syncthreads();
    for (int off = 1; off < 256; off <<= 1) {
        int u = (t >= off) ? sh[t - off] : 0;
        __syncthreads();
        sh[t] += u;
        __syncthreads();
    }
    if (t < nb) bofs[t] = sh[t] - v;  // exclusive
    if (t == 255) rowptr[n] = sh[255];
}

__global__ __launch_bounds__(256) void scan_write_kernel(const int* __restrict__ deg,
                                                         const int* __restrict__ bofs,
                                                         int* __restrict__ rowptr,
                                                         int* __restrict__ ctr, int n) {
    __shared__ int sh[256];
    int t = threadIdx.x;
    int i = blockIdx.x * 256 + t;
    int d = (i < n) ? deg[i] : 0;
    sh[t] = d;
    __syncthreads();
    for (int off = 1; off < 256; off <<= 1) {
        int u = (t >= off) ? sh[t - off] : 0;
        __syncthreads();
        sh[t] += u;
        __syncthreads();
    }
    if (i < n) {
        int v = bofs[blockIdx.x] + sh[t] - d;
        rowptr[i] = v;
        ctr[i] = v;
    }
}

__global__ void scatter_kernel(const void* __restrict__ ei, const int* __restrict__ flag,
                               int* __restrict__ ctr, int* __restrict__ srcs, int E_) {
    int is64 = flag[0];
    int i = blockIdx.x * 256 + threadIdx.x;
    if (i < E_) {
        int s = edge_at(ei, is64, i);
        int d = edge_at(ei, is64, (long long)E_ + i);
        int pos = atomicAdd(&ctr[d], 1);
        srcs[pos] = s;
    }
}

// ---------- W transpose + bf16 cast: Wt[c][k] = bf16(W[k][c]) ----------
__global__ void transpose_cast_kernel(const float* __restrict__ W,
                                      unsigned short* __restrict__ Wt, int K, int Ccols) {
    int idx = blockIdx.x * 256 + threadIdx.x;
    if (idx >= K * Ccols) return;
    int c = idx / K, k = idx % K;
    Wt[idx] = f2bf(W[(long long)k * Ccols + c]);
}

// ---------- MFMA bf16 GEMM: C[M,NCOL] = A[M,256] @ W[256,NCOL], Wt = W^T bf16 ----------
// Block: 256 threads = 4 waves; 64 rows x all NCOL cols. Whole-K A tile staged in LDS
// (bf16, BN+ReLU fused for layer 2); B-frags stream from L2-resident Wt.
// Verified gfx950 fragment convention (m89/m91/m97): A row-major [M][K], B^T [N][K];
// A/B frag: lane l -> row/col = l&15, k = (l>>4)*8 + j. C/D: col=l&15, row=(l>>4)*4+reg.
template <int NCOL, bool FUSEBN>
__global__ __launch_bounds__(256) void gemm_mfma_kernel(const float* __restrict__ A,
                                                        const unsigned short* __restrict__ Wt,
                                                        const float* __restrict__ bnsum,
                                                        const float* __restrict__ gamma,
                                                        const float* __restrict__ beta,
                                                        unsigned short* __restrict__ C, int M) {
    constexpr int KD = 256;
    constexpr int NT = NCOL / 16;
    constexpr int PITCH = KD + 8;  // bf16 elems; +8 keeps ds_read_b128 conflict-free
    __shared__ unsigned short A_lds[64 * PITCH];
    __shared__ float scs[FUSEBN ? KD : 1];
    __shared__ float shs[FUSEBN ? KD : 1];
    const int t = threadIdx.x;
    const int row0 = blockIdx.x * 64;

    if (FUSEBN) {
        float invN = 1.f / (float)M;
        for (int c = t; c < KD; c += 256) {
            float mu = bnsum[c] * invN;
            float var = bnsum[KD + c] * invN - mu * mu;
            float s = rsqrtf(var + EPS_BN) * gamma[c];
            scs[c] = s;
            shs[c] = beta[c] - mu * s;
        }
        __syncthreads();
    }

    // stage A[64][256] as bf16 (BN+ReLU fused if requested)
#pragma unroll
    for (int i = 0; i < 16; i++) {
        int f4 = t + i * 256;          // float4 index, 0..4095
        int r = f4 >> 6, c4 = f4 & 63; // row in tile, float4-column
        int gr = row0 + r;
        float4 v = make_float4(0.f, 0.f, 0.f, 0.f);
        if (gr < M) v = *(const float4*)&A[(long long)gr * KD + c4 * 4];
        if (FUSEBN) {
            int k = c4 * 4;
            v.x = fmaxf(v.x * scs[k + 0] + shs[k + 0], 0.f);
            v.y = fmaxf(v.y * scs[k + 1] + shs[k + 1], 0.f);
            v.z = fmaxf(v.z * scs[k + 2] + shs[k + 2], 0.f);
            v.w = fmaxf(v.w * scs[k + 3] + shs[k + 3], 0.f);
        }
        ushort4 o;
        o.x = f2bf(v.x); o.y = f2bf(v.y); o.z = f2bf(v.z); o.w = f2bf(v.w);
        *(ushort4*)&A_lds[r * PITCH + c4 * 4] = o;
    }
    __syncthreads();

    const int w = t >> 6, l = t & 63;
    const int rl = l & 15, kg = l >> 4;
    f32x4 acc[NT];
#pragma unroll
    for (int c = 0; c < NT; c++) acc[c] = (f32x4)(0.f);

    const unsigned short* arow = &A_lds[(w * 16 + rl) * PITCH + kg * 8];
    for (int kk = 0; kk < KD; kk += 32) {
        short8v af = *(const short8v*)(arow + kk);
#pragma unroll
        for (int c = 0; c < NT; c++) {
            short8v bf = *(const short8v*)&Wt[(c * 16 + rl) * KD + kk + kg * 8];
            acc[c] = __builtin_amdgcn_mfma_f32_16x16x32_bf16(af, bf, acc[c], 0, 0, 0);
        }
    }

#pragma unroll
    for (int c = 0; c < NT; c++) {
#pragma unroll
        for (int r = 0; r < 4; r++) {
            int gr = row0 + w * 16 + kg * 4 + r;
            if (gr < M) C[(long long)gr * NCOL + c * 16 + rl] = f2bf(acc[c][r]);
        }
    }
}

// ---------- attention coefficients (bf16 h) ----------
__global__ __launch_bounds__(256) void attn_coef1_kernel(const unsigned short* __restrict__ h,
                                                         const float* __restrict__ att_src,
                                                         const float* __restrict__ att_dst,
                                                         float* __restrict__ a_s,
                                                         float* __restrict__ a_d, int Nn) {
    int wid = threadIdx.x >> 6, lane = threadIdx.x & 63;
    int n = blockIdx.x * 4 + wid;
    if (n >= Nn) return;
    int col = lane * 4;
    ushort4 hv = *(const ushort4*)&h[(long long)n * 256 + col];
    float h0 = bf2f(hv.x), h1 = bf2f(hv.y), h2 = bf2f(hv.z), h3 = bf2f(hv.w);
    float4 as = *(const float4*)&att_src[col];
    float4 ad = *(const float4*)&att_dst[col];
    float ps = h0 * as.x + h1 * as.y + h2 * as.z + h3 * as.w;
    float pd = h0 * ad.x + h1 * ad.y + h2 * ad.z + h3 * ad.w;
    for (int off = 16; off >= 1; off >>= 1) {
        ps += __shfl_xor(ps, off);
        pd += __shfl_xor(pd, off);
    }
    if ((lane & 31) == 0) {
        int hh = lane >> 5;
        a_s[n * 2 + hh] = ps;
        a_d[n * 2 + hh] = pd;
    }
}

__global__ __launch_bounds__(256) void attn_coef2_kernel(const unsigned short* __restrict__ h,
                                                         const float* __restrict__ att_src,
                                                         const float* __restrict__ att_dst,
                                                         float* __restrict__ a_s,
                                                         float* __restrict__ a_d, int Nn) {
    int wid = threadIdx.x >> 6, lane = threadIdx.x & 63;
    int n = blockIdx.x * 4 + wid;
    if (n >= Nn) return;
    int col = lane * 2;
    unsigned int hv = *(const unsigned int*)&h[(long long)n * 128 + col];
    float h0 = bf2f((unsigned short)(hv & 0xffffu));
    float h1 = bf2f((unsigned short)(hv >> 16));
    float2 as = *(const float2*)&att_src[col];
    float2 ad = *(const float2*)&att_dst[col];
    float ps = h0 * as.x + h1 * as.y;
    float pd = h0 * ad.x + h1 * ad.y;
    for (int off = 32; off >= 1; off >>= 1) {
        ps += __shfl_xor(ps, off);
        pd += __shfl_xor(pd, off);
    }
    if (lane == 0) { a_s[n] = ps; a_d[n] = pd; }
}

// ---------- softmax + aggregation (one wave per dst node, bf16 h gather) ----------
__global__ __launch_bounds__(256) void aggregate1_kernel(const unsigned short* __restrict__ h,
                                                         const int* __restrict__ rowptr,
                                                         const int* __restrict__ srcs,
                                                         const float* __restrict__ a_s,
                                                         const float* __restrict__ a_d,
                                                         const float* __restrict__ bias,
                                                         float* __restrict__ out, int Nn) {
    int wid = threadIdx.x >> 6, lane = threadIdx.x & 63;
    int n = blockIdx.x * 4 + wid;
    if (n >= Nn) return;
    int beg = rowptr[n], end = rowptr[n + 1];
    float ad0 = a_d[n * 2 + 0], ad1 = a_d[n * 2 + 1];
    float m0 = -1e30f, m1 = -1e30f;
    for (int j = beg + lane; j < end; j += 64) {
        int s = srcs[j];
        m0 = fmaxf(m0, lrelu(a_s[s * 2 + 0] + ad0));
        m1 = fmaxf(m1, lrelu(a_s[s * 2 + 1] + ad1));
    }
    for (int off = 32; off >= 1; off >>= 1) {
        m0 = fmaxf(m0, __shfl_xor(m0, off));
        m1 = fmaxf(m1, __shfl_xor(m1, off));
    }
    int hh = lane >> 5;
    float mh = hh ? m1 : m0;
    float adh = hh ? ad1 : ad0;
    int col = (hh << 7) + (lane & 31) * 4;
    float4 acc = make_float4(0.f, 0.f, 0.f, 0.f);
    float denom = 0.f;
    int j = beg;
    for (; j + 2 <= end; j += 2) {
        int s0 = srcs[j], s1 = srcs[j + 1];
        float w0 = __expf(lrelu(a_s[s0 * 2 + hh] + adh) - mh);
        float w1 = __expf(lrelu(a_s[s1 * 2 + hh] + adh) - mh);
        ushort4 p0 = *(const ushort4*)&h[(long long)s0 * 256 + col];
        ushort4 p1 = *(const ushort4*)&h[(long long)s1 * 256 + col];
        denom += w0 + w1;
        acc.x += w0 * bf2f(p0.x) + w1 * bf2f(p1.x);
        acc.y += w0 * bf2f(p0.y) + w1 * bf2f(p1.y);
        acc.z += w0 * bf2f(p0.z) + w1 * bf2f(p1.z);
        acc.w += w0 * bf2f(p0.w) + w1 * bf2f(p1.w);
    }
    if (j < end) {
        int s0 = srcs[j];
        float w0 = __expf(lrelu(a_s[s0 * 2 + hh] + adh) - mh);
        ushort4 p0 = *(const ushort4*)&h[(long long)s0 * 256 + col];
        denom += w0;
        acc.x += w0 * bf2f(p0.x);
        acc.y += w0 * bf2f(p0.y);
        acc.z += w0 * bf2f(p0.z);
        acc.w += w0 * bf2f(p0.w);
    }
    float inv = 1.f / (denom + 1e-16f);
    float4 bv = *(const float4*)&bias[col];
    float4 o = make_float4(acc.x * inv + bv.x, acc.y * inv + bv.y,
                           acc.z * inv + bv.z, acc.w * inv + bv.w);
    *(float4*)&out[(long long)n * 256 + col] = o;
}

__global__ __launch_bounds__(256) void aggregate2_kernel(const unsigned short* __restrict__ h,
                                                         const int* __restrict__ rowptr,
                                                         const int* __restrict__ srcs,
                                                         const float* __restrict__ a_s,
                                                         const float* __restrict__ a_d,
                                                         const float* __restrict__ bias,
                                                         float* __restrict__ out, int Nn) {
    int wid = threadIdx.x >> 6, lane = threadIdx.x & 63;
    int n = blockIdx.x * 4 + wid;
    if (n >= Nn) return;
    int beg = rowptr[n], end = rowptr[n + 1];
    float ad = a_d[n];
    float m = -1e30f;
    for (int j = beg + lane; j < end; j += 64) {
        int s = srcs[j];
        m = fmaxf(m, lrelu(a_s[s] + ad));
    }
    for (int off = 32; off >= 1; off >>= 1) m = fmaxf(m, __shfl_xor(m, off));
    int col = lane * 2;
    float2 acc = make_float2(0.f, 0.f);
    float denom = 0.f;
    int j = beg;
    for (; j + 2 <= end; j += 2) {
        int s0 = srcs[j], s1 = srcs[j + 1];
        float w0 = __expf(lrelu(a_s[s0] + ad) - m);
        float w1 = __expf(lrelu(a_s[s1] + ad) - m);
        unsigned int p0 = *(const unsigned int*)&h[(long long)s0 * 128 + col];
        unsigned int p1 = *(const unsigned int*)&h[(long long)s1 * 128 + col];
        denom += w0 + w1;
        acc.x += w0 * bf2f((unsigned short)(p0 & 0xffffu)) + w1 * bf2f((unsigned short)(p1 & 0xffffu));
        acc.y += w0 * bf2f((unsigned short)(p0 >> 16)) + w1 * bf2f((unsigned short)(p1 >> 16));
    }
    if (j < end) {
        int s0 = srcs[j];
        float w0 = __expf(lrelu(a_s[s0] + ad) - m);
        unsigned int p0 = *(const unsigned int*)&h[(long long)s0 * 128 + col];
        denom += w0;
        acc.x += w0 * bf2f((unsigned short)(p0 & 0xffffu));
        acc.y += w0 * bf2f((unsigned short)(p0 >> 16));
    }
    float inv = 1.f / (denom + 1e-16f);
    out[(long long)n * 128 + col]     = acc.x * inv + bias[col];
    out[(long long)n * 128 + col + 1] = acc.y * inv + bias[col + 1];
}

// ---------- batchnorm ----------
template <int CW>
__global__ __launch_bounds__(256) void bn_stats_kernel(const float* __restrict__ x,
                                                       float* __restrict__ sums, int Nn) {
    int t = threadIdx.x;
    int col = t % CW;
    int rpb = 256 / CW;
    int r0 = blockIdx.x * rpb + t / CW;
    int rs = gridDim.x * rpb;
    float s = 0.f, q = 0.f;
    for (int r = r0; r < Nn; r += rs) {
        float v = x[(long long)r * CW + col];
        s += v; q += v * v;
    }
    atomicAdd(&sums[col], s);
    atomicAdd(&sums[CW + col], q);
}

template <int CW>
__global__ __launch_bounds__(256) void bn_apply_kernel(float* __restrict__ x,
                                                       const float* __restrict__ sums,
                                                       const float* __restrict__ gamma,
                                                       const float* __restrict__ beta, int Nn) {
    int t = threadIdx.x;
    int col = t % CW;
    float mu = sums[col] / (float)Nn;
    float var = sums[CW + col] / (float)Nn - mu * mu;
    float sc = rsqrtf(var + EPS_BN) * gamma[col];
    float sh = beta[col] - mu * sc;
    int rpb = 256 / CW;
    int r0 = blockIdx.x * rpb + t / CW;
    int rs = gridDim.x * rpb;
    for (int r = r0; r < Nn; r += rs) {
        long long idx = (long long)r * CW + col;
        float v = x[idx] * sc + sh;
        x[idx] = fmaxf(v, 0.f);
    }
}

extern "C" void kernel_launch(void* const* d_in, const int* in_sizes, int n_in,
                              void* d_out, int out_size, void* d_ws, size_t ws_size,
                              hipStream_t stream) {
    const float* x        = (const float*)d_in[0];
    const void*  ei       = d_in[1];
    const float* W1       = (const float*)d_in[2];
    const float* att_src1 = (const float*)d_in[3];
    const float* att_dst1 = (const float*)d_in[4];
    const float* b1       = (const float*)d_in[5];
    const float* g1       = (const float*)d_in[6];
    const float* be1      = (const float*)d_in[7];
    const float* W2       = (const float*)d_in[8];
    const float* att_src2 = (const float*)d_in[9];
    const float* att_dst2 = (const float*)d_in[10];
    const float* b2       = (const float*)d_in[11];
    const float* g2       = (const float*)d_in[12];
    const float* be2      = (const float*)d_in[13];

    const int Nn = in_sizes[0] / IN_DIM;  // 50000
    const int E_ = in_sizes[1] / 2;       // 800000

    char* ws = (char*)d_ws;
    size_t o = 0;
    auto alloc = [&](size_t bytes) {
        size_t r = o;
        o += (bytes + 255) & ~(size_t)255;
        return r;
    };
    int*   flag   = (int*)(ws + alloc(4));
    int*   deg    = (int*)(ws + alloc((size_t)Nn * 4));
    int*   rowptr = (int*)(ws + alloc((size_t)(Nn + 1) * 4));
    int*   ctr    = (int*)(ws + alloc((size_t)Nn * 4));
    int*   srcs   = (int*)(ws + alloc((size_t)E_ * 4));
    int*   bsum   = (int*)(ws + alloc(256 * 4));
    int*   bofs   = (int*)(ws + alloc(256 * 4));
    float* as1    = (float*)(ws + alloc((size_t)Nn * 2 * 4));
    float* ad1    = (float*)(ws + alloc((size_t)Nn * 2 * 4));
    float* as2    = (float*)(ws + alloc((size_t)Nn * 4));
    float* ad2    = (float*)(ws + alloc((size_t)Nn * 4));
    float* bn1    = (float*)(ws + alloc(512 * 4));
    float* bn2    = (float*)(ws + alloc(256 * 4));
    unsigned short* Wt1 = (unsigned short*)(ws + alloc((size_t)256 * 256 * 2));
    unsigned short* Wt2 = (unsigned short*)(ws + alloc((size_t)128 * 256 * 2));
    unsigned short* h1b = (unsigned short*)(ws + alloc((size_t)Nn * 256 * 2));
    unsigned short* h2b = (unsigned short*)(ws + alloc((size_t)Nn * 128 * 2));
    float* x2     = (float*)(ws + alloc((size_t)Nn * 256 * 4));
    float* outf   = (float*)d_out;

    hipMemsetAsync(deg, 0, (size_t)Nn * 4, stream);
    hipMemsetAsync(bn1, 0, 512 * 4, stream);
    hipMemsetAsync(bn2, 0, 256 * 4, stream);

    // weight transpose + bf16 cast (tiny)
    transpose_cast_kernel<<<(256 * 256 + 255) / 256, 256, 0, stream>>>(W1, Wt1, 256, 256);
    transpose_cast_kernel<<<(128 * 256 + 255) / 256, 256, 0, stream>>>(W2, Wt2, 256, 128);

    detect_kernel<<<1, 256, 0, stream>>>((const unsigned int*)ei, flag, (long long)2 * E_);

    int eb = (E_ + 255) / 256;
    int nsb = (Nn + 255) / 256;  // 196 <= 256
    count_deg_kernel<<<eb, 256, 0, stream>>>(ei, flag, deg, E_);
    scan_partial_kernel<<<nsb, 256, 0, stream>>>(deg, bsum, Nn);
    scan_bsum_kernel<<<1, 256, 0, stream>>>(bsum, bofs, rowptr, nsb, Nn);
    scan_write_kernel<<<nsb, 256, 0, stream>>>(deg, bofs, rowptr, ctr, Nn);
    scatter_kernel<<<eb, 256, 0, stream>>>(ei, flag, ctr, srcs, E_);

    int nb4 = (Nn + 3) / 4;
    int gb = (Nn + 63) / 64;

    // layer 1
    gemm_mfma_kernel<256, false><<<gb, 256, 0, stream>>>(x, Wt1, nullptr, nullptr, nullptr,
                                                         h1b, Nn);
    attn_coef1_kernel<<<nb4, 256, 0, stream>>>(h1b, att_src1, att_dst1, as1, ad1, Nn);
    aggregate1_kernel<<<nb4, 256, 0, stream>>>(h1b, rowptr, srcs, as1, ad1, b1, x2, Nn);
    bn_stats_kernel<256><<<256, 256, 0, stream>>>(x2, bn1, Nn);

    // layer 2 (BN1-apply+ReLU fused into GEMM2's A staging)
    gemm_mfma_kernel<128, true><<<gb, 256, 0, stream>>>(x2, Wt2, bn1, g1, be1, h2b, Nn);
    attn_coef2_kernel<<<nb4, 256, 0, stream>>>(h2b, att_src2, att_dst2, as2, ad2, Nn);
    aggregate2_kernel<<<nb4, 256, 0, stream>>>(h2b, rowptr, srcs, as2, ad2, b2, outf, Nn);
    bn_stats_kernel<128><<<256, 256, 0, stream>>>(outf, bn2, Nn);
    bn_apply_kernel<128><<<512, 256, 0, stream>>>(outf, bn2, g2, be2, Nn);
}

// Round 4
// 427.984 us; speedup vs baseline: 1.7303x; 1.1185x over previous
//
#include <hip/hip_runtime.h>
#include <math.h>

#define IN_DIM 256
#define EPS_BN 1e-5f

typedef __attribute__((ext_vector_type(8))) short short8v;  // 8 bf16 (4 VGPRs)
typedef __attribute__((ext_vector_type(4))) float f32x4;    // MFMA C/D

__device__ __forceinline__ float lrelu(float v) { return v > 0.f ? v : 0.2f * v; }

// bf16 <-> f32 helpers (RNE)
__device__ __forceinline__ unsigned short f2bf(float f) {
    unsigned int u = __float_as_uint(f);
    u += 0x7fffu + ((u >> 16) & 1u);
    return (unsigned short)(u >> 16);
}
__device__ __forceinline__ float bf2f(unsigned short s) {
    return __uint_as_float((unsigned int)s << 16);
}

// async global->LDS, 16B per lane; lds dest must be wave-uniform base (lane*16 implicit)
__device__ __forceinline__ void gld16(const void* g, void* l) {
    __builtin_amdgcn_global_load_lds((const __attribute__((address_space(1))) void*)g,
                                     (__attribute__((address_space(3))) void*)l, 16, 0, 0);
}

// ---------- edge-index dtype detection (int32 vs int64) ----------
__global__ void detect_kernel(const unsigned int* __restrict__ w, int* __restrict__ flag,
                              long long nwords) {
    __shared__ int nz;
    if (threadIdx.x == 0) nz = 0;
    __syncthreads();
    int cnt = 0;
    for (int i = 0; i < 4; i++) {
        long long idx = 2LL * (threadIdx.x + i * 256) + 1;  // odd 32-bit words
        if (idx < nwords && w[idx] != 0u) cnt++;
    }
    if (cnt) atomicAdd(&nz, 1);
    __syncthreads();
    if (threadIdx.x == 0) flag[0] = (nz == 0) ? 1 : 0;  // all-zero odd words -> int64
}

__device__ __forceinline__ int edge_at(const void* ei, int is64, long long i) {
    if (is64) return (int)((const long long*)ei)[i];
    return ((const int*)ei)[i];
}

// ---------- CSR build ----------
__global__ void count_deg_kernel(const void* __restrict__ ei, const int* __restrict__ flag,
                                 int* __restrict__ deg, int E_) {
    int is64 = flag[0];
    int i = blockIdx.x * 256 + threadIdx.x;
    if (i < E_) {
        int d = edge_at(ei, is64, (long long)E_ + i);
        atomicAdd(&deg[d], 1);
    }
}

__global__ __launch_bounds__(256) void scan_partial_kernel(const int* __restrict__ deg,
                                                           int* __restrict__ bsum, int n) {
    __shared__ int sh[256];
    int t = threadIdx.x;
    int i = blockIdx.x * 256 + t;
    sh[t] = (i < n) ? deg[i] : 0;
    __syncthreads();
    for (int off = 128; off >= 1; off >>= 1) {
        if (t < off) sh[t] += sh[t + off];
        __syncthreads();
    }
    if (t == 0) bsum[blockIdx.x] = sh[0];
}

__global__ __launch_bounds__(256) void scan_bsum_kernel(int* __restrict__ bsum,
                                                        int* __restrict__ bofs,
                                                        int* __restrict__ rowptr,
                                                        int nb, int n) {
    __shared__ int sh[256];
    int t = threadIdx.x;
    int v = (t < nb) ? bsum[t] : 0;
    sh[t] = v;
    __syncthreads();
    for (int off = 1; off < 256; off <<= 1) {
        int u = (t >= off) ? sh[t - off] : 0;
        __syncthreads();
        sh[t] += u;
        __syncthreads();
    }
    if (t < nb) bofs[t] = sh[t] - v;  // exclusive
    if (t == 255) rowptr[n] = sh[255];
}

__global__ __launch_bounds__(256) void scan_write_kernel(const int* __restrict__ deg,
                                                         const int* __restrict__ bofs,
                                                         int* __restrict__ rowptr,
                                                         int* __restrict__ ctr, int n) {
    __shared__ int sh[256];
    int t = threadIdx.x;
    int i = blockIdx.x * 256 + t;
    int d = (i < n) ? deg[i] : 0;
    sh[t] = d;
    __syncthreads();
    for (int off = 1; off < 256; off <<= 1) {
        int u = (t >= off) ? sh[t - off] : 0;
        __syncthreads();
        sh[t] += u;
        __syncthreads();
    }
    if (i < n) {
        int v = bofs[blockIdx.x] + sh[t] - d;
        rowptr[i] = v;
        ctr[i] = v;
    }
}

__global__ void scatter_kernel(const void* __restrict__ ei, const int* __restrict__ flag,
                               int* __restrict__ ctr, int* __restrict__ srcs, int E_) {
    int is64 = flag[0];
    int i = blockIdx.x * 256 + threadIdx.x;
    if (i < E_) {
        int s = edge_at(ei, is64, i);
        int d = edge_at(ei, is64, (long long)E_ + i);
        int pos = atomicAdd(&ctr[d], 1);
        srcs[pos] = s;
    }
}

// ---------- W transpose + bf16 cast: Wt[c][k] = bf16(W[k][c]) ----------
__global__ void transpose_cast_kernel(const float* __restrict__ W,
                                      unsigned short* __restrict__ Wt, int K, int Ccols) {
    int idx = blockIdx.x * 256 + threadIdx.x;
    if (idx >= K * Ccols) return;
    int c = idx / K, k = idx % K;
    Wt[idx] = f2bf(W[(long long)k * Ccols + c]);
}

// ---------- f32 -> bf16 bulk cast (8 elems/thread) ----------
__global__ __launch_bounds__(256) void cast_bf16_kernel(const float* __restrict__ in,
                                                        unsigned short* __restrict__ out,
                                                        long long n8) {
    long long i = (long long)blockIdx.x * 256 + threadIdx.x;
    if (i >= n8) return;
    const float4* p = (const float4*)(in + i * 8);
    float4 v0 = p[0], v1 = p[1];
    ushort4 o0, o1;
    o0.x = f2bf(v0.x); o0.y = f2bf(v0.y); o0.z = f2bf(v0.z); o0.w = f2bf(v0.w);
    o1.x = f2bf(v1.x); o1.y = f2bf(v1.y); o1.z = f2bf(v1.z); o1.w = f2bf(v1.w);
    *(ushort4*)(out + i * 8) = o0;
    *(ushort4*)(out + i * 8 + 4) = o1;
}

// ---------- MFMA bf16 GEMM: C[M,NCOL] = Ab[M,256] @ Wt^T, all operands bf16 ----------
// Block: 256 thr = 4 waves; tile 128 rows x 64 cols. B panel [64][256] staged once in LDS,
// A staged per 64-k chunk [128][64]; both via global_load_lds w=16 with pre-swizzled source
// (LDS linear dest) + XOR-swizzled reads: 16B-slot low bits ^= (row&7). <=2-way bank alias.
// Fragment conventions identical to the round-3 verified kernel (16x16x32_bf16).
template <int NCOL>
__global__ __launch_bounds__(256) void gemm_mfma_kernel(const unsigned short* __restrict__ Ab,
                                                        const unsigned short* __restrict__ Wt,
                                                        unsigned short* __restrict__ C, int M) {
    __shared__ unsigned short B_lds[64 * 256];   // 32 KB
    __shared__ unsigned short A_lds[128 * 64];   // 16 KB
    const int t = threadIdx.x;
    const int w = t >> 6, l = t & 63;
    const int row0 = blockIdx.x * 128;
    const int col0 = blockIdx.y * 64;

    // stage B [64 cols][256 k] once
    {
        const char* wb = (const char*)Wt + (size_t)col0 * 512;
#pragma unroll
        for (int it = 0; it < 8; ++it) {
            int q = w * 8 + it;            // wave-chunk 0..31
            int i = q * 64 + l;            // 16B-slot id
            int r = i >> 5;                // B row (col of W)
            int cs = (i & 31) ^ (r & 7);   // involution image
            gld16(wb + (size_t)r * 512 + cs * 16, (char*)B_lds + q * 1024);
        }
    }
    // stage A chunk 0
    const char* ab = (const char*)Ab + (size_t)row0 * 512;
#pragma unroll
    for (int it = 0; it < 4; ++it) {
        int q = w * 4 + it;
        int i = q * 64 + l;
        int r = i >> 3;
        int cs = (i & 7) ^ (r & 7);
        gld16(ab + (size_t)r * 512 + cs * 16, (char*)A_lds + q * 1024);
    }
    __syncthreads();

    const int rl = l & 15, kg = l >> 4;
    f32x4 acc0[4], acc1[4];
#pragma unroll
    for (int i = 0; i < 4; ++i) { acc0[i] = (f32x4)(0.f); acc1[i] = (f32x4)(0.f); }

    const int ar0 = w * 32 + rl, ar1 = ar0 + 16;
    const int aswz = (ar0 & 7) << 4;  // (ar1&7)==(ar0&7)

    for (int c = 0; c < 4; ++c) {
#pragma unroll
        for (int s = 0; s < 2; ++s) {
            short8v a0 = *(const short8v*)((const char*)A_lds +
                          ((ar0 * 128 + s * 64 + kg * 16) ^ aswz));
            short8v a1 = *(const short8v*)((const char*)A_lds +
                          ((ar1 * 128 + s * 64 + kg * 16) ^ aswz));
#pragma unroll
            for (int ct = 0; ct < 4; ++ct) {
                int br = ct * 16 + rl;
                short8v bfr = *(const short8v*)((const char*)B_lds +
                               ((br * 512 + c * 128 + s * 64 + kg * 16) ^ ((br & 7) << 4)));
                acc0[ct] = __builtin_amdgcn_mfma_f32_16x16x32_bf16(a0, bfr, acc0[ct], 0, 0, 0);
                acc1[ct] = __builtin_amdgcn_mfma_f32_16x16x32_bf16(a1, bfr, acc1[ct], 0, 0, 0);
            }
        }
        __syncthreads();
        if (c < 3) {
#pragma unroll
            for (int it = 0; it < 4; ++it) {
                int q = w * 4 + it;
                int i = q * 64 + l;
                int r = i >> 3;
                int cs = (i & 7) ^ (r & 7);
                gld16(ab + (size_t)r * 512 + (c + 1) * 128 + cs * 16, (char*)A_lds + q * 1024);
            }
            __syncthreads();
        }
    }

#pragma unroll
    for (int ct = 0; ct < 4; ++ct) {
#pragma unroll
        for (int r = 0; r < 4; ++r) {
            int gr0 = row0 + w * 32 + kg * 4 + r;
            if (gr0 < M) C[(long long)gr0 * NCOL + col0 + ct * 16 + rl] = f2bf(acc0[ct][r]);
            int gr1 = gr0 + 16;
            if (gr1 < M) C[(long long)gr1 * NCOL + col0 + ct * 16 + rl] = f2bf(acc1[ct][r]);
        }
    }
}

// ---------- attention coefficients (bf16 h) ----------
__global__ __launch_bounds__(256) void attn_coef1_kernel(const unsigned short* __restrict__ h,
                                                         const float* __restrict__ att_src,
                                                         const float* __restrict__ att_dst,
                                                         float* __restrict__ a_s,
                                                         float* __restrict__ a_d, int Nn) {
    int wid = threadIdx.x >> 6, lane = threadIdx.x & 63;
    int n = blockIdx.x * 4 + wid;
    if (n >= Nn) return;
    int col = lane * 4;
    ushort4 hv = *(const ushort4*)&h[(long long)n * 256 + col];
    float h0 = bf2f(hv.x), h1 = bf2f(hv.y), h2 = bf2f(hv.z), h3 = bf2f(hv.w);
    float4 as = *(const float4*)&att_src[col];
    float4 ad = *(const float4*)&att_dst[col];
    float ps = h0 * as.x + h1 * as.y + h2 * as.z + h3 * as.w;
    float pd = h0 * ad.x + h1 * ad.y + h2 * ad.z + h3 * ad.w;
    for (int off = 16; off >= 1; off >>= 1) {
        ps += __shfl_xor(ps, off);
        pd += __shfl_xor(pd, off);
    }
    if ((lane & 31) == 0) {
        int hh = lane >> 5;
        a_s[n * 2 + hh] = ps;
        a_d[n * 2 + hh] = pd;
    }
}

__global__ __launch_bounds__(256) void attn_coef2_kernel(const unsigned short* __restrict__ h,
                                                         const float* __restrict__ att_src,
                                                         const float* __restrict__ att_dst,
                                                         float* __restrict__ a_s,
                                                         float* __restrict__ a_d, int Nn) {
    int wid = threadIdx.x >> 6, lane = threadIdx.x & 63;
    int n = blockIdx.x * 4 + wid;
    if (n >= Nn) return;
    int col = lane * 2;
    unsigned int hv = *(const unsigned int*)&h[(long long)n * 128 + col];
    float h0 = bf2f((unsigned short)(hv & 0xffffu));
    float h1 = bf2f((unsigned short)(hv >> 16));
    float2 as = *(const float2*)&att_src[col];
    float2 ad = *(const float2*)&att_dst[col];
    float ps = h0 * as.x + h1 * as.y;
    float pd = h0 * ad.x + h1 * ad.y;
    for (int off = 32; off >= 1; off >>= 1) {
        ps += __shfl_xor(ps, off);
        pd += __shfl_xor(pd, off);
    }
    if (lane == 0) { a_s[n] = ps; a_d[n] = pd; }
}

// ---------- softmax + aggregation (one wave per dst node) ----------
// layer 1: writes bf16 [N,256]
__global__ __launch_bounds__(256) void aggregate1_kernel(const unsigned short* __restrict__ h,
                                                         const int* __restrict__ rowptr,
                                                         const int* __restrict__ srcs,
                                                         const float* __restrict__ a_s,
                                                         const float* __restrict__ a_d,
                                                         const float* __restrict__ bias,
                                                         unsigned short* __restrict__ out, int Nn) {
    int wid = threadIdx.x >> 6, lane = threadIdx.x & 63;
    int n = blockIdx.x * 4 + wid;
    if (n >= Nn) return;
    int beg = rowptr[n], end = rowptr[n + 1];
    float ad0 = a_d[n * 2 + 0], ad1 = a_d[n * 2 + 1];
    float m0 = -1e30f, m1 = -1e30f;
    for (int j = beg + lane; j < end; j += 64) {
        int s = srcs[j];
        m0 = fmaxf(m0, lrelu(a_s[s * 2 + 0] + ad0));
        m1 = fmaxf(m1, lrelu(a_s[s * 2 + 1] + ad1));
    }
    for (int off = 32; off >= 1; off >>= 1) {
        m0 = fmaxf(m0, __shfl_xor(m0, off));
        m1 = fmaxf(m1, __shfl_xor(m1, off));
    }
    int hh = lane >> 5;
    float mh = hh ? m1 : m0;
    float adh = hh ? ad1 : ad0;
    int col = (hh << 7) + (lane & 31) * 4;
    float4 acc = make_float4(0.f, 0.f, 0.f, 0.f);
    float denom = 0.f;
    int j = beg;
    for (; j + 2 <= end; j += 2) {
        int s0 = srcs[j], s1 = srcs[j + 1];
        float w0 = __expf(lrelu(a_s[s0 * 2 + hh] + adh) - mh);
        float w1 = __expf(lrelu(a_s[s1 * 2 + hh] + adh) - mh);
        ushort4 p0 = *(const ushort4*)&h[(long long)s0 * 256 + col];
        ushort4 p1 = *(const ushort4*)&h[(long long)s1 * 256 + col];
        denom += w0 + w1;
        acc.x += w0 * bf2f(p0.x) + w1 * bf2f(p1.x);
        acc.y += w0 * bf2f(p0.y) + w1 * bf2f(p1.y);
        acc.z += w0 * bf2f(p0.z) + w1 * bf2f(p1.z);
        acc.w += w0 * bf2f(p0.w) + w1 * bf2f(p1.w);
    }
    if (j < end) {
        int s0 = srcs[j];
        float w0 = __expf(lrelu(a_s[s0 * 2 + hh] + adh) - mh);
        ushort4 p0 = *(const ushort4*)&h[(long long)s0 * 256 + col];
        denom += w0;
        acc.x += w0 * bf2f(p0.x);
        acc.y += w0 * bf2f(p0.y);
        acc.z += w0 * bf2f(p0.z);
        acc.w += w0 * bf2f(p0.w);
    }
    float inv = 1.f / (denom + 1e-16f);
    float4 bv = *(const float4*)&bias[col];
    ushort4 ov;
    ov.x = f2bf(acc.x * inv + bv.x);
    ov.y = f2bf(acc.y * inv + bv.y);
    ov.z = f2bf(acc.z * inv + bv.z);
    ov.w = f2bf(acc.w * inv + bv.w);
    *(ushort4*)&out[(long long)n * 256 + col] = ov;
}

__global__ __launch_bounds__(256) void aggregate2_kernel(const unsigned short* __restrict__ h,
                                                         const int* __restrict__ rowptr,
                                                         const int* __restrict__ srcs,
                                                         const float* __restrict__ a_s,
                                                         const float* __restrict__ a_d,
                                                         const float* __restrict__ bias,
                                                         float* __restrict__ out, int Nn) {
    int wid = threadIdx.x >> 6, lane = threadIdx.x & 63;
    int n = blockIdx.x * 4 + wid;
    if (n >= Nn) return;
    int beg = rowptr[n], end = rowptr[n + 1];
    float ad = a_d[n];
    float m = -1e30f;
    for (int j = beg + lane; j < end; j += 64) {
        int s = srcs[j];
        m = fmaxf(m, lrelu(a_s[s] + ad));
    }
    for (int off = 32; off >= 1; off >>= 1) m = fmaxf(m, __shfl_xor(m, off));
    int col = lane * 2;
    float2 acc = make_float2(0.f, 0.f);
    float denom = 0.f;
    int j = beg;
    for (; j + 2 <= end; j += 2) {
        int s0 = srcs[j], s1 = srcs[j + 1];
        float w0 = __expf(lrelu(a_s[s0] + ad) - m);
        float w1 = __expf(lrelu(a_s[s1] + ad) - m);
        unsigned int p0 = *(const unsigned int*)&h[(long long)s0 * 128 + col];
        unsigned int p1 = *(const unsigned int*)&h[(long long)s1 * 128 + col];
        denom += w0 + w1;
        acc.x += w0 * bf2f((unsigned short)(p0 & 0xffffu)) + w1 * bf2f((unsigned short)(p1 & 0xffffu));
        acc.y += w0 * bf2f((unsigned short)(p0 >> 16)) + w1 * bf2f((unsigned short)(p1 >> 16));
    }
    if (j < end) {
        int s0 = srcs[j];
        float w0 = __expf(lrelu(a_s[s0] + ad) - m);
        unsigned int p0 = *(const unsigned int*)&h[(long long)s0 * 128 + col];
        denom += w0;
        acc.x += w0 * bf2f((unsigned short)(p0 & 0xffffu));
        acc.y += w0 * bf2f((unsigned short)(p0 >> 16));
    }
    float inv = 1.f / (denom + 1e-16f);
    out[(long long)n * 128 + col]     = acc.x * inv + bias[col];
    out[(long long)n * 128 + col + 1] = acc.y * inv + bias[col + 1];
}

// ---------- batchnorm ----------
// stats over bf16 [N,256] (2 cols per thread)
__global__ __launch_bounds__(256) void bn_stats_bf16_kernel(const unsigned short* __restrict__ x,
                                                            float* __restrict__ sums, int Nn) {
    int t = threadIdx.x;
    int c2 = (t & 127) * 2;
    int r0 = blockIdx.x * 2 + (t >> 7);
    int rs = gridDim.x * 2;
    float s0 = 0.f, q0 = 0.f, s1 = 0.f, q1 = 0.f;
    for (int r = r0; r < Nn; r += rs) {
        unsigned int v = *(const unsigned int*)&x[(long long)r * 256 + c2];
        float a = bf2f((unsigned short)(v & 0xffffu));
        float b = bf2f((unsigned short)(v >> 16));
        s0 += a; q0 += a * a;
        s1 += b; q1 += b * b;
    }
    atomicAdd(&sums[c2], s0);     atomicAdd(&sums[256 + c2], q0);
    atomicAdd(&sums[c2 + 1], s1); atomicAdd(&sums[256 + c2 + 1], q1);
}

// BN+ReLU applied to bf16 input, bf16 output (for GEMM2's A)
__global__ __launch_bounds__(256) void bn_apply_cast_kernel(const unsigned short* __restrict__ xin,
                                                            const float* __restrict__ sums,
                                                            const float* __restrict__ gamma,
                                                            const float* __restrict__ beta,
                                                            unsigned short* __restrict__ xout,
                                                            int Nn) {
    int t = threadIdx.x;
    int c2 = (t & 127) * 2;
    int r = blockIdx.x * 2 + (t >> 7);
    if (r >= Nn) return;
    float invN = 1.f / (float)Nn;
    float mu0 = sums[c2] * invN;
    float var0 = sums[256 + c2] * invN - mu0 * mu0;
    float sc0 = rsqrtf(var0 + EPS_BN) * gamma[c2];
    float sh0 = beta[c2] - mu0 * sc0;
    float mu1 = sums[c2 + 1] * invN;
    float var1 = sums[256 + c2 + 1] * invN - mu1 * mu1;
    float sc1 = rsqrtf(var1 + EPS_BN) * gamma[c2 + 1];
    float sh1 = beta[c2 + 1] - mu1 * sc1;
    unsigned int v = *(const unsigned int*)&xin[(long long)r * 256 + c2];
    float a = bf2f((unsigned short)(v & 0xffffu));
    float b = bf2f((unsigned short)(v >> 16));
    a = fmaxf(a * sc0 + sh0, 0.f);
    b = fmaxf(b * sc1 + sh1, 0.f);
    unsigned int o = (unsigned int)f2bf(a) | ((unsigned int)f2bf(b) << 16);
    *(unsigned int*)&xout[(long long)r * 256 + c2] = o;
}

template <int CW>
__global__ __launch_bounds__(256) void bn_stats_kernel(const float* __restrict__ x,
                                                       float* __restrict__ sums, int Nn) {
    int t = threadIdx.x;
    int col = t % CW;
    int rpb = 256 / CW;
    int r0 = blockIdx.x * rpb + t / CW;
    int rs = gridDim.x * rpb;
    float s = 0.f, q = 0.f;
    for (int r = r0; r < Nn; r += rs) {
        float v = x[(long long)r * CW + col];
        s += v; q += v * v;
    }
    atomicAdd(&sums[col], s);
    atomicAdd(&sums[CW + col], q);
}

template <int CW>
__global__ __launch_bounds__(256) void bn_apply_kernel(float* __restrict__ x,
                                                       const float* __restrict__ sums,
                                                       const float* __restrict__ gamma,
                                                       const float* __restrict__ beta, int Nn) {
    int t = threadIdx.x;
    int col = t % CW;
    float mu = sums[col] / (float)Nn;
    float var = sums[CW + col] / (float)Nn - mu * mu;
    float sc = rsqrtf(var + EPS_BN) * gamma[col];
    float sh = beta[col] - mu * sc;
    int rpb = 256 / CW;
    int r0 = blockIdx.x * rpb + t / CW;
    int rs = gridDim.x * rpb;
    for (int r = r0; r < Nn; r += rs) {
        long long idx = (long long)r * CW + col;
        float v = x[idx] * sc + sh;
        x[idx] = fmaxf(v, 0.f);
    }
}

extern "C" void kernel_launch(void* const* d_in, const int* in_sizes, int n_in,
                              void* d_out, int out_size, void* d_ws, size_t ws_size,
                              hipStream_t stream) {
    const float* x        = (const float*)d_in[0];
    const void*  ei       = d_in[1];
    const float* W1       = (const float*)d_in[2];
    const float* att_src1 = (const float*)d_in[3];
    const float* att_dst1 = (const float*)d_in[4];
    const float* b1       = (const float*)d_in[5];
    const float* g1       = (const float*)d_in[6];
    const float* be1      = (const float*)d_in[7];
    const float* W2       = (const float*)d_in[8];
    const float* att_src2 = (const float*)d_in[9];
    const float* att_dst2 = (const float*)d_in[10];
    const float* b2       = (const float*)d_in[11];
    const float* g2       = (const float*)d_in[12];
    const float* be2      = (const float*)d_in[13];

    const int Nn = in_sizes[0] / IN_DIM;  // 50000
    const int E_ = in_sizes[1] / 2;       // 800000
    const int gb = (Nn + 127) / 128;      // 391 row-blocks
    const int Mpad = gb * 128 + 128;      // slack rows for OOB tile staging

    char* ws = (char*)d_ws;
    size_t o = 0;
    auto alloc = [&](size_t bytes) {
        size_t r = o;
        o += (bytes + 255) & ~(size_t)255;
        return r;
    };
    int*   flag   = (int*)(ws + alloc(4));
    int*   deg    = (int*)(ws + alloc((size_t)Nn * 4));
    int*   rowptr = (int*)(ws + alloc((size_t)(Nn + 1) * 4));
    int*   ctr    = (int*)(ws + alloc((size_t)Nn * 4));
    int*   srcs   = (int*)(ws + alloc((size_t)E_ * 4));
    int*   bsum   = (int*)(ws + alloc(256 * 4));
    int*   bofs   = (int*)(ws + alloc(256 * 4));
    float* as1    = (float*)(ws + alloc((size_t)Nn * 2 * 4));
    float* ad1    = (float*)(ws + alloc((size_t)Nn * 2 * 4));
    float* as2    = (float*)(ws + alloc((size_t)Nn * 4));
    float* ad2    = (float*)(ws + alloc((size_t)Nn * 4));
    float* bn1    = (float*)(ws + alloc(512 * 4));
    float* bn2    = (float*)(ws + alloc(256 * 4));
    unsigned short* Wt1  = (unsigned short*)(ws + alloc((size_t)256 * 256 * 2));
    unsigned short* Wt2  = (unsigned short*)(ws + alloc((size_t)128 * 256 * 2));
    unsigned short* xb   = (unsigned short*)(ws + alloc((size_t)Mpad * 256 * 2));  // bf16(x)
    unsigned short* x2b0 = (unsigned short*)(ws + alloc((size_t)Nn * 256 * 2));    // agg1 out
    unsigned short* x2b  = (unsigned short*)(ws + alloc((size_t)Mpad * 256 * 2));  // post-BN1
    unsigned short* h1b  = (unsigned short*)(ws + alloc((size_t)Nn * 256 * 2));
    unsigned short* h2b  = (unsigned short*)(ws + alloc((size_t)Nn * 128 * 2));
    float* outf   = (float*)d_out;

    hipMemsetAsync(deg, 0, (size_t)Nn * 4, stream);
    hipMemsetAsync(bn1, 0, 512 * 4, stream);
    hipMemsetAsync(bn2, 0, 256 * 4, stream);

    transpose_cast_kernel<<<(256 * 256 + 255) / 256, 256, 0, stream>>>(W1, Wt1, 256, 256);
    transpose_cast_kernel<<<(128 * 256 + 255) / 256, 256, 0, stream>>>(W2, Wt2, 256, 128);
    {
        long long n8 = (long long)Nn * 256 / 8;
        cast_bf16_kernel<<<(int)((n8 + 255) / 256), 256, 0, stream>>>(x, xb, n8);
    }

    detect_kernel<<<1, 256, 0, stream>>>((const unsigned int*)ei, flag, (long long)2 * E_);
    int eb = (E_ + 255) / 256;
    int nsb = (Nn + 255) / 256;  // <= 256
    count_deg_kernel<<<eb, 256, 0, stream>>>(ei, flag, deg, E_);
    scan_partial_kernel<<<nsb, 256, 0, stream>>>(deg, bsum, Nn);
    scan_bsum_kernel<<<1, 256, 0, stream>>>(bsum, bofs, rowptr, nsb, Nn);
    scan_write_kernel<<<nsb, 256, 0, stream>>>(deg, bofs, rowptr, ctr, Nn);
    scatter_kernel<<<eb, 256, 0, stream>>>(ei, flag, ctr, srcs, E_);

    int nb4 = (Nn + 3) / 4;
    int nr2 = (Nn + 1) / 2;

    // layer 1
    gemm_mfma_kernel<256><<<dim3(gb, 4), 256, 0, stream>>>(xb, Wt1, h1b, Nn);
    attn_coef1_kernel<<<nb4, 256, 0, stream>>>(h1b, att_src1, att_dst1, as1, ad1, Nn);
    aggregate1_kernel<<<nb4, 256, 0, stream>>>(h1b, rowptr, srcs, as1, ad1, b1, x2b0, Nn);
    bn_stats_bf16_kernel<<<256, 256, 0, stream>>>(x2b0, bn1, Nn);
    bn_apply_cast_kernel<<<nr2, 256, 0, stream>>>(x2b0, bn1, g1, be1, x2b, Nn);

    // layer 2
    gemm_mfma_kernel<128><<<dim3(gb, 2), 256, 0, stream>>>(x2b, Wt2, h2b, Nn);
    attn_coef2_kernel<<<nb4, 256, 0, stream>>>(h2b, att_src2, att_dst2, as2, ad2, Nn);
    aggregate2_kernel<<<nb4, 256, 0, stream>>>(h2b, rowptr, srcs, as2, ad2, b2, outf, Nn);
    bn_stats_kernel<128><<<256, 256, 0, stream>>>(outf, bn2, Nn);
    bn_apply_kernel<128><<<512, 256, 0, stream>>>(outf, bn2, g2, be2, Nn);
}

// Round 5
// 396.573 us; speedup vs baseline: 1.8673x; 1.0792x over previous
//
#include <hip/hip_runtime.h>
#include <math.h>

#define IN_DIM 256
#define EPS_BN 1e-5f

typedef __attribute__((ext_vector_type(8))) short short8v;  // 8 bf16 (4 VGPRs)
typedef __attribute__((ext_vector_type(4))) float f32x4;    // MFMA C/D

__device__ __forceinline__ float lrelu(float v) { return v > 0.f ? v : 0.2f * v; }

// bf16 <-> f32 helpers (RNE)
__device__ __forceinline__ unsigned short f2bf(float f) {
    unsigned int u = __float_as_uint(f);
    u += 0x7fffu + ((u >> 16) & 1u);
    return (unsigned short)(u >> 16);
}
__device__ __forceinline__ float bf2f(unsigned short s) {
    return __uint_as_float((unsigned int)s << 16);
}

// async global->LDS, 16B per lane; lds dest must be wave-uniform base (lane*16 implicit)
__device__ __forceinline__ void gld16(const void* g, void* l) {
    __builtin_amdgcn_global_load_lds((const __attribute__((address_space(1))) void*)g,
                                     (__attribute__((address_space(3))) void*)l, 16, 0, 0);
}

// ---------- edge-index dtype detection (int32 vs int64) ----------
__global__ void detect_kernel(const unsigned int* __restrict__ w, int* __restrict__ flag,
                              long long nwords) {
    __shared__ int nz;
    if (threadIdx.x == 0) nz = 0;
    __syncthreads();
    int cnt = 0;
    for (int i = 0; i < 4; i++) {
        long long idx = 2LL * (threadIdx.x + i * 256) + 1;  // odd 32-bit words
        if (idx < nwords && w[idx] != 0u) cnt++;
    }
    if (cnt) atomicAdd(&nz, 1);
    __syncthreads();
    if (threadIdx.x == 0) flag[0] = (nz == 0) ? 1 : 0;  // all-zero odd words -> int64
}

__device__ __forceinline__ int edge_at(const void* ei, int is64, long long i) {
    if (is64) return (int)((const long long*)ei)[i];
    return ((const int*)ei)[i];
}

// ---------- CSR build ----------
__global__ void count_deg_kernel(const void* __restrict__ ei, const int* __restrict__ flag,
                                 int* __restrict__ deg, int E_) {
    int is64 = flag[0];
    int i = blockIdx.x * 256 + threadIdx.x;
    if (i < E_) {
        int d = edge_at(ei, is64, (long long)E_ + i);
        atomicAdd(&deg[d], 1);
    }
}

__global__ __launch_bounds__(256) void scan_partial_kernel(const int* __restrict__ deg,
                                                           int* __restrict__ bsum, int n) {
    __shared__ int sh[256];
    int t = threadIdx.x;
    int i = blockIdx.x * 256 + t;
    sh[t] = (i < n) ? deg[i] : 0;
    __syncthreads();
    for (int off = 128; off >= 1; off >>= 1) {
        if (t < off) sh[t] += sh[t + off];
        __syncthreads();
    }
    if (t == 0) bsum[blockIdx.x] = sh[0];
}

__global__ __launch_bounds__(256) void scan_bsum_kernel(int* __restrict__ bsum,
                                                        int* __restrict__ bofs,
                                                        int* __restrict__ rowptr,
                                                        int nb, int n) {
    __shared__ int sh[256];
    int t = threadIdx.x;
    int v = (t < nb) ? bsum[t] : 0;
    sh[t] = v;
    __syncthreads();
    for (int off = 1; off < 256; off <<= 1) {
        int u = (t >= off) ? sh[t - off] : 0;
        __syncthreads();
        sh[t] += u;
        __syncthreads();
    }
    if (t < nb) bofs[t] = sh[t] - v;  // exclusive
    if (t == 255) rowptr[n] = sh[255];
}

__global__ __launch_bounds__(256) void scan_write_kernel(const int* __restrict__ deg,
                                                         const int* __restrict__ bofs,
                                                         int* __restrict__ rowptr,
                                                         int* __restrict__ ctr, int n) {
    __shared__ int sh[256];
    int t = threadIdx.x;
    int i = blockIdx.x * 256 + t;
    int d = (i < n) ? deg[i] : 0;
    sh[t] = d;
    __syncthreads();
    for (int off = 1; off < 256; off <<= 1) {
        int u = (t >= off) ? sh[t - off] : 0;
        __syncthreads();
        sh[t] += u;
        __syncthreads();
    }
    if (i < n) {
        int v = bofs[blockIdx.x] + sh[t] - d;
        rowptr[i] = v;
        ctr[i] = v;
    }
}

__global__ void scatter_kernel(const void* __restrict__ ei, const int* __restrict__ flag,
                               int* __restrict__ ctr, int* __restrict__ srcs, int E_) {
    int is64 = flag[0];
    int i = blockIdx.x * 256 + threadIdx.x;
    if (i < E_) {
        int s = edge_at(ei, is64, i);
        int d = edge_at(ei, is64, (long long)E_ + i);
        int pos = atomicAdd(&ctr[d], 1);
        srcs[pos] = s;
    }
}

// ---------- W transpose + bf16 cast: Wt[c][k] = bf16(W[k][c]) ----------
__global__ void transpose_cast_kernel(const float* __restrict__ W,
                                      unsigned short* __restrict__ Wt, int K, int Ccols) {
    int idx = blockIdx.x * 256 + threadIdx.x;
    if (idx >= K * Ccols) return;
    int c = idx / K, k = idx % K;
    Wt[idx] = f2bf(W[(long long)k * Ccols + c]);
}

// ---------- f32 -> bf16 bulk cast (8 elems/thread) ----------
__global__ __launch_bounds__(256) void cast_bf16_kernel(const float* __restrict__ in,
                                                        unsigned short* __restrict__ out,
                                                        long long n8) {
    long long i = (long long)blockIdx.x * 256 + threadIdx.x;
    if (i >= n8) return;
    const float4* p = (const float4*)(in + i * 8);
    float4 v0 = p[0], v1 = p[1];
    ushort4 o0, o1;
    o0.x = f2bf(v0.x); o0.y = f2bf(v0.y); o0.z = f2bf(v0.z); o0.w = f2bf(v0.w);
    o1.x = f2bf(v1.x); o1.y = f2bf(v1.y); o1.z = f2bf(v1.z); o1.w = f2bf(v1.w);
    *(ushort4*)(out + i * 8) = o0;
    *(ushort4*)(out + i * 8 + 4) = o1;
}

// ---------- MFMA bf16 GEMM: C[M,NCOL] = Ab[M,256] @ Wt^T, all operands bf16 ----------
template <int NCOL>
__global__ __launch_bounds__(256) void gemm_mfma_kernel(const unsigned short* __restrict__ Ab,
                                                        const unsigned short* __restrict__ Wt,
                                                        unsigned short* __restrict__ C, int M) {
    __shared__ unsigned short B_lds[64 * 256];   // 32 KB
    __shared__ unsigned short A_lds[128 * 64];   // 16 KB
    const int t = threadIdx.x;
    const int w = t >> 6, l = t & 63;
    const int row0 = blockIdx.x * 128;
    const int col0 = blockIdx.y * 64;

    // stage B [64 cols][256 k] once
    {
        const char* wb = (const char*)Wt + (size_t)col0 * 512;
#pragma unroll
        for (int it = 0; it < 8; ++it) {
            int q = w * 8 + it;            // wave-chunk 0..31
            int i = q * 64 + l;            // 16B-slot id
            int r = i >> 5;                // B row (col of W)
            int cs = (i & 31) ^ (r & 7);   // involution image
            gld16(wb + (size_t)r * 512 + cs * 16, (char*)B_lds + q * 1024);
        }
    }
    // stage A chunk 0
    const char* ab = (const char*)Ab + (size_t)row0 * 512;
#pragma unroll
    for (int it = 0; it < 4; ++it) {
        int q = w * 4 + it;
        int i = q * 64 + l;
        int r = i >> 3;
        int cs = (i & 7) ^ (r & 7);
        gld16(ab + (size_t)r * 512 + cs * 16, (char*)A_lds + q * 1024);
    }
    __syncthreads();

    const int rl = l & 15, kg = l >> 4;
    f32x4 acc0[4], acc1[4];
#pragma unroll
    for (int i = 0; i < 4; ++i) { acc0[i] = (f32x4)(0.f); acc1[i] = (f32x4)(0.f); }

    const int ar0 = w * 32 + rl, ar1 = ar0 + 16;
    const int aswz = (ar0 & 7) << 4;  // (ar1&7)==(ar0&7)

    for (int c = 0; c < 4; ++c) {
#pragma unroll
        for (int s = 0; s < 2; ++s) {
            short8v a0 = *(const short8v*)((const char*)A_lds +
                          ((ar0 * 128 + s * 64 + kg * 16) ^ aswz));
            short8v a1 = *(const short8v*)((const char*)A_lds +
                          ((ar1 * 128 + s * 64 + kg * 16) ^ aswz));
#pragma unroll
            for (int ct = 0; ct < 4; ++ct) {
                int br = ct * 16 + rl;
                short8v bfr = *(const short8v*)((const char*)B_lds +
                               ((br * 512 + c * 128 + s * 64 + kg * 16) ^ ((br & 7) << 4)));
                acc0[ct] = __builtin_amdgcn_mfma_f32_16x16x32_bf16(a0, bfr, acc0[ct], 0, 0, 0);
                acc1[ct] = __builtin_amdgcn_mfma_f32_16x16x32_bf16(a1, bfr, acc1[ct], 0, 0, 0);
            }
        }
        __syncthreads();
        if (c < 3) {
#pragma unroll
            for (int it = 0; it < 4; ++it) {
                int q = w * 4 + it;
                int i = q * 64 + l;
                int r = i >> 3;
                int cs = (i & 7) ^ (r & 7);
                gld16(ab + (size_t)r * 512 + (c + 1) * 128 + cs * 16, (char*)A_lds + q * 1024);
            }
            __syncthreads();
        }
    }

#pragma unroll
    for (int ct = 0; ct < 4; ++ct) {
#pragma unroll
        for (int r = 0; r < 4; ++r) {
            int gr0 = row0 + w * 32 + kg * 4 + r;
            if (gr0 < M) C[(long long)gr0 * NCOL + col0 + ct * 16 + rl] = f2bf(acc0[ct][r]);
            int gr1 = gr0 + 16;
            if (gr1 < M) C[(long long)gr1 * NCOL + col0 + ct * 16 + rl] = f2bf(acc1[ct][r]);
        }
    }
}

// ---------- attention coefficients (bf16 h) ----------
__global__ __launch_bounds__(256) void attn_coef1_kernel(const unsigned short* __restrict__ h,
                                                         const float* __restrict__ att_src,
                                                         const float* __restrict__ att_dst,
                                                         float* __restrict__ a_s,
                                                         float* __restrict__ a_d, int Nn) {
    int wid = threadIdx.x >> 6, lane = threadIdx.x & 63;
    int n = blockIdx.x * 4 + wid;
    if (n >= Nn) return;
    int col = lane * 4;
    ushort4 hv = *(const ushort4*)&h[(long long)n * 256 + col];
    float h0 = bf2f(hv.x), h1 = bf2f(hv.y), h2 = bf2f(hv.z), h3 = bf2f(hv.w);
    float4 as = *(const float4*)&att_src[col];
    float4 ad = *(const float4*)&att_dst[col];
    float ps = h0 * as.x + h1 * as.y + h2 * as.z + h3 * as.w;
    float pd = h0 * ad.x + h1 * ad.y + h2 * ad.z + h3 * ad.w;
    for (int off = 16; off >= 1; off >>= 1) {
        ps += __shfl_xor(ps, off);
        pd += __shfl_xor(pd, off);
    }
    if ((lane & 31) == 0) {
        int hh = lane >> 5;
        a_s[n * 2 + hh] = ps;
        a_d[n * 2 + hh] = pd;
    }
}

__global__ __launch_bounds__(256) void attn_coef2_kernel(const unsigned short* __restrict__ h,
                                                         const float* __restrict__ att_src,
                                                         const float* __restrict__ att_dst,
                                                         float* __restrict__ a_s,
                                                         float* __restrict__ a_d, int Nn) {
    int wid = threadIdx.x >> 6, lane = threadIdx.x & 63;
    int n = blockIdx.x * 4 + wid;
    if (n >= Nn) return;
    int col = lane * 2;
    unsigned int hv = *(const unsigned int*)&h[(long long)n * 128 + col];
    float h0 = bf2f((unsigned short)(hv & 0xffffu));
    float h1 = bf2f((unsigned short)(hv >> 16));
    float2 as = *(const float2*)&att_src[col];
    float2 ad = *(const float2*)&att_dst[col];
    float ps = h0 * as.x + h1 * as.y;
    float pd = h0 * ad.x + h1 * ad.y;
    for (int off = 32; off >= 1; off >>= 1) {
        ps += __shfl_xor(ps, off);
        pd += __shfl_xor(pd, off);
    }
    if (lane == 0) { a_s[n] = ps; a_d[n] = pd; }
}

// ---------- softmax + aggregation: one wave per dst node, online softmax ----------
// Per 64-edge chunk: lane e owns edge cb+e (coalesced srcs read, one 8B a_s gather,
// one exp per head). Payload loop broadcasts s/w via __shfl (uniform idx -> readlane).
__global__ __launch_bounds__(256) void aggregate1_kernel(const unsigned short* __restrict__ h,
                                                         const int* __restrict__ rowptr,
                                                         const int* __restrict__ srcs,
                                                         const float* __restrict__ a_s,
                                                         const float* __restrict__ a_d,
                                                         const float* __restrict__ bias,
                                                         unsigned short* __restrict__ out, int Nn) {
    int wid = threadIdx.x >> 6, lane = threadIdx.x & 63;
    int n = blockIdx.x * 4 + wid;
    if (n >= Nn) return;
    int beg = rowptr[n], end = rowptr[n + 1];
    float ad0 = a_d[n * 2 + 0], ad1 = a_d[n * 2 + 1];
    int hh = lane >> 5;
    int col = (hh << 7) + (lane & 31) * 4;
    float4 acc = make_float4(0.f, 0.f, 0.f, 0.f);
    float den = 0.f;
    float m0 = -1e30f, m1 = -1e30f;

    for (int cb = beg; cb < end; cb += 64) {
        int cnt = end - cb; if (cnt > 64) cnt = 64;
        int s_l = 0;
        float e0 = -1e30f, e1 = -1e30f;
        if (lane < cnt) {
            s_l = srcs[cb + lane];
            float2 av = *(const float2*)&a_s[s_l * 2];
            e0 = lrelu(av.x + ad0);
            e1 = lrelu(av.y + ad1);
        }
        float cm0 = e0, cm1 = e1;
        for (int off = 32; off >= 1; off >>= 1) {
            cm0 = fmaxf(cm0, __shfl_xor(cm0, off));
            cm1 = fmaxf(cm1, __shfl_xor(cm1, off));
        }
        float f0 = 1.f, f1 = 1.f;
        if (cm0 > m0) { f0 = __expf(m0 - cm0); m0 = cm0; }
        if (cm1 > m1) { f1 = __expf(m1 - cm1); m1 = cm1; }
        float fo = hh ? f1 : f0;
        acc.x *= fo; acc.y *= fo; acc.z *= fo; acc.w *= fo;
        den *= fo;
        // per-edge weights, computed once by owning lane
        float w0 = __expf(e0 - m0);   // e0=-1e30 -> 0 for invalid lanes
        float w1 = __expf(e1 - m1);

        int c = 0;
        for (; c + 2 <= cnt; c += 2) {
            int sA = __shfl(s_l, c), sB = __shfl(s_l, c + 1);
            float w0A = __shfl(w0, c), w1A = __shfl(w1, c);
            float w0B = __shfl(w0, c + 1), w1B = __shfl(w1, c + 1);
            float wA = hh ? w1A : w0A;
            float wB = hh ? w1B : w0B;
            ushort4 pA = *(const ushort4*)&h[(long long)sA * 256 + col];
            ushort4 pB = *(const ushort4*)&h[(long long)sB * 256 + col];
            den += wA + wB;
            acc.x += wA * bf2f(pA.x) + wB * bf2f(pB.x);
            acc.y += wA * bf2f(pA.y) + wB * bf2f(pB.y);
            acc.z += wA * bf2f(pA.z) + wB * bf2f(pB.z);
            acc.w += wA * bf2f(pA.w) + wB * bf2f(pB.w);
        }
        if (c < cnt) {
            int sA = __shfl(s_l, c);
            float w0A = __shfl(w0, c), w1A = __shfl(w1, c);
            float wA = hh ? w1A : w0A;
            ushort4 pA = *(const ushort4*)&h[(long long)sA * 256 + col];
            den += wA;
            acc.x += wA * bf2f(pA.x);
            acc.y += wA * bf2f(pA.y);
            acc.z += wA * bf2f(pA.z);
            acc.w += wA * bf2f(pA.w);
        }
    }

    float inv = 1.f / (den + 1e-16f);
    float4 bv = *(const float4*)&bias[col];
    ushort4 ov;
    ov.x = f2bf(acc.x * inv + bv.x);
    ov.y = f2bf(acc.y * inv + bv.y);
    ov.z = f2bf(acc.z * inv + bv.z);
    ov.w = f2bf(acc.w * inv + bv.w);
    *(ushort4*)&out[(long long)n * 256 + col] = ov;
}

__global__ __launch_bounds__(256) void aggregate2_kernel(const unsigned short* __restrict__ h,
                                                         const int* __restrict__ rowptr,
                                                         const int* __restrict__ srcs,
                                                         const float* __restrict__ a_s,
                                                         const float* __restrict__ a_d,
                                                         const float* __restrict__ bias,
                                                         float* __restrict__ out, int Nn) {
    int wid = threadIdx.x >> 6, lane = threadIdx.x & 63;
    int n = blockIdx.x * 4 + wid;
    if (n >= Nn) return;
    int beg = rowptr[n], end = rowptr[n + 1];
    float ad = a_d[n];
    int col = lane * 2;
    float2 acc = make_float2(0.f, 0.f);
    float den = 0.f;
    float m = -1e30f;

    for (int cb = beg; cb < end; cb += 64) {
        int cnt = end - cb; if (cnt > 64) cnt = 64;
        int s_l = 0;
        float e = -1e30f;
        if (lane < cnt) {
            s_l = srcs[cb + lane];
            e = lrelu(a_s[s_l] + ad);
        }
        float cm = e;
        for (int off = 32; off >= 1; off >>= 1) cm = fmaxf(cm, __shfl_xor(cm, off));
        if (cm > m) {
            float f = __expf(m - cm);
            m = cm;
            acc.x *= f; acc.y *= f; den *= f;
        }
        float wv = __expf(e - m);

        int c = 0;
        for (; c + 2 <= cnt; c += 2) {
            int sA = __shfl(s_l, c), sB = __shfl(s_l, c + 1);
            float wA = __shfl(wv, c), wB = __shfl(wv, c + 1);
            unsigned int pA = *(const unsigned int*)&h[(long long)sA * 128 + col];
            unsigned int pB = *(const unsigned int*)&h[(long long)sB * 128 + col];
            den += wA + wB;
            acc.x += wA * bf2f((unsigned short)(pA & 0xffffu)) + wB * bf2f((unsigned short)(pB & 0xffffu));
            acc.y += wA * bf2f((unsigned short)(pA >> 16)) + wB * bf2f((unsigned short)(pB >> 16));
        }
        if (c < cnt) {
            int sA = __shfl(s_l, c);
            float wA = __shfl(wv, c);
            unsigned int pA = *(const unsigned int*)&h[(long long)sA * 128 + col];
            den += wA;
            acc.x += wA * bf2f((unsigned short)(pA & 0xffffu));
            acc.y += wA * bf2f((unsigned short)(pA >> 16));
        }
    }

    float inv = 1.f / (den + 1e-16f);
    out[(long long)n * 128 + col]     = acc.x * inv + bias[col];
    out[(long long)n * 128 + col + 1] = acc.y * inv + bias[col + 1];
}

// ---------- batchnorm ----------
__global__ __launch_bounds__(256) void bn_stats_bf16_kernel(const unsigned short* __restrict__ x,
                                                            float* __restrict__ sums, int Nn) {
    int t = threadIdx.x;
    int c2 = (t & 127) * 2;
    int r0 = blockIdx.x * 2 + (t >> 7);
    int rs = gridDim.x * 2;
    float s0 = 0.f, q0 = 0.f, s1 = 0.f, q1 = 0.f;
    for (int r = r0; r < Nn; r += rs) {
        unsigned int v = *(const unsigned int*)&x[(long long)r * 256 + c2];
        float a = bf2f((unsigned short)(v & 0xffffu));
        float b = bf2f((unsigned short)(v >> 16));
        s0 += a; q0 += a * a;
        s1 += b; q1 += b * b;
    }
    atomicAdd(&sums[c2], s0);     atomicAdd(&sums[256 + c2], q0);
    atomicAdd(&sums[c2 + 1], s1); atomicAdd(&sums[256 + c2 + 1], q1);
}

__global__ __launch_bounds__(256) void bn_apply_cast_kernel(const unsigned short* __restrict__ xin,
                                                            const float* __restrict__ sums,
                                                            const float* __restrict__ gamma,
                                                            const float* __restrict__ beta,
                                                            unsigned short* __restrict__ xout,
                                                            int Nn) {
    int t = threadIdx.x;
    int c2 = (t & 127) * 2;
    int r = blockIdx.x * 2 + (t >> 7);
    if (r >= Nn) return;
    float invN = 1.f / (float)Nn;
    float mu0 = sums[c2] * invN;
    float var0 = sums[256 + c2] * invN - mu0 * mu0;
    float sc0 = rsqrtf(var0 + EPS_BN) * gamma[c2];
    float sh0 = beta[c2] - mu0 * sc0;
    float mu1 = sums[c2 + 1] * invN;
    float var1 = sums[256 + c2 + 1] * invN - mu1 * mu1;
    float sc1 = rsqrtf(var1 + EPS_BN) * gamma[c2 + 1];
    float sh1 = beta[c2 + 1] - mu1 * sc1;
    unsigned int v = *(const unsigned int*)&xin[(long long)r * 256 + c2];
    float a = bf2f((unsigned short)(v & 0xffffu));
    float b = bf2f((unsigned short)(v >> 16));
    a = fmaxf(a * sc0 + sh0, 0.f);
    b = fmaxf(b * sc1 + sh1, 0.f);
    unsigned int o = (unsigned int)f2bf(a) | ((unsigned int)f2bf(b) << 16);
    *(unsigned int*)&xout[(long long)r * 256 + c2] = o;
}

template <int CW>
__global__ __launch_bounds__(256) void bn_stats_kernel(const float* __restrict__ x,
                                                       float* __restrict__ sums, int Nn) {
    int t = threadIdx.x;
    int col = t % CW;
    int rpb = 256 / CW;
    int r0 = blockIdx.x * rpb + t / CW;
    int rs = gridDim.x * rpb;
    float s = 0.f, q = 0.f;
    for (int r = r0; r < Nn; r += rs) {
        float v = x[(long long)r * CW + col];
        s += v; q += v * v;
    }
    atomicAdd(&sums[col], s);
    atomicAdd(&sums[CW + col], q);
}

template <int CW>
__global__ __launch_bounds__(256) void bn_apply_kernel(float* __restrict__ x,
                                                       const float* __restrict__ sums,
                                                       const float* __restrict__ gamma,
                                                       const float* __restrict__ beta, int Nn) {
    int t = threadIdx.x;
    int col = t % CW;
    float mu = sums[col] / (float)Nn;
    float var = sums[CW + col] / (float)Nn - mu * mu;
    float sc = rsqrtf(var + EPS_BN) * gamma[col];
    float sh = beta[col] - mu * sc;
    int rpb = 256 / CW;
    int r0 = blockIdx.x * rpb + t / CW;
    int rs = gridDim.x * rpb;
    for (int r = r0; r < Nn; r += rs) {
        long long idx = (long long)r * CW + col;
        float v = x[idx] * sc + sh;
        x[idx] = fmaxf(v, 0.f);
    }
}

extern "C" void kernel_launch(void* const* d_in, const int* in_sizes, int n_in,
                              void* d_out, int out_size, void* d_ws, size_t ws_size,
                              hipStream_t stream) {
    const float* x        = (const float*)d_in[0];
    const void*  ei       = d_in[1];
    const float* W1       = (const float*)d_in[2];
    const float* att_src1 = (const float*)d_in[3];
    const float* att_dst1 = (const float*)d_in[4];
    const float* b1       = (const float*)d_in[5];
    const float* g1       = (const float*)d_in[6];
    const float* be1      = (const float*)d_in[7];
    const float* W2       = (const float*)d_in[8];
    const float* att_src2 = (const float*)d_in[9];
    const float* att_dst2 = (const float*)d_in[10];
    const float* b2       = (const float*)d_in[11];
    const float* g2       = (const float*)d_in[12];
    const float* be2      = (const float*)d_in[13];

    const int Nn = in_sizes[0] / IN_DIM;  // 50000
    const int E_ = in_sizes[1] / 2;       // 800000
    const int gb = (Nn + 127) / 128;      // 391 row-blocks
    const int Mpad = gb * 128 + 128;      // slack rows for OOB tile staging

    char* ws = (char*)d_ws;
    size_t o = 0;
    auto alloc = [&](size_t bytes) {
        size_t r = o;
        o += (bytes + 255) & ~(size_t)255;
        return r;
    };
    int*   flag   = (int*)(ws + alloc(4));
    int*   deg    = (int*)(ws + alloc((size_t)Nn * 4));
    int*   rowptr = (int*)(ws + alloc((size_t)(Nn + 1) * 4));
    int*   ctr    = (int*)(ws + alloc((size_t)Nn * 4));
    int*   srcs   = (int*)(ws + alloc((size_t)E_ * 4));
    int*   bsum   = (int*)(ws + alloc(256 * 4));
    int*   bofs   = (int*)(ws + alloc(256 * 4));
    float* as1    = (float*)(ws + alloc((size_t)Nn * 2 * 4));
    float* ad1    = (float*)(ws + alloc((size_t)Nn * 2 * 4));
    float* as2    = (float*)(ws + alloc((size_t)Nn * 4));
    float* ad2    = (float*)(ws + alloc((size_t)Nn * 4));
    float* bn1    = (float*)(ws + alloc(512 * 4));
    float* bn2    = (float*)(ws + alloc(256 * 4));
    unsigned short* Wt1  = (unsigned short*)(ws + alloc((size_t)256 * 256 * 2));
    unsigned short* Wt2  = (unsigned short*)(ws + alloc((size_t)128 * 256 * 2));
    unsigned short* xb   = (unsigned short*)(ws + alloc((size_t)Mpad * 256 * 2));  // bf16(x)
    unsigned short* x2b0 = (unsigned short*)(ws + alloc((size_t)Nn * 256 * 2));    // agg1 out
    unsigned short* x2b  = (unsigned short*)(ws + alloc((size_t)Mpad * 256 * 2));  // post-BN1
    unsigned short* h1b  = (unsigned short*)(ws + alloc((size_t)Nn * 256 * 2));
    unsigned short* h2b  = (unsigned short*)(ws + alloc((size_t)Nn * 128 * 2));
    float* outf   = (float*)d_out;

    hipMemsetAsync(deg, 0, (size_t)Nn * 4, stream);
    hipMemsetAsync(bn1, 0, 512 * 4, stream);
    hipMemsetAsync(bn2, 0, 256 * 4, stream);

    transpose_cast_kernel<<<(256 * 256 + 255) / 256, 256, 0, stream>>>(W1, Wt1, 256, 256);
    transpose_cast_kernel<<<(128 * 256 + 255) / 256, 256, 0, stream>>>(W2, Wt2, 256, 128);
    {
        long long n8 = (long long)Nn * 256 / 8;
        cast_bf16_kernel<<<(int)((n8 + 255) / 256), 256, 0, stream>>>(x, xb, n8);
    }

    detect_kernel<<<1, 256, 0, stream>>>((const unsigned int*)ei, flag, (long long)2 * E_);
    int eb = (E_ + 255) / 256;
    int nsb = (Nn + 255) / 256;  // <= 256
    count_deg_kernel<<<eb, 256, 0, stream>>>(ei, flag, deg, E_);
    scan_partial_kernel<<<nsb, 256, 0, stream>>>(deg, bsum, Nn);
    scan_bsum_kernel<<<1, 256, 0, stream>>>(bsum, bofs, rowptr, nsb, Nn);
    scan_write_kernel<<<nsb, 256, 0, stream>>>(deg, bofs, rowptr, ctr, Nn);
    scatter_kernel<<<eb, 256, 0, stream>>>(ei, flag, ctr, srcs, E_);

    int nb4 = (Nn + 3) / 4;
    int nr2 = (Nn + 1) / 2;

    // layer 1
    gemm_mfma_kernel<256><<<dim3(gb, 4), 256, 0, stream>>>(xb, Wt1, h1b, Nn);
    attn_coef1_kernel<<<nb4, 256, 0, stream>>>(h1b, att_src1, att_dst1, as1, ad1, Nn);
    aggregate1_kernel<<<nb4, 256, 0, stream>>>(h1b, rowptr, srcs, as1, ad1, b1, x2b0, Nn);
    bn_stats_bf16_kernel<<<256, 256, 0, stream>>>(x2b0, bn1, Nn);
    bn_apply_cast_kernel<<<nr2, 256, 0, stream>>>(x2b0, bn1, g1, be1, x2b, Nn);

    // layer 2
    gemm_mfma_kernel<128><<<dim3(gb, 2), 256, 0, stream>>>(x2b, Wt2, h2b, Nn);
    attn_coef2_kernel<<<nb4, 256, 0, stream>>>(h2b, att_src2, att_dst2, as2, ad2, Nn);
    aggregate2_kernel<<<nb4, 256, 0, stream>>>(h2b, rowptr, srcs, as2, ad2, b2, outf, Nn);
    bn_stats_kernel<128><<<256, 256, 0, stream>>>(outf, bn2, Nn);
    bn_apply_kernel<128><<<512, 256, 0, stream>>>(outf, bn2, g2, be2, Nn);
}

// Round 6
// 370.675 us; speedup vs baseline: 1.9978x; 1.0699x over previous
//
#include <hip/hip_runtime.h>
#include <math.h>

#define IN_DIM 256
#define EPS_BN 1e-5f

typedef __attribute__((ext_vector_type(8))) short short8v;  // 8 bf16 (4 VGPRs)
typedef __attribute__((ext_vector_type(4))) float f32x4;    // MFMA C/D

__device__ __forceinline__ float lrelu(float v) { return v > 0.f ? v : 0.2f * v; }

// bf16 <-> f32 helpers (RNE)
__device__ __forceinline__ unsigned short f2bf(float f) {
    unsigned int u = __float_as_uint(f);
    u += 0x7fffu + ((u >> 16) & 1u);
    return (unsigned short)(u >> 16);
}
__device__ __forceinline__ float bf2f(unsigned short s) {
    return __uint_as_float((unsigned int)s << 16);
}

// async global->LDS, 16B per lane; lds dest is wave-uniform base (lane*16 implicit)
__device__ __forceinline__ void gld16(const void* g, void* l) {
    __builtin_amdgcn_global_load_lds((const __attribute__((address_space(1))) void*)g,
                                     (__attribute__((address_space(3))) void*)l, 16, 0, 0);
}

// ---------- edge-index dtype detection (int32 vs int64) ----------
__global__ void detect_kernel(const unsigned int* __restrict__ w, int* __restrict__ flag,
                              long long nwords) {
    __shared__ int nz;
    if (threadIdx.x == 0) nz = 0;
    __syncthreads();
    int cnt = 0;
    for (int i = 0; i < 4; i++) {
        long long idx = 2LL * (threadIdx.x + i * 256) + 1;  // odd 32-bit words
        if (idx < nwords && w[idx] != 0u) cnt++;
    }
    if (cnt) atomicAdd(&nz, 1);
    __syncthreads();
    if (threadIdx.x == 0) flag[0] = (nz == 0) ? 1 : 0;  // all-zero odd words -> int64
}

__device__ __forceinline__ int edge_at(const void* ei, int is64, long long i) {
    if (is64) return (int)((const long long*)ei)[i];
    return ((const int*)ei)[i];
}

// ---------- CSR build ----------
__global__ void count_deg_kernel(const void* __restrict__ ei, const int* __restrict__ flag,
                                 int* __restrict__ deg, int E_) {
    int is64 = flag[0];
    int i = blockIdx.x * 256 + threadIdx.x;
    if (i < E_) {
        int d = edge_at(ei, is64, (long long)E_ + i);
        atomicAdd(&deg[d], 1);
    }
}

__global__ __launch_bounds__(256) void scan_partial_kernel(const int* __restrict__ deg,
                                                           int* __restrict__ bsum, int n) {
    __shared__ int sh[256];
    int t = threadIdx.x;
    int i = blockIdx.x * 256 + t;
    sh[t] = (i < n) ? deg[i] : 0;
    __syncthreads();
    for (int off = 128; off >= 1; off >>= 1) {
        if (t < off) sh[t] += sh[t + off];
        __syncthreads();
    }
    if (t == 0) bsum[blockIdx.x] = sh[0];
}

// combined: per-block computes its base offset from bsum, then local scan + write
__global__ __launch_bounds__(256) void scan_write_kernel(const int* __restrict__ deg,
                                                         const int* __restrict__ bsum,
                                                         int* __restrict__ rowptr,
                                                         int* __restrict__ ctr, int n, int nb) {
    __shared__ int sh[256];
    __shared__ int base_sh;
    int t = threadIdx.x;
    int b = blockIdx.x;
    sh[t] = (t < b) ? bsum[t] : 0;
    __syncthreads();
    for (int off = 128; off >= 1; off >>= 1) {
        if (t < off) sh[t] += sh[t + off];
        __syncthreads();
    }
    if (t == 0) base_sh = sh[0];
    __syncthreads();
    int i = b * 256 + t;
    int d = (i < n) ? deg[i] : 0;
    sh[t] = d;
    __syncthreads();
    for (int off = 1; off < 256; off <<= 1) {
        int u = (t >= off) ? sh[t - off] : 0;
        __syncthreads();
        sh[t] += u;
        __syncthreads();
    }
    if (i < n) {
        int v = base_sh + sh[t] - d;
        rowptr[i] = v;
        ctr[i] = v;
    }
    if (b == nb - 1 && t == 255) rowptr[n] = base_sh + sh[255];
}

__global__ void scatter_kernel(const void* __restrict__ ei, const int* __restrict__ flag,
                               int* __restrict__ ctr, int* __restrict__ srcs, int E_) {
    int is64 = flag[0];
    int i = blockIdx.x * 256 + threadIdx.x;
    if (i < E_) {
        int s = edge_at(ei, is64, i);
        int d = edge_at(ei, is64, (long long)E_ + i);
        int pos = atomicAdd(&ctr[d], 1);
        srcs[pos] = s;
    }
}

// ---------- combined prep: bf16(x) + Wt1 + Wt2 transpose-casts in one launch ----------
__global__ __launch_bounds__(256) void prep_kernel(const float* __restrict__ x,
                                                   unsigned short* __restrict__ xb, long long n8,
                                                   const float* __restrict__ W1,
                                                   unsigned short* __restrict__ Wt1,
                                                   const float* __restrict__ W2,
                                                   unsigned short* __restrict__ Wt2) {
    long long nbx = (n8 + 255) / 256;
    long long b = blockIdx.x;
    if (b < nbx) {
        long long i = b * 256 + threadIdx.x;
        if (i < n8) {
            const float4* p = (const float4*)(x + i * 8);
            float4 v0 = p[0], v1 = p[1];
            ushort4 o0, o1;
            o0.x = f2bf(v0.x); o0.y = f2bf(v0.y); o0.z = f2bf(v0.z); o0.w = f2bf(v0.w);
            o1.x = f2bf(v1.x); o1.y = f2bf(v1.y); o1.z = f2bf(v1.z); o1.w = f2bf(v1.w);
            *(ushort4*)(xb + i * 8) = o0;
            *(ushort4*)(xb + i * 8 + 4) = o1;
        }
        return;
    }
    b -= nbx;
    if (b < 256) {  // Wt1[c][k] = bf16(W1[k][c]), 256x256
        int idx = (int)b * 256 + threadIdx.x;
        int c = idx >> 8, k = idx & 255;
        Wt1[idx] = f2bf(W1[(long long)k * 256 + c]);
        return;
    }
    b -= 256;       // Wt2[c][k] = bf16(W2[k][c]), 128x256
    int idx = (int)b * 256 + threadIdx.x;
    int c = idx >> 8, k = idx & 255;
    Wt2[idx] = f2bf(W2[(long long)k * 128 + c]);
}

// ---------- MFMA bf16 GEMM + fused attention-coef epilogue ----------
// C[M,NCOL] = Ab[M,256] @ Wt^T (bf16, f32 acc); also a_s[n*NH+h] += sum_c h[n,c]*att_s[c]
// over this block's 64 cols (atomicAdd; a_s/a_d pre-zeroed). head = col0>>7 for NH=2.
template <int NCOL, int NH>
__global__ __launch_bounds__(256) void gemm_mfma_kernel(const unsigned short* __restrict__ Ab,
                                                        const unsigned short* __restrict__ Wt,
                                                        unsigned short* __restrict__ C,
                                                        const float* __restrict__ att_s,
                                                        const float* __restrict__ att_d,
                                                        float* __restrict__ a_s,
                                                        float* __restrict__ a_d, int M) {
    __shared__ unsigned short B_lds[64 * 256];   // 32 KB
    __shared__ unsigned short A_lds[128 * 64];   // 16 KB
    const int t = threadIdx.x;
    const int w = t >> 6, l = t & 63;
    const int row0 = blockIdx.x * 128;
    const int col0 = blockIdx.y * 64;

    // stage B [64 cols][256 k] once (pre-swizzled source, linear LDS dest)
    {
        const char* wb = (const char*)Wt + (size_t)col0 * 512;
#pragma unroll
        for (int it = 0; it < 8; ++it) {
            int q = w * 8 + it;
            int i = q * 64 + l;
            int r = i >> 5;
            int cs = (i & 31) ^ (r & 7);
            gld16(wb + (size_t)r * 512 + cs * 16, (char*)B_lds + q * 1024);
        }
    }
    // stage A chunk 0
    const char* ab = (const char*)Ab + (size_t)row0 * 512;
#pragma unroll
    for (int it = 0; it < 4; ++it) {
        int q = w * 4 + it;
        int i = q * 64 + l;
        int r = i >> 3;
        int cs = (i & 7) ^ (r & 7);
        gld16(ab + (size_t)r * 512 + cs * 16, (char*)A_lds + q * 1024);
    }
    __syncthreads();

    const int rl = l & 15, kg = l >> 4;
    f32x4 acc0[4], acc1[4];
#pragma unroll
    for (int i = 0; i < 4; ++i) { acc0[i] = (f32x4)(0.f); acc1[i] = (f32x4)(0.f); }

    const int ar0 = w * 32 + rl, ar1 = ar0 + 16;
    const int aswz = (ar0 & 7) << 4;

    for (int c = 0; c < 4; ++c) {
#pragma unroll
        for (int s = 0; s < 2; ++s) {
            short8v a0 = *(const short8v*)((const char*)A_lds +
                          ((ar0 * 128 + s * 64 + kg * 16) ^ aswz));
            short8v a1 = *(const short8v*)((const char*)A_lds +
                          ((ar1 * 128 + s * 64 + kg * 16) ^ aswz));
#pragma unroll
            for (int ct = 0; ct < 4; ++ct) {
                int br = ct * 16 + rl;
                short8v bfr = *(const short8v*)((const char*)B_lds +
                               ((br * 512 + c * 128 + s * 64 + kg * 16) ^ ((br & 7) << 4)));
                acc0[ct] = __builtin_amdgcn_mfma_f32_16x16x32_bf16(a0, bfr, acc0[ct], 0, 0, 0);
                acc1[ct] = __builtin_amdgcn_mfma_f32_16x16x32_bf16(a1, bfr, acc1[ct], 0, 0, 0);
            }
        }
        __syncthreads();
        if (c < 3) {
#pragma unroll
            for (int it = 0; it < 4; ++it) {
                int q = w * 4 + it;
                int i = q * 64 + l;
                int r = i >> 3;
                int cs = (i & 7) ^ (r & 7);
                gld16(ab + (size_t)r * 512 + (c + 1) * 128 + cs * 16, (char*)A_lds + q * 1024);
            }
            __syncthreads();
        }
    }

    // C store (bf16)
#pragma unroll
    for (int ct = 0; ct < 4; ++ct) {
#pragma unroll
        for (int r = 0; r < 4; ++r) {
            int gr0 = row0 + w * 32 + kg * 4 + r;
            if (gr0 < M) C[(long long)gr0 * NCOL + col0 + ct * 16 + rl] = f2bf(acc0[ct][r]);
            int gr1 = gr0 + 16;
            if (gr1 < M) C[(long long)gr1 * NCOL + col0 + ct * 16 + rl] = f2bf(acc1[ct][r]);
        }
    }

    // fused attention-coefficient partial dots (f32, pre-round acc)
    float asp0[4] = {}, adp0[4] = {}, asp1[4] = {}, adp1[4] = {};
#pragma unroll
    for (int ct = 0; ct < 4; ++ct) {
        int col = col0 + ct * 16 + rl;
        float vs = att_s[col], vd = att_d[col];
#pragma unroll
        for (int r = 0; r < 4; ++r) {
            asp0[r] += acc0[ct][r] * vs; adp0[r] += acc0[ct][r] * vd;
            asp1[r] += acc1[ct][r] * vs; adp1[r] += acc1[ct][r] * vd;
        }
    }
#pragma unroll
    for (int off = 1; off < 16; off <<= 1) {
#pragma unroll
        for (int r = 0; r < 4; ++r) {
            asp0[r] += __shfl_xor(asp0[r], off);
            adp0[r] += __shfl_xor(adp0[r], off);
            asp1[r] += __shfl_xor(asp1[r], off);
            adp1[r] += __shfl_xor(adp1[r], off);
        }
    }
    if (rl == 0) {
        int head = (NH == 2) ? (col0 >> 7) : 0;
#pragma unroll
        for (int r = 0; r < 4; ++r) {
            int gr0 = row0 + w * 32 + kg * 4 + r;
            if (gr0 < M) {
                atomicAdd(&a_s[gr0 * NH + head], asp0[r]);
                atomicAdd(&a_d[gr0 * NH + head], adp0[r]);
            }
            int gr1 = gr0 + 16;
            if (gr1 < M) {
                atomicAdd(&a_s[gr1 * NH + head], asp1[r]);
                atomicAdd(&a_d[gr1 * NH + head], adp1[r]);
            }
        }
    }
}

// ---------- softmax + aggregation: one wave per dst node, online softmax ----------
// Layer 1: 2 edges/iter (lane 0-31 edge A, 32-63 edge B), 16B/lane payload, 8 cols/lane.
// Chunk setup stores {src, w} per head in wave-local LDS; payload has NO shfl.
__global__ __launch_bounds__(256) void aggregate1_kernel(const unsigned short* __restrict__ h,
                                                         const int* __restrict__ rowptr,
                                                         const int* __restrict__ srcs,
                                                         const float* __restrict__ a_s,
                                                         const float* __restrict__ a_d,
                                                         const float* __restrict__ bias,
                                                         unsigned short* __restrict__ out, int Nn) {
    __shared__ float sw_lds[4 * 256];  // per wave: [2 heads][64 edges][{src_bits, w}]
    int wid = threadIdx.x >> 6, lane = threadIdx.x & 63;
    int n = blockIdx.x * 4 + wid;
    if (n >= Nn) return;
    float* wbase = &sw_lds[wid * 256];
    int beg = rowptr[n], end = rowptr[n + 1];
    float ad0 = a_d[n * 2], ad1 = a_d[n * 2 + 1];
    const int hh = (lane >> 4) & 1;     // head of this lane's columns
    const int ebase = lane >> 5;        // edge slot (A=0 / B=1)
    const int colb = (lane & 31) * 8;   // column base (8 cols/lane)
    float acc[8] = {0.f, 0.f, 0.f, 0.f, 0.f, 0.f, 0.f, 0.f};
    float den = 0.f, m0 = -1e30f, m1 = -1e30f;

    for (int cb = beg; cb < end; cb += 64) {
        int cnt = end - cb; if (cnt > 64) cnt = 64;
        float e0 = -1e30f, e1 = -1e30f;
        int s_l = 0;
        if (lane < cnt) {
            s_l = srcs[cb + lane];
            float2 av = *(const float2*)&a_s[(size_t)s_l * 2];
            e0 = lrelu(av.x + ad0);
            e1 = lrelu(av.y + ad1);
        }
        float cm0 = e0, cm1 = e1;
        for (int off = 32; off >= 1; off >>= 1) {
            cm0 = fmaxf(cm0, __shfl_xor(cm0, off));
            cm1 = fmaxf(cm1, __shfl_xor(cm1, off));
        }
        float f0 = (cm0 > m0) ? __expf(m0 - cm0) : 1.f;
        float f1 = (cm1 > m1) ? __expf(m1 - cm1) : 1.f;
        m0 = fmaxf(m0, cm0); m1 = fmaxf(m1, cm1);
        float fo = hh ? f1 : f0;
#pragma unroll
        for (int j = 0; j < 8; j++) acc[j] *= fo;
        den *= fo;
        if (lane < cnt) {
            *(float2*)&wbase[lane * 2] = make_float2(__int_as_float(s_l), __expf(e0 - m0));
            *(float2*)&wbase[128 + lane * 2] = make_float2(__int_as_float(s_l), __expf(e1 - m1));
        }
        int c = 0;
        for (; c + 4 <= cnt; c += 4) {
            float2 swA = *(const float2*)&wbase[hh * 128 + (c + ebase) * 2];
            float2 swB = *(const float2*)&wbase[hh * 128 + (c + 2 + ebase) * 2];
            int sA = __float_as_int(swA.x), sB = __float_as_int(swB.x);
            short8v pA = *(const short8v*)(h + ((size_t)sA << 8) + colb);
            short8v pB = *(const short8v*)(h + ((size_t)sB << 8) + colb);
            float wA = swA.y, wB = swB.y;
            den += wA + wB;
#pragma unroll
            for (int j = 0; j < 8; j++)
                acc[j] += wA * bf2f((unsigned short)pA[j]) + wB * bf2f((unsigned short)pB[j]);
        }
        for (; c < cnt; c += 2) {
            int e = c + ebase;
            if (e < cnt) {
                float2 swA = *(const float2*)&wbase[hh * 128 + e * 2];
                int sA = __float_as_int(swA.x);
                short8v pA = *(const short8v*)(h + ((size_t)sA << 8) + colb);
                float wA = swA.y;
                den += wA;
#pragma unroll
                for (int j = 0; j < 8; j++) acc[j] += wA * bf2f((unsigned short)pA[j]);
            }
        }
    }
    den += __shfl_xor(den, 32);
#pragma unroll
    for (int j = 0; j < 8; j++) acc[j] += __shfl_xor(acc[j], 32);
    if (lane < 32) {
        float inv = 1.f / (den + 1e-16f);
        float4 b0 = *(const float4*)&bias[colb];
        float4 b1 = *(const float4*)&bias[colb + 4];
        short8v o;
        o[0] = (short)f2bf(acc[0] * inv + b0.x); o[1] = (short)f2bf(acc[1] * inv + b0.y);
        o[2] = (short)f2bf(acc[2] * inv + b0.z); o[3] = (short)f2bf(acc[3] * inv + b0.w);
        o[4] = (short)f2bf(acc[4] * inv + b1.x); o[5] = (short)f2bf(acc[5] * inv + b1.y);
        o[6] = (short)f2bf(acc[6] * inv + b1.z); o[7] = (short)f2bf(acc[7] * inv + b1.w);
        *(short8v*)(out + ((size_t)n << 8) + colb) = o;
    }
}

// Layer 2: 4 edges/iter (16 lanes each), 8 cols/lane, single head, f32 out.
__global__ __launch_bounds__(256) void aggregate2_kernel(const unsigned short* __restrict__ h,
                                                         const int* __restrict__ rowptr,
                                                         const int* __restrict__ srcs,
                                                         const float* __restrict__ a_s,
                                                         const float* __restrict__ a_d,
                                                         const float* __restrict__ bias,
                                                         float* __restrict__ out, int Nn) {
    __shared__ float sw_lds[4 * 128];  // per wave: [64 edges][{src_bits, w}]
    int wid = threadIdx.x >> 6, lane = threadIdx.x & 63;
    int n = blockIdx.x * 4 + wid;
    if (n >= Nn) return;
    float* wbase = &sw_lds[wid * 128];
    int beg = rowptr[n], end = rowptr[n + 1];
    float ad = a_d[n];
    const int eoff = lane >> 4;        // edge slot 0..3
    const int colb = (lane & 15) * 8;  // 8 cols/lane
    float acc[8] = {0.f, 0.f, 0.f, 0.f, 0.f, 0.f, 0.f, 0.f};
    float den = 0.f, m = -1e30f;

    for (int cb = beg; cb < end; cb += 64) {
        int cnt = end - cb; if (cnt > 64) cnt = 64;
        float e_ = -1e30f;
        int s_l = 0;
        if (lane < cnt) {
            s_l = srcs[cb + lane];
            e_ = lrelu(a_s[s_l] + ad);
        }
        float cm = e_;
        for (int off = 32; off >= 1; off >>= 1) cm = fmaxf(cm, __shfl_xor(cm, off));
        float f = (cm > m) ? __expf(m - cm) : 1.f;
        m = fmaxf(m, cm);
#pragma unroll
        for (int j = 0; j < 8; j++) acc[j] *= f;
        den *= f;
        if (lane < cnt)
            *(float2*)&wbase[lane * 2] = make_float2(__int_as_float(s_l), __expf(e_ - m));
        int c = 0;
        for (; c + 8 <= cnt; c += 8) {
            float2 swA = *(const float2*)&wbase[(c + eoff) * 2];
            float2 swB = *(const float2*)&wbase[(c + 4 + eoff) * 2];
            int sA = __float_as_int(swA.x), sB = __float_as_int(swB.x);
            short8v pA = *(const short8v*)(h + ((size_t)sA << 7) + colb);
            short8v pB = *(const short8v*)(h + ((size_t)sB << 7) + colb);
            float wA = swA.y, wB = swB.y;
            den += wA + wB;
#pragma unroll
            for (int j = 0; j < 8; j++)
                acc[j] += wA * bf2f((unsigned short)pA[j]) + wB * bf2f((unsigned short)pB[j]);
        }
        for (; c < cnt; c += 4) {
            int e = c + eoff;
            if (e < cnt) {
                float2 swA = *(const float2*)&wbase[e * 2];
                int sA = __float_as_int(swA.x);
                short8v pA = *(const short8v*)(h + ((size_t)sA << 7) + colb);
                float wA = swA.y;
                den += wA;
#pragma unroll
                for (int j = 0; j < 8; j++) acc[j] += wA * bf2f((unsigned short)pA[j]);
            }
        }
    }
    den += __shfl_xor(den, 16);
    den += __shfl_xor(den, 32);
#pragma unroll
    for (int j = 0; j < 8; j++) {
        acc[j] += __shfl_xor(acc[j], 16);
        acc[j] += __shfl_xor(acc[j], 32);
    }
    if (lane < 16) {
        float inv = 1.f / (den + 1e-16f);
        float* ob = out + (size_t)n * 128 + colb;
        float4 b0 = *(const float4*)&bias[colb];
        float4 b1 = *(const float4*)&bias[colb + 4];
        float4 o0 = make_float4(acc[0] * inv + b0.x, acc[1] * inv + b0.y,
                                acc[2] * inv + b0.z, acc[3] * inv + b0.w);
        float4 o1 = make_float4(acc[4] * inv + b1.x, acc[5] * inv + b1.y,
                                acc[6] * inv + b1.z, acc[7] * inv + b1.w);
        *(float4*)ob = o0;
        *(float4*)(ob + 4) = o1;
    }
}

// ---------- batchnorm ----------
__global__ __launch_bounds__(256) void bn_stats_bf16_kernel(const unsigned short* __restrict__ x,
                                                            float* __restrict__ sums, int Nn) {
    int t = threadIdx.x;
    int c2 = (t & 127) * 2;
    int r0 = blockIdx.x * 2 + (t >> 7);
    int rs = gridDim.x * 2;
    float s0 = 0.f, q0 = 0.f, s1 = 0.f, q1 = 0.f;
    for (int r = r0; r < Nn; r += rs) {
        unsigned int v = *(const unsigned int*)&x[(long long)r * 256 + c2];
        float a = bf2f((unsigned short)(v & 0xffffu));
        float b = bf2f((unsigned short)(v >> 16));
        s0 += a; q0 += a * a;
        s1 += b; q1 += b * b;
    }
    atomicAdd(&sums[c2], s0);     atomicAdd(&sums[256 + c2], q0);
    atomicAdd(&sums[c2 + 1], s1); atomicAdd(&sums[256 + c2 + 1], q1);
}

__global__ __launch_bounds__(256) void bn_apply_cast_kernel(const unsigned short* __restrict__ xin,
                                                            const float* __restrict__ sums,
                                                            const float* __restrict__ gamma,
                                                            const float* __restrict__ beta,
                                                            unsigned short* __restrict__ xout,
                                                            int Nn) {
    int t = threadIdx.x;
    int c2 = (t & 127) * 2;
    int r = blockIdx.x * 2 + (t >> 7);
    if (r >= Nn) return;
    float invN = 1.f / (float)Nn;
    float mu0 = sums[c2] * invN;
    float var0 = sums[256 + c2] * invN - mu0 * mu0;
    float sc0 = rsqrtf(var0 + EPS_BN) * gamma[c2];
    float sh0 = beta[c2] - mu0 * sc0;
    float mu1 = sums[c2 + 1] * invN;
    float var1 = sums[256 + c2 + 1] * invN - mu1 * mu1;
    float sc1 = rsqrtf(var1 + EPS_BN) * gamma[c2 + 1];
    float sh1 = beta[c2 + 1] - mu1 * sc1;
    unsigned int v = *(const unsigned int*)&xin[(long long)r * 256 + c2];
    float a = bf2f((unsigned short)(v & 0xffffu));
    float b = bf2f((unsigned short)(v >> 16));
    a = fmaxf(a * sc0 + sh0, 0.f);
    b = fmaxf(b * sc1 + sh1, 0.f);
    unsigned int o = (unsigned int)f2bf(a) | ((unsigned int)f2bf(b) << 16);
    *(unsigned int*)&xout[(long long)r * 256 + c2] = o;
}

template <int CW>
__global__ __launch_bounds__(256) void bn_stats_kernel(const float* __restrict__ x,
                                                       float* __restrict__ sums, int Nn) {
    int t = threadIdx.x;
    int col = t % CW;
    int rpb = 256 / CW;
    int r0 = blockIdx.x * rpb + t / CW;
    int rs = gridDim.x * rpb;
    float s = 0.f, q = 0.f;
    for (int r = r0; r < Nn; r += rs) {
        float v = x[(long long)r * CW + col];
        s += v; q += v * v;
    }
    atomicAdd(&sums[col], s);
    atomicAdd(&sums[CW + col], q);
}

template <int CW>
__global__ __launch_bounds__(256) void bn_apply_kernel(float* __restrict__ x,
                                                       const float* __restrict__ sums,
                                                       const float* __restrict__ gamma,
                                                       const float* __restrict__ beta, int Nn) {
    int t = threadIdx.x;
    int col = t % CW;
    float mu = sums[col] / (float)Nn;
    float var = sums[CW + col] / (float)Nn - mu * mu;
    float sc = rsqrtf(var + EPS_BN) * gamma[col];
    float sh = beta[col] - mu * sc;
    int rpb = 256 / CW;
    int r0 = blockIdx.x * rpb + t / CW;
    int rs = gridDim.x * rpb;
    for (int r = r0; r < Nn; r += rs) {
        long long idx = (long long)r * CW + col;
        float v = x[idx] * sc + sh;
        x[idx] = fmaxf(v, 0.f);
    }
}

extern "C" void kernel_launch(void* const* d_in, const int* in_sizes, int n_in,
                              void* d_out, int out_size, void* d_ws, size_t ws_size,
                              hipStream_t stream) {
    const float* x        = (const float*)d_in[0];
    const void*  ei       = d_in[1];
    const float* W1       = (const float*)d_in[2];
    const float* att_src1 = (const float*)d_in[3];
    const float* att_dst1 = (const float*)d_in[4];
    const float* b1       = (const float*)d_in[5];
    const float* g1       = (const float*)d_in[6];
    const float* be1      = (const float*)d_in[7];
    const float* W2       = (const float*)d_in[8];
    const float* att_src2 = (const float*)d_in[9];
    const float* att_dst2 = (const float*)d_in[10];
    const float* b2       = (const float*)d_in[11];
    const float* g2       = (const float*)d_in[12];
    const float* be2      = (const float*)d_in[13];

    const int Nn = in_sizes[0] / IN_DIM;  // 50000
    const int E_ = in_sizes[1] / 2;       // 800000
    const int gb = (Nn + 127) / 128;      // 391 row-blocks
    const int Mpad = gb * 128 + 128;

    char* ws = (char*)d_ws;
    size_t o = 0;
    auto alloc = [&](size_t bytes) {
        size_t r = o;
        o += (bytes + 255) & ~(size_t)255;
        return r;
    };
    int* flag = (int*)(ws + alloc(4));
    // --- contiguous zero-region: deg, as1, ad1, as2, ad2 ---
    size_t z0 = o;
    int*   deg = (int*)(ws + alloc((size_t)Nn * 4));
    float* as1 = (float*)(ws + alloc((size_t)Nn * 2 * 4));
    float* ad1 = (float*)(ws + alloc((size_t)Nn * 2 * 4));
    float* as2 = (float*)(ws + alloc((size_t)Nn * 4));
    float* ad2 = (float*)(ws + alloc((size_t)Nn * 4));
    size_t z1 = o;
    // --- contiguous zero-region: bn1, bn2 ---
    float* bn1 = (float*)(ws + alloc(512 * 4));
    float* bn2 = (float*)(ws + alloc(256 * 4));
    size_t z2 = o;
    int*   rowptr = (int*)(ws + alloc((size_t)(Nn + 1) * 4));
    int*   ctr    = (int*)(ws + alloc((size_t)Nn * 4));
    int*   srcs   = (int*)(ws + alloc((size_t)E_ * 4));
    int*   bsum   = (int*)(ws + alloc(256 * 4));
    unsigned short* Wt1  = (unsigned short*)(ws + alloc((size_t)256 * 256 * 2));
    unsigned short* Wt2  = (unsigned short*)(ws + alloc((size_t)128 * 256 * 2));
    unsigned short* xb   = (unsigned short*)(ws + alloc((size_t)Mpad * 256 * 2));
    unsigned short* x2b0 = (unsigned short*)(ws + alloc((size_t)Nn * 256 * 2));
    unsigned short* x2b  = (unsigned short*)(ws + alloc((size_t)Mpad * 256 * 2));
    unsigned short* h1b  = (unsigned short*)(ws + alloc((size_t)Nn * 256 * 2));
    unsigned short* h2b  = (unsigned short*)(ws + alloc((size_t)Nn * 128 * 2));
    float* outf = (float*)d_out;

    hipMemsetAsync(ws + z0, 0, z1 - z0, stream);          // deg + attn coef accumulators
    hipMemsetAsync(ws + (size_t)((char*)bn1 - ws), 0, z2 - (size_t)((char*)bn1 - ws), stream);

    {
        long long n8 = (long long)Nn * 256 / 8;
        long long grid = (n8 + 255) / 256 + 256 + 128;
        prep_kernel<<<(int)grid, 256, 0, stream>>>(x, xb, n8, W1, Wt1, W2, Wt2);
    }

    detect_kernel<<<1, 256, 0, stream>>>((const unsigned int*)ei, flag, (long long)2 * E_);
    int eb = (E_ + 255) / 256;
    int nsb = (Nn + 255) / 256;  // <= 256
    count_deg_kernel<<<eb, 256, 0, stream>>>(ei, flag, deg, E_);
    scan_partial_kernel<<<nsb, 256, 0, stream>>>(deg, bsum, Nn);
    scan_write_kernel<<<nsb, 256, 0, stream>>>(deg, bsum, rowptr, ctr, Nn, nsb);
    scatter_kernel<<<eb, 256, 0, stream>>>(ei, flag, ctr, srcs, E_);

    int nb4 = (Nn + 3) / 4;
    int nr2 = (Nn + 1) / 2;

    // layer 1
    gemm_mfma_kernel<256, 2><<<dim3(gb, 4), 256, 0, stream>>>(xb, Wt1, h1b, att_src1, att_dst1,
                                                              as1, ad1, Nn);
    aggregate1_kernel<<<nb4, 256, 0, stream>>>(h1b, rowptr, srcs, as1, ad1, b1, x2b0, Nn);
    bn_stats_bf16_kernel<<<256, 256, 0, stream>>>(x2b0, bn1, Nn);
    bn_apply_cast_kernel<<<nr2, 256, 0, stream>>>(x2b0, bn1, g1, be1, x2b, Nn);

    // layer 2
    gemm_mfma_kernel<128, 1><<<dim3(gb, 2), 256, 0, stream>>>(x2b, Wt2, h2b, att_src2, att_dst2,
                                                              as2, ad2, Nn);
    aggregate2_kernel<<<nb4, 256, 0, stream>>>(h2b, rowptr, srcs, as2, ad2, b2, outf, Nn);
    bn_stats_kernel<128><<<256, 256, 0, stream>>>(outf, bn2, Nn);
    bn_apply_kernel<128><<<512, 256, 0, stream>>>(outf, bn2, g2, be2, Nn);
}

// Round 7
// 306.217 us; speedup vs baseline: 2.4183x; 1.2105x over previous
//
#include <hip/hip_runtime.h>
#include <math.h>

#define IN_DIM 256
#define EPS_BN 1e-5f
#define NS 16  // BN shadow-copy count (atomic contention spreader)

typedef __attribute__((ext_vector_type(8))) short short8v;  // 8 bf16 (4 VGPRs)
typedef __attribute__((ext_vector_type(4))) float f32x4;    // MFMA C/D

__device__ __forceinline__ float lrelu(float v) { return v > 0.f ? v : 0.2f * v; }

__device__ __forceinline__ unsigned short f2bf(float f) {
    unsigned int u = __float_as_uint(f);
    u += 0x7fffu + ((u >> 16) & 1u);
    return (unsigned short)(u >> 16);
}
__device__ __forceinline__ float bf2f(unsigned short s) {
    return __uint_as_float((unsigned int)s << 16);
}

__device__ __forceinline__ void gld16(const void* g, void* l) {
    __builtin_amdgcn_global_load_lds((const __attribute__((address_space(1))) void*)g,
                                     (__attribute__((address_space(3))) void*)l, 16, 0, 0);
}

__device__ __forceinline__ int edge_at(const void* ei, int is64, long long i) {
    if (is64) return (int)((const long long*)ei)[i];
    return ((const int*)ei)[i];
}

// ---------- combined prep: bf16(x), Wt1, Wt2, edge-dtype detect — one launch ----------
__global__ __launch_bounds__(256) void prep_kernel(const float* __restrict__ x,
                                                   unsigned short* __restrict__ xb, long long n8,
                                                   const float* __restrict__ W1,
                                                   unsigned short* __restrict__ Wt1,
                                                   const float* __restrict__ W2,
                                                   unsigned short* __restrict__ Wt2,
                                                   const unsigned int* __restrict__ eiw,
                                                   int* __restrict__ flag, long long nwords) {
    __shared__ int nz;
    long long nbx = (n8 + 255) / 256;
    long long b = blockIdx.x;
    if (b < nbx) {
        long long i = b * 256 + threadIdx.x;
        if (i < n8) {
            const float4* p = (const float4*)(x + i * 8);
            float4 v0 = p[0], v1 = p[1];
            ushort4 o0, o1;
            o0.x = f2bf(v0.x); o0.y = f2bf(v0.y); o0.z = f2bf(v0.z); o0.w = f2bf(v0.w);
            o1.x = f2bf(v1.x); o1.y = f2bf(v1.y); o1.z = f2bf(v1.z); o1.w = f2bf(v1.w);
            *(ushort4*)(xb + i * 8) = o0;
            *(ushort4*)(xb + i * 8 + 4) = o1;
        }
        return;
    }
    b -= nbx;
    if (b < 256) {  // Wt1[c][k] = bf16(W1[k][c]), 256x256
        int idx = (int)b * 256 + threadIdx.x;
        int c = idx >> 8, k = idx & 255;
        Wt1[idx] = f2bf(W1[(long long)k * 256 + c]);
        return;
    }
    b -= 256;
    if (b < 128) {  // Wt2[c][k] = bf16(W2[k][c]), 128x256
        int idx = (int)b * 256 + threadIdx.x;
        int c = idx >> 8, k = idx & 255;
        Wt2[idx] = f2bf(W2[(long long)k * 128 + c]);
        return;
    }
    // last block: int32-vs-int64 detection (odd 32-bit words all zero -> int64)
    if (threadIdx.x == 0) nz = 0;
    __syncthreads();
    int cnt = 0;
    for (int i = 0; i < 4; i++) {
        long long idx = 2LL * (threadIdx.x + i * 256) + 1;
        if (idx < nwords && eiw[idx] != 0u) cnt++;
    }
    if (cnt) atomicAdd(&nz, 1);
    __syncthreads();
    if (threadIdx.x == 0) flag[0] = (nz == 0) ? 1 : 0;
}

// ---------- CSR build ----------
__global__ void count_deg_kernel(const void* __restrict__ ei, const int* __restrict__ flag,
                                 int* __restrict__ deg, int E_) {
    int is64 = flag[0];
    int i = blockIdx.x * 256 + threadIdx.x;
    if (i < E_) {
        int d = edge_at(ei, is64, (long long)E_ + i);
        atomicAdd(&deg[d], 1);
    }
}

__global__ __launch_bounds__(256) void scan_partial_kernel(const int* __restrict__ deg,
                                                           int* __restrict__ bsum, int n) {
    __shared__ int sh[256];
    int t = threadIdx.x;
    int i = blockIdx.x * 256 + t;
    sh[t] = (i < n) ? deg[i] : 0;
    __syncthreads();
    for (int off = 128; off >= 1; off >>= 1) {
        if (t < off) sh[t] += sh[t + off];
        __syncthreads();
    }
    if (t == 0) bsum[blockIdx.x] = sh[0];
}

__global__ __launch_bounds__(256) void scan_write_kernel(const int* __restrict__ deg,
                                                         const int* __restrict__ bsum,
                                                         int* __restrict__ rowptr,
                                                         int* __restrict__ ctr, int n, int nb) {
    __shared__ int sh[256];
    __shared__ int base_sh;
    int t = threadIdx.x;
    int b = blockIdx.x;
    sh[t] = (t < b) ? bsum[t] : 0;
    __syncthreads();
    for (int off = 128; off >= 1; off >>= 1) {
        if (t < off) sh[t] += sh[t + off];
        __syncthreads();
    }
    if (t == 0) base_sh = sh[0];
    __syncthreads();
    int i = b * 256 + t;
    int d = (i < n) ? deg[i] : 0;
    sh[t] = d;
    __syncthreads();
    for (int off = 1; off < 256; off <<= 1) {
        int u = (t >= off) ? sh[t - off] : 0;
        __syncthreads();
        sh[t] += u;
        __syncthreads();
    }
    if (i < n) {
        int v = base_sh + sh[t] - d;
        rowptr[i] = v;
        ctr[i] = v;
    }
    if (b == nb - 1 && t == 255) rowptr[n] = base_sh + sh[255];
}

__global__ void scatter_kernel(const void* __restrict__ ei, const int* __restrict__ flag,
                               int* __restrict__ ctr, int* __restrict__ srcs, int E_) {
    int is64 = flag[0];
    int i = blockIdx.x * 256 + threadIdx.x;
    if (i < E_) {
        int s = edge_at(ei, is64, i);
        int d = edge_at(ei, is64, (long long)E_ + i);
        int pos = atomicAdd(&ctr[d], 1);
        srcs[pos] = s;
    }
}

// ---------- MFMA bf16 GEMM + fused attn-coef epilogue (+ optional fused BN on A) ----------
// C[M,NCOL] = A'[M,256] @ Wt^T. FUSEBN: A' = relu(bn(Ab)) computed during reg-staging
// (stats from NS shadow sums). Non-fused: A staged via global_load_lds (padded Ab).
template <int NCOL, int NH, bool FUSEBN>
__global__ __launch_bounds__(256) void gemm_mfma_kernel(const unsigned short* __restrict__ Ab,
                                                        const unsigned short* __restrict__ Wt,
                                                        unsigned short* __restrict__ C,
                                                        const float* __restrict__ att_s,
                                                        const float* __restrict__ att_d,
                                                        float* __restrict__ a_s,
                                                        float* __restrict__ a_d, int M,
                                                        const float* __restrict__ bnsh,
                                                        const float* __restrict__ gamma,
                                                        const float* __restrict__ beta) {
    __shared__ unsigned short B_lds[64 * 256];   // 32 KB
    __shared__ unsigned short A_lds[128 * 64];   // 16 KB
    __shared__ float scs[FUSEBN ? 256 : 1];
    __shared__ float shs[FUSEBN ? 256 : 1];
    const int t = threadIdx.x;
    const int w = t >> 6, l = t & 63;
    const int row0 = blockIdx.x * 128;
    const int col0 = blockIdx.y * 64;

    // stage B [64 cols][256 k] once (pre-swizzled source, linear LDS dest)
    {
        const char* wb = (const char*)Wt + (size_t)col0 * 512;
#pragma unroll
        for (int it = 0; it < 8; ++it) {
            int q = w * 8 + it;
            int i = q * 64 + l;
            int r = i >> 5;
            int cs = (i & 31) ^ (r & 7);
            gld16(wb + (size_t)r * 512 + cs * 16, (char*)B_lds + q * 1024);
        }
    }

    short8v nxt[4];
    const char* ab = (const char*)Ab + (size_t)row0 * 512;

    if (FUSEBN) {
        // BN coefficients from shadow sums
        {
            int c = t;  // 256 threads, 256 cols
            float s = 0.f, q = 0.f;
#pragma unroll
            for (int sh = 0; sh < NS; sh++) { s += bnsh[sh * 512 + c]; q += bnsh[sh * 512 + 256 + c]; }
            float invN = 1.f / (float)M;
            float mu = s * invN;
            float var = q * invN - mu * mu;
            float sc = rsqrtf(var + EPS_BN) * gamma[c];
            scs[c] = sc;
            shs[c] = beta[c] - mu * sc;
        }
        // load chunk 0 into regs
#pragma unroll
        for (int it = 0; it < 4; ++it) {
            int i = it * 256 + t;
            int r = i >> 3, g = i & 7;
            int gr = row0 + r;
            nxt[it] = (gr < M) ? *(const short8v*)(Ab + (size_t)gr * 256 + g * 8)
                               : (short8v)(short)0;
        }
        __syncthreads();  // scs/shs ready
        // BN+relu+pack -> swizzled LDS
#pragma unroll
        for (int it = 0; it < 4; ++it) {
            int i = it * 256 + t;
            int r = i >> 3, g = i & 7;
            int kb = g * 8;
            float4 s0 = *(const float4*)&scs[kb], s1 = *(const float4*)&scs[kb + 4];
            float4 h0 = *(const float4*)&shs[kb], h1 = *(const float4*)&shs[kb + 4];
            short8v v = nxt[it];
            short8v ov;
            ov[0] = (short)f2bf(fmaxf(bf2f((unsigned short)v[0]) * s0.x + h0.x, 0.f));
            ov[1] = (short)f2bf(fmaxf(bf2f((unsigned short)v[1]) * s0.y + h0.y, 0.f));
            ov[2] = (short)f2bf(fmaxf(bf2f((unsigned short)v[2]) * s0.z + h0.z, 0.f));
            ov[3] = (short)f2bf(fmaxf(bf2f((unsigned short)v[3]) * s0.w + h0.w, 0.f));
            ov[4] = (short)f2bf(fmaxf(bf2f((unsigned short)v[4]) * s1.x + h1.x, 0.f));
            ov[5] = (short)f2bf(fmaxf(bf2f((unsigned short)v[5]) * s1.y + h1.y, 0.f));
            ov[6] = (short)f2bf(fmaxf(bf2f((unsigned short)v[6]) * s1.z + h1.z, 0.f));
            ov[7] = (short)f2bf(fmaxf(bf2f((unsigned short)v[7]) * s1.w + h1.w, 0.f));
            *(short8v*)((char*)A_lds + r * 128 + ((g ^ (r & 7)) << 4)) = ov;
        }
    } else {
        // chunk 0 via DMA (pre-swizzled source)
#pragma unroll
        for (int it = 0; it < 4; ++it) {
            int q = w * 4 + it;
            int i = q * 64 + l;
            int r = i >> 3;
            int cs = (i & 7) ^ (r & 7);
            gld16(ab + (size_t)r * 512 + cs * 16, (char*)A_lds + q * 1024);
        }
    }
    __syncthreads();

    const int rl = l & 15, kg = l >> 4;
    f32x4 acc0[4], acc1[4];
#pragma unroll
    for (int i = 0; i < 4; ++i) { acc0[i] = (f32x4)(0.f); acc1[i] = (f32x4)(0.f); }

    const int ar0 = w * 32 + rl, ar1 = ar0 + 16;
    const int aswz = (ar0 & 7) << 4;

    for (int c = 0; c < 4; ++c) {
        if (FUSEBN && c < 3) {  // prefetch next chunk early (hide under MFMA)
#pragma unroll
            for (int it = 0; it < 4; ++it) {
                int i = it * 256 + t;
                int r = i >> 3, g = i & 7;
                int gr = row0 + r;
                nxt[it] = (gr < M) ? *(const short8v*)(Ab + (size_t)gr * 256 + (c + 1) * 64 + g * 8)
                                   : (short8v)(short)0;
            }
        }
#pragma unroll
        for (int s = 0; s < 2; ++s) {
            short8v a0 = *(const short8v*)((const char*)A_lds +
                          ((ar0 * 128 + s * 64 + kg * 16) ^ aswz));
            short8v a1 = *(const short8v*)((const char*)A_lds +
                          ((ar1 * 128 + s * 64 + kg * 16) ^ aswz));
#pragma unroll
            for (int ct = 0; ct < 4; ++ct) {
                int br = ct * 16 + rl;
                short8v bfr = *(const short8v*)((const char*)B_lds +
                               ((br * 512 + c * 128 + s * 64 + kg * 16) ^ ((br & 7) << 4)));
                acc0[ct] = __builtin_amdgcn_mfma_f32_16x16x32_bf16(a0, bfr, acc0[ct], 0, 0, 0);
                acc1[ct] = __builtin_amdgcn_mfma_f32_16x16x32_bf16(a1, bfr, acc1[ct], 0, 0, 0);
            }
        }
        __syncthreads();
        if (c < 3) {
            if (FUSEBN) {
#pragma unroll
                for (int it = 0; it < 4; ++it) {
                    int i = it * 256 + t;
                    int r = i >> 3, g = i & 7;
                    int kb = (c + 1) * 64 + g * 8;
                    float4 s0 = *(const float4*)&scs[kb], s1 = *(const float4*)&scs[kb + 4];
                    float4 h0 = *(const float4*)&shs[kb], h1 = *(const float4*)&shs[kb + 4];
                    short8v v = nxt[it];
                    short8v ov;
                    ov[0] = (short)f2bf(fmaxf(bf2f((unsigned short)v[0]) * s0.x + h0.x, 0.f));
                    ov[1] = (short)f2bf(fmaxf(bf2f((unsigned short)v[1]) * s0.y + h0.y, 0.f));
                    ov[2] = (short)f2bf(fmaxf(bf2f((unsigned short)v[2]) * s0.z + h0.z, 0.f));
                    ov[3] = (short)f2bf(fmaxf(bf2f((unsigned short)v[3]) * s0.w + h0.w, 0.f));
                    ov[4] = (short)f2bf(fmaxf(bf2f((unsigned short)v[4]) * s1.x + h1.x, 0.f));
                    ov[5] = (short)f2bf(fmaxf(bf2f((unsigned short)v[5]) * s1.y + h1.y, 0.f));
                    ov[6] = (short)f2bf(fmaxf(bf2f((unsigned short)v[6]) * s1.z + h1.z, 0.f));
                    ov[7] = (short)f2bf(fmaxf(bf2f((unsigned short)v[7]) * s1.w + h1.w, 0.f));
                    *(short8v*)((char*)A_lds + r * 128 + ((g ^ (r & 7)) << 4)) = ov;
                }
            } else {
#pragma unroll
                for (int it = 0; it < 4; ++it) {
                    int q = w * 4 + it;
                    int i = q * 64 + l;
                    int r = i >> 3;
                    int cs = (i & 7) ^ (r & 7);
                    gld16(ab + (size_t)r * 512 + (c + 1) * 128 + cs * 16, (char*)A_lds + q * 1024);
                }
            }
            __syncthreads();
        }
    }

    // C store (bf16)
#pragma unroll
    for (int ct = 0; ct < 4; ++ct) {
#pragma unroll
        for (int r = 0; r < 4; ++r) {
            int gr0 = row0 + w * 32 + kg * 4 + r;
            if (gr0 < M) C[(long long)gr0 * NCOL + col0 + ct * 16 + rl] = f2bf(acc0[ct][r]);
            int gr1 = gr0 + 16;
            if (gr1 < M) C[(long long)gr1 * NCOL + col0 + ct * 16 + rl] = f2bf(acc1[ct][r]);
        }
    }

    // fused attention-coefficient partial dots (f32, pre-round acc)
    float asp0[4] = {}, adp0[4] = {}, asp1[4] = {}, adp1[4] = {};
#pragma unroll
    for (int ct = 0; ct < 4; ++ct) {
        int col = col0 + ct * 16 + rl;
        float vs = att_s[col], vd = att_d[col];
#pragma unroll
        for (int r = 0; r < 4; ++r) {
            asp0[r] += acc0[ct][r] * vs; adp0[r] += acc0[ct][r] * vd;
            asp1[r] += acc1[ct][r] * vs; adp1[r] += acc1[ct][r] * vd;
        }
    }
#pragma unroll
    for (int off = 1; off < 16; off <<= 1) {
#pragma unroll
        for (int r = 0; r < 4; ++r) {
            asp0[r] += __shfl_xor(asp0[r], off);
            adp0[r] += __shfl_xor(adp0[r], off);
            asp1[r] += __shfl_xor(asp1[r], off);
            adp1[r] += __shfl_xor(adp1[r], off);
        }
    }
    if (rl == 0) {
        int head = (NH == 2) ? (col0 >> 7) : 0;
#pragma unroll
        for (int r = 0; r < 4; ++r) {
            int gr0 = row0 + w * 32 + kg * 4 + r;
            if (gr0 < M) {
                atomicAdd(&a_s[gr0 * NH + head], asp0[r]);
                atomicAdd(&a_d[gr0 * NH + head], adp0[r]);
            }
            int gr1 = gr0 + 16;
            if (gr1 < M) {
                atomicAdd(&a_s[gr1 * NH + head], asp1[r]);
                atomicAdd(&a_d[gr1 * NH + head], adp1[r]);
            }
        }
    }
}

// ---------- softmax + aggregation (one wave per node) + fused BN-stats ----------
__global__ __launch_bounds__(256) void aggregate1_kernel(const unsigned short* __restrict__ h,
                                                         const int* __restrict__ rowptr,
                                                         const int* __restrict__ srcs,
                                                         const float* __restrict__ a_s,
                                                         const float* __restrict__ a_d,
                                                         const float* __restrict__ bias,
                                                         unsigned short* __restrict__ out,
                                                         float* __restrict__ bnsh, int Nn) {
    __shared__ float sw_lds[4 * 256];
    __shared__ float ssum[4][256];
    __shared__ float ssq[4][256];
    const int t = threadIdx.x;
    const int wid = t >> 6, lane = t & 63;
    const int n = blockIdx.x * 4 + wid;
    const int colb = (lane & 31) * 8;
    if (lane < 32) {
#pragma unroll
        for (int j = 0; j < 8; j++) { ssum[wid][colb + j] = 0.f; ssq[wid][colb + j] = 0.f; }
    }
    if (n < Nn) {
        float* wbase = &sw_lds[wid * 256];
        int beg = rowptr[n], end = rowptr[n + 1];
        float2 adv = *(const float2*)&a_d[(size_t)n * 2];
        float ad0 = adv.x, ad1 = adv.y;
        const int hh = (lane >> 4) & 1;
        const int eb = lane >> 5;
        float acc[8] = {0.f, 0.f, 0.f, 0.f, 0.f, 0.f, 0.f, 0.f};
        float den = 0.f, m0 = -1e30f, m1 = -1e30f;

        for (int cb = beg; cb < end; cb += 64) {
            int cnt = end - cb; if (cnt > 64) cnt = 64;
            float e0 = -1e30f, e1 = -1e30f;
            int s_l = 0;
            if (lane < cnt) {
                s_l = srcs[cb + lane];
                float2 av = *(const float2*)&a_s[(size_t)s_l * 2];
                e0 = lrelu(av.x + ad0);
                e1 = lrelu(av.y + ad1);
            }
            float cm0 = e0, cm1 = e1;
            for (int off = 32; off >= 1; off >>= 1) {
                cm0 = fmaxf(cm0, __shfl_xor(cm0, off));
                cm1 = fmaxf(cm1, __shfl_xor(cm1, off));
            }
            if (cm0 > m0 || cm1 > m1) {  // wave-uniform rescale (skip when max stable)
                float f0 = (cm0 > m0) ? __expf(m0 - cm0) : 1.f;
                float f1 = (cm1 > m1) ? __expf(m1 - cm1) : 1.f;
                m0 = fmaxf(m0, cm0); m1 = fmaxf(m1, cm1);
                float fo = hh ? f1 : f0;
#pragma unroll
                for (int j = 0; j < 8; j++) acc[j] *= fo;
                den *= fo;
            }
            if (lane < cnt) {
                *(float2*)&wbase[lane * 2] = make_float2(__int_as_float(s_l), __expf(e0 - m0));
                *(float2*)&wbase[128 + lane * 2] = make_float2(__int_as_float(s_l), __expf(e1 - m1));
            }
            int c = 0;
            for (; c + 8 <= cnt; c += 8) {  // 4 outstanding gathers/lane
                float2 sw0 = *(const float2*)&wbase[hh * 128 + (c + eb) * 2];
                float2 sw1 = *(const float2*)&wbase[hh * 128 + (c + 2 + eb) * 2];
                float2 sw2 = *(const float2*)&wbase[hh * 128 + (c + 4 + eb) * 2];
                float2 sw3 = *(const float2*)&wbase[hh * 128 + (c + 6 + eb) * 2];
                short8v p0 = *(const short8v*)(h + ((size_t)__float_as_int(sw0.x) << 8) + colb);
                short8v p1 = *(const short8v*)(h + ((size_t)__float_as_int(sw1.x) << 8) + colb);
                short8v p2 = *(const short8v*)(h + ((size_t)__float_as_int(sw2.x) << 8) + colb);
                short8v p3 = *(const short8v*)(h + ((size_t)__float_as_int(sw3.x) << 8) + colb);
                den += sw0.y + sw1.y + sw2.y + sw3.y;
#pragma unroll
                for (int j = 0; j < 8; j++)
                    acc[j] += sw0.y * bf2f((unsigned short)p0[j]) + sw1.y * bf2f((unsigned short)p1[j])
                            + sw2.y * bf2f((unsigned short)p2[j]) + sw3.y * bf2f((unsigned short)p3[j]);
            }
            for (; c + 4 <= cnt; c += 4) {
                float2 sw0 = *(const float2*)&wbase[hh * 128 + (c + eb) * 2];
                float2 sw1 = *(const float2*)&wbase[hh * 128 + (c + 2 + eb) * 2];
                short8v p0 = *(const short8v*)(h + ((size_t)__float_as_int(sw0.x) << 8) + colb);
                short8v p1 = *(const short8v*)(h + ((size_t)__float_as_int(sw1.x) << 8) + colb);
                den += sw0.y + sw1.y;
#pragma unroll
                for (int j = 0; j < 8; j++)
                    acc[j] += sw0.y * bf2f((unsigned short)p0[j]) + sw1.y * bf2f((unsigned short)p1[j]);
            }
            for (; c < cnt; c += 2) {
                int e = c + eb;
                if (e < cnt) {
                    float2 sw0 = *(const float2*)&wbase[hh * 128 + e * 2];
                    short8v p0 = *(const short8v*)(h + ((size_t)__float_as_int(sw0.x) << 8) + colb);
                    den += sw0.y;
#pragma unroll
                    for (int j = 0; j < 8; j++) acc[j] += sw0.y * bf2f((unsigned short)p0[j]);
                }
            }
        }
        den += __shfl_xor(den, 32);
#pragma unroll
        for (int j = 0; j < 8; j++) acc[j] += __shfl_xor(acc[j], 32);
        if (lane < 32) {
            float inv = 1.f / (den + 1e-16f);
            float4 b0 = *(const float4*)&bias[colb];
            float4 b1 = *(const float4*)&bias[colb + 4];
            float of[8];
            of[0] = acc[0] * inv + b0.x; of[1] = acc[1] * inv + b0.y;
            of[2] = acc[2] * inv + b0.z; of[3] = acc[3] * inv + b0.w;
            of[4] = acc[4] * inv + b1.x; of[5] = acc[5] * inv + b1.y;
            of[6] = acc[6] * inv + b1.z; of[7] = acc[7] * inv + b1.w;
            short8v o;
#pragma unroll
            for (int j = 0; j < 8; j++) {
                o[j] = (short)f2bf(of[j]);
                ssum[wid][colb + j] = of[j];
                ssq[wid][colb + j] = of[j] * of[j];
            }
            *(short8v*)(out + ((size_t)n << 8) + colb) = o;
        }
    }
    __syncthreads();
    {
        int sh = blockIdx.x & (NS - 1);
        float s = ssum[0][t] + ssum[1][t] + ssum[2][t] + ssum[3][t];
        float q = ssq[0][t] + ssq[1][t] + ssq[2][t] + ssq[3][t];
        atomicAdd(&bnsh[sh * 512 + t], s);
        atomicAdd(&bnsh[sh * 512 + 256 + t], q);
    }
}

__global__ __launch_bounds__(256) void aggregate2_kernel(const unsigned short* __restrict__ h,
                                                         const int* __restrict__ rowptr,
                                                         const int* __restrict__ srcs,
                                                         const float* __restrict__ a_s,
                                                         const float* __restrict__ a_d,
                                                         const float* __restrict__ bias,
                                                         float* __restrict__ out,
                                                         float* __restrict__ bnsh, int Nn) {
    __shared__ float sw_lds[4 * 128];
    __shared__ float ssum[4][128];
    __shared__ float ssq[4][128];
    const int t = threadIdx.x;
    const int wid = t >> 6, lane = t & 63;
    const int n = blockIdx.x * 4 + wid;
    const int colb = (lane & 15) * 8;
    if (lane < 16) {
#pragma unroll
        for (int j = 0; j < 8; j++) { ssum[wid][colb + j] = 0.f; ssq[wid][colb + j] = 0.f; }
    }
    if (n < Nn) {
        float* wbase = &sw_lds[wid * 128];
        int beg = rowptr[n], end = rowptr[n + 1];
        float ad = a_d[n];
        const int eo = lane >> 4;
        float acc[8] = {0.f, 0.f, 0.f, 0.f, 0.f, 0.f, 0.f, 0.f};
        float den = 0.f, m = -1e30f;

        for (int cb = beg; cb < end; cb += 64) {
            int cnt = end - cb; if (cnt > 64) cnt = 64;
            float e_ = -1e30f;
            int s_l = 0;
            if (lane < cnt) {
                s_l = srcs[cb + lane];
                e_ = lrelu(a_s[s_l] + ad);
            }
            float cm = e_;
            for (int off = 32; off >= 1; off >>= 1) cm = fmaxf(cm, __shfl_xor(cm, off));
            if (cm > m) {
                float f = __expf(m - cm);
                m = cm;
#pragma unroll
                for (int j = 0; j < 8; j++) acc[j] *= f;
                den *= f;
            }
            if (lane < cnt)
                *(float2*)&wbase[lane * 2] = make_float2(__int_as_float(s_l), __expf(e_ - m));
            int c = 0;
            for (; c + 16 <= cnt; c += 16) {  // 4 outstanding gathers/lane
                float2 sw0 = *(const float2*)&wbase[(c + eo) * 2];
                float2 sw1 = *(const float2*)&wbase[(c + 4 + eo) * 2];
                float2 sw2 = *(const float2*)&wbase[(c + 8 + eo) * 2];
                float2 sw3 = *(const float2*)&wbase[(c + 12 + eo) * 2];
                short8v p0 = *(const short8v*)(h + ((size_t)__float_as_int(sw0.x) << 7) + colb);
                short8v p1 = *(const short8v*)(h + ((size_t)__float_as_int(sw1.x) << 7) + colb);
                short8v p2 = *(const short8v*)(h + ((size_t)__float_as_int(sw2.x) << 7) + colb);
                short8v p3 = *(const short8v*)(h + ((size_t)__float_as_int(sw3.x) << 7) + colb);
                den += sw0.y + sw1.y + sw2.y + sw3.y;
#pragma unroll
                for (int j = 0; j < 8; j++)
                    acc[j] += sw0.y * bf2f((unsigned short)p0[j]) + sw1.y * bf2f((unsigned short)p1[j])
                            + sw2.y * bf2f((unsigned short)p2[j]) + sw3.y * bf2f((unsigned short)p3[j]);
            }
            for (; c + 8 <= cnt; c += 8) {
                float2 sw0 = *(const float2*)&wbase[(c + eo) * 2];
                float2 sw1 = *(const float2*)&wbase[(c + 4 + eo) * 2];
                short8v p0 = *(const short8v*)(h + ((size_t)__float_as_int(sw0.x) << 7) + colb);
                short8v p1 = *(const short8v*)(h + ((size_t)__float_as_int(sw1.x) << 7) + colb);
                den += sw0.y + sw1.y;
#pragma unroll
                for (int j = 0; j < 8; j++)
                    acc[j] += sw0.y * bf2f((unsigned short)p0[j]) + sw1.y * bf2f((unsigned short)p1[j]);
            }
            for (; c < cnt; c += 4) {
                int e = c + eo;
                if (e < cnt) {
                    float2 sw0 = *(const float2*)&wbase[e * 2];
                    short8v p0 = *(const short8v*)(h + ((size_t)__float_as_int(sw0.x) << 7) + colb);
                    den += sw0.y;
#pragma unroll
                    for (int j = 0; j < 8; j++) acc[j] += sw0.y * bf2f((unsigned short)p0[j]);
                }
            }
        }
        den += __shfl_xor(den, 16);
        den += __shfl_xor(den, 32);
#pragma unroll
        for (int j = 0; j < 8; j++) {
            acc[j] += __shfl_xor(acc[j], 16);
            acc[j] += __shfl_xor(acc[j], 32);
        }
        if (lane < 16) {
            float inv = 1.f / (den + 1e-16f);
            float4 b0 = *(const float4*)&bias[colb];
            float4 b1 = *(const float4*)&bias[colb + 4];
            float of[8];
            of[0] = acc[0] * inv + b0.x; of[1] = acc[1] * inv + b0.y;
            of[2] = acc[2] * inv + b0.z; of[3] = acc[3] * inv + b0.w;
            of[4] = acc[4] * inv + b1.x; of[5] = acc[5] * inv + b1.y;
            of[6] = acc[6] * inv + b1.z; of[7] = acc[7] * inv + b1.w;
#pragma unroll
            for (int j = 0; j < 8; j++) {
                ssum[wid][colb + j] = of[j];
                ssq[wid][colb + j] = of[j] * of[j];
            }
            float* ob = out + (size_t)n * 128 + colb;
            *(float4*)ob = make_float4(of[0], of[1], of[2], of[3]);
            *(float4*)(ob + 4) = make_float4(of[4], of[5], of[6], of[7]);
        }
    }
    __syncthreads();
    if (t < 128) {
        int sh = blockIdx.x & (NS - 1);
        float s = ssum[0][t] + ssum[1][t] + ssum[2][t] + ssum[3][t];
        atomicAdd(&bnsh[sh * 256 + t], s);
    } else {
        int c = t - 128;
        int sh = blockIdx.x & (NS - 1);
        float q = ssq[0][c] + ssq[1][c] + ssq[2][c] + ssq[3][c];
        atomicAdd(&bnsh[sh * 256 + 128 + c], q);
    }
}

// ---------- final BN+ReLU on f32 output, stats from shadows ----------
__global__ __launch_bounds__(256) void bn_apply_final_kernel(float* __restrict__ x,
                                                             const float* __restrict__ bnsh,
                                                             const float* __restrict__ gamma,
                                                             const float* __restrict__ beta,
                                                             int Nn) {
    int t = threadIdx.x;
    int col = t & 127;
    float s = 0.f, q = 0.f;
#pragma unroll
    for (int sh = 0; sh < NS; sh++) { s += bnsh[sh * 256 + col]; q += bnsh[sh * 256 + 128 + col]; }
    float mu = s / (float)Nn;
    float var = q / (float)Nn - mu * mu;
    float sc = rsqrtf(var + EPS_BN) * gamma[col];
    float sh_ = beta[col] - mu * sc;
    int r0 = blockIdx.x * 2 + (t >> 7);
    int rs = gridDim.x * 2;
    for (int r = r0; r < Nn; r += rs) {
        size_t idx = (size_t)r * 128 + col;
        x[idx] = fmaxf(x[idx] * sc + sh_, 0.f);
    }
}

extern "C" void kernel_launch(void* const* d_in, const int* in_sizes, int n_in,
                              void* d_out, int out_size, void* d_ws, size_t ws_size,
                              hipStream_t stream) {
    const float* x        = (const float*)d_in[0];
    const void*  ei       = d_in[1];
    const float* W1       = (const float*)d_in[2];
    const float* att_src1 = (const float*)d_in[3];
    const float* att_dst1 = (const float*)d_in[4];
    const float* b1       = (const float*)d_in[5];
    const float* g1       = (const float*)d_in[6];
    const float* be1      = (const float*)d_in[7];
    const float* W2       = (const float*)d_in[8];
    const float* att_src2 = (const float*)d_in[9];
    const float* att_dst2 = (const float*)d_in[10];
    const float* b2       = (const float*)d_in[11];
    const float* g2       = (const float*)d_in[12];
    const float* be2      = (const float*)d_in[13];

    const int Nn = in_sizes[0] / IN_DIM;  // 50000
    const int E_ = in_sizes[1] / 2;       // 800000
    const int gb = (Nn + 127) / 128;      // 391 row-blocks
    const int Mpad = gb * 128 + 128;

    char* ws = (char*)d_ws;
    size_t o = 0;
    auto alloc = [&](size_t bytes) {
        size_t r = o;
        o += (bytes + 255) & ~(size_t)255;
        return r;
    };
    int* flag = (int*)(ws + alloc(4));
    // --- single contiguous zero region ---
    size_t z0 = o;
    int*   deg   = (int*)(ws + alloc((size_t)Nn * 4));
    float* as1   = (float*)(ws + alloc((size_t)Nn * 2 * 4));
    float* ad1   = (float*)(ws + alloc((size_t)Nn * 2 * 4));
    float* as2   = (float*)(ws + alloc((size_t)Nn * 4));
    float* ad2   = (float*)(ws + alloc((size_t)Nn * 4));
    float* bn1sh = (float*)(ws + alloc((size_t)NS * 512 * 4));
    float* bn2sh = (float*)(ws + alloc((size_t)NS * 256 * 4));
    size_t z1 = o;
    int*   rowptr = (int*)(ws + alloc((size_t)(Nn + 1) * 4));
    int*   ctr    = (int*)(ws + alloc((size_t)Nn * 4));
    int*   srcs   = (int*)(ws + alloc((size_t)E_ * 4));
    int*   bsum   = (int*)(ws + alloc(256 * 4));
    unsigned short* Wt1  = (unsigned short*)(ws + alloc((size_t)256 * 256 * 2));
    unsigned short* Wt2  = (unsigned short*)(ws + alloc((size_t)128 * 256 * 2));
    unsigned short* xb   = (unsigned short*)(ws + alloc((size_t)Mpad * 256 * 2));
    unsigned short* x2b0 = (unsigned short*)(ws + alloc((size_t)Nn * 256 * 2));
    unsigned short* h1b  = (unsigned short*)(ws + alloc((size_t)Nn * 256 * 2));
    unsigned short* h2b  = (unsigned short*)(ws + alloc((size_t)Nn * 128 * 2));
    float* outf = (float*)d_out;

    hipMemsetAsync(ws + z0, 0, z1 - z0, stream);

    {
        long long n8 = (long long)Nn * 256 / 8;
        long long grid = (n8 + 255) / 256 + 256 + 128 + 1;
        prep_kernel<<<(int)grid, 256, 0, stream>>>(x, xb, n8, W1, Wt1, W2, Wt2,
                                                   (const unsigned int*)ei, flag,
                                                   (long long)2 * E_);
    }

    int eb = (E_ + 255) / 256;
    int nsb = (Nn + 255) / 256;  // <= 256
    count_deg_kernel<<<eb, 256, 0, stream>>>(ei, flag, deg, E_);
    scan_partial_kernel<<<nsb, 256, 0, stream>>>(deg, bsum, Nn);
    scan_write_kernel<<<nsb, 256, 0, stream>>>(deg, bsum, rowptr, ctr, Nn, nsb);
    scatter_kernel<<<eb, 256, 0, stream>>>(ei, flag, ctr, srcs, E_);

    int nb4 = (Nn + 3) / 4;

    // layer 1
    gemm_mfma_kernel<256, 2, false><<<dim3(gb, 4), 256, 0, stream>>>(
        xb, Wt1, h1b, att_src1, att_dst1, as1, ad1, Nn, nullptr, nullptr, nullptr);
    aggregate1_kernel<<<nb4, 256, 0, stream>>>(h1b, rowptr, srcs, as1, ad1, b1, x2b0, bn1sh, Nn);

    // layer 2 (BN1-apply+ReLU fused into GEMM2's A reg-staging)
    gemm_mfma_kernel<128, 1, true><<<dim3(gb, 2), 256, 0, stream>>>(
        x2b0, Wt2, h2b, att_src2, att_dst2, as2, ad2, Nn, bn1sh, g1, be1);
    aggregate2_kernel<<<nb4, 256, 0, stream>>>(h2b, rowptr, srcs, as2, ad2, b2, outf, bn2sh, Nn);
    bn_apply_final_kernel<<<512, 256, 0, stream>>>(outf, bn2sh, g2, be2, Nn);
}

// Round 8
// 295.596 us; speedup vs baseline: 2.5052x; 1.0359x over previous
//
#include <hip/hip_runtime.h>
#include <math.h>

#define IN_DIM 256
#define EPS_BN 1e-5f
#define NS 16  // BN shadow-copy count (atomic contention spreader)

typedef __attribute__((ext_vector_type(8))) short short8v;  // 8 bf16 (4 VGPRs)
typedef __attribute__((ext_vector_type(4))) float f32x4;    // MFMA C/D

__device__ __forceinline__ float lrelu(float v) { return v > 0.f ? v : 0.2f * v; }

__device__ __forceinline__ unsigned short f2bf(float f) {
    unsigned int u = __float_as_uint(f);
    u += 0x7fffu + ((u >> 16) & 1u);
    return (unsigned short)(u >> 16);
}
__device__ __forceinline__ float bf2f(unsigned short s) {
    return __uint_as_float((unsigned int)s << 16);
}

__device__ __forceinline__ void gld16(const void* g, void* l) {
    __builtin_amdgcn_global_load_lds((const __attribute__((address_space(1))) void*)g,
                                     (__attribute__((address_space(3))) void*)l, 16, 0, 0);
}

__device__ __forceinline__ int edge_at(const void* ei, int is64, long long i) {
    if (is64) return (int)((const long long*)ei)[i];
    return ((const int*)ei)[i];
}

// ---------- combined prep: bf16(x), Wt1, Wt2, edge-dtype detect — one launch ----------
__global__ __launch_bounds__(256) void prep_kernel(const float* __restrict__ x,
                                                   unsigned short* __restrict__ xb, long long n8,
                                                   const float* __restrict__ W1,
                                                   unsigned short* __restrict__ Wt1,
                                                   const float* __restrict__ W2,
                                                   unsigned short* __restrict__ Wt2,
                                                   const unsigned int* __restrict__ eiw,
                                                   int* __restrict__ flag, long long nwords) {
    __shared__ int nz;
    long long nbx = (n8 + 255) / 256;
    long long b = blockIdx.x;
    if (b < nbx) {
        long long i = b * 256 + threadIdx.x;
        if (i < n8) {
            const float4* p = (const float4*)(x + i * 8);
            float4 v0 = p[0], v1 = p[1];
            ushort4 o0, o1;
            o0.x = f2bf(v0.x); o0.y = f2bf(v0.y); o0.z = f2bf(v0.z); o0.w = f2bf(v0.w);
            o1.x = f2bf(v1.x); o1.y = f2bf(v1.y); o1.z = f2bf(v1.z); o1.w = f2bf(v1.w);
            *(ushort4*)(xb + i * 8) = o0;
            *(ushort4*)(xb + i * 8 + 4) = o1;
        }
        return;
    }
    b -= nbx;
    if (b < 256) {  // Wt1[c][k] = bf16(W1[k][c]), 256x256
        int idx = (int)b * 256 + threadIdx.x;
        int c = idx >> 8, k = idx & 255;
        Wt1[idx] = f2bf(W1[(long long)k * 256 + c]);
        return;
    }
    b -= 256;
    if (b < 128) {  // Wt2[c][k] = bf16(W2[k][c]), 128x256
        int idx = (int)b * 256 + threadIdx.x;
        int c = idx >> 8, k = idx & 255;
        Wt2[idx] = f2bf(W2[(long long)k * 128 + c]);
        return;
    }
    // last block: int32-vs-int64 detection (odd 32-bit words all zero -> int64)
    if (threadIdx.x == 0) nz = 0;
    __syncthreads();
    int cnt = 0;
    for (int i = 0; i < 4; i++) {
        long long idx = 2LL * (threadIdx.x + i * 256) + 1;
        if (idx < nwords && eiw[idx] != 0u) cnt++;
    }
    if (cnt) atomicAdd(&nz, 1);
    __syncthreads();
    if (threadIdx.x == 0) flag[0] = (nz == 0) ? 1 : 0;
}

// ---------- CSR build ----------
__global__ void count_deg_kernel(const void* __restrict__ ei, const int* __restrict__ flag,
                                 int* __restrict__ deg, int E_) {
    int is64 = flag[0];
    int i = blockIdx.x * 256 + threadIdx.x;
    if (i < E_) {
        int d = edge_at(ei, is64, (long long)E_ + i);
        atomicAdd(&deg[d], 1);
    }
}

__global__ __launch_bounds__(256) void scan_partial_kernel(const int* __restrict__ deg,
                                                           int* __restrict__ bsum, int n) {
    __shared__ int sh[256];
    int t = threadIdx.x;
    int i = blockIdx.x * 256 + t;
    sh[t] = (i < n) ? deg[i] : 0;
    __syncthreads();
    for (int off = 128; off >= 1; off >>= 1) {
        if (t < off) sh[t] += sh[t + off];
        __syncthreads();
    }
    if (t == 0) bsum[blockIdx.x] = sh[0];
}

__global__ __launch_bounds__(256) void scan_write_kernel(const int* __restrict__ deg,
                                                         const int* __restrict__ bsum,
                                                         int* __restrict__ rowptr,
                                                         int* __restrict__ ctr, int n, int nb) {
    __shared__ int sh[256];
    __shared__ int base_sh;
    int t = threadIdx.x;
    int b = blockIdx.x;
    sh[t] = (t < b) ? bsum[t] : 0;
    __syncthreads();
    for (int off = 128; off >= 1; off >>= 1) {
        if (t < off) sh[t] += sh[t + off];
        __syncthreads();
    }
    if (t == 0) base_sh = sh[0];
    __syncthreads();
    int i = b * 256 + t;
    int d = (i < n) ? deg[i] : 0;
    sh[t] = d;
    __syncthreads();
    for (int off = 1; off < 256; off <<= 1) {
        int u = (t >= off) ? sh[t - off] : 0;
        __syncthreads();
        sh[t] += u;
        __syncthreads();
    }
    if (i < n) {
        int v = base_sh + sh[t] - d;
        rowptr[i] = v;
        ctr[i] = v;
    }
    if (b == nb - 1 && t == 255) rowptr[n] = base_sh + sh[255];
}

__global__ void scatter_kernel(const void* __restrict__ ei, const int* __restrict__ flag,
                               int* __restrict__ ctr, int* __restrict__ srcs, int E_) {
    int is64 = flag[0];
    int i = blockIdx.x * 256 + threadIdx.x;
    if (i < E_) {
        int s = edge_at(ei, is64, i);
        int d = edge_at(ei, is64, (long long)E_ + i);
        int pos = atomicAdd(&ctr[d], 1);
        srcs[pos] = s;
    }
}

// ---------- MFMA bf16 GEMM + fused attn-coef epilogue (+ optional fused BN on A) ----------
template <int NCOL, int NH, bool FUSEBN>
__global__ __launch_bounds__(256) void gemm_mfma_kernel(const unsigned short* __restrict__ Ab,
                                                        const unsigned short* __restrict__ Wt,
                                                        unsigned short* __restrict__ C,
                                                        const float* __restrict__ att_s,
                                                        const float* __restrict__ att_d,
                                                        float* __restrict__ a_s,
                                                        float* __restrict__ a_d, int M,
                                                        const float* __restrict__ bnsh,
                                                        const float* __restrict__ gamma,
                                                        const float* __restrict__ beta) {
    __shared__ unsigned short B_lds[64 * 256];   // 32 KB
    __shared__ unsigned short A_lds[128 * 64];   // 16 KB
    __shared__ float scs[FUSEBN ? 256 : 1];
    __shared__ float shs[FUSEBN ? 256 : 1];
    const int t = threadIdx.x;
    const int w = t >> 6, l = t & 63;
    const int row0 = blockIdx.x * 128;
    const int col0 = blockIdx.y * 64;

    // stage B [64 cols][256 k] once (pre-swizzled source, linear LDS dest)
    {
        const char* wb = (const char*)Wt + (size_t)col0 * 512;
#pragma unroll
        for (int it = 0; it < 8; ++it) {
            int q = w * 8 + it;
            int i = q * 64 + l;
            int r = i >> 5;
            int cs = (i & 31) ^ (r & 7);
            gld16(wb + (size_t)r * 512 + cs * 16, (char*)B_lds + q * 1024);
        }
    }

    short8v nxt[4];
    const char* ab = (const char*)Ab + (size_t)row0 * 512;

    if (FUSEBN) {
        {
            int c = t;
            float s = 0.f, q = 0.f;
#pragma unroll
            for (int sh = 0; sh < NS; sh++) { s += bnsh[sh * 512 + c]; q += bnsh[sh * 512 + 256 + c]; }
            float invN = 1.f / (float)M;
            float mu = s * invN;
            float var = q * invN - mu * mu;
            float sc = rsqrtf(var + EPS_BN) * gamma[c];
            scs[c] = sc;
            shs[c] = beta[c] - mu * sc;
        }
#pragma unroll
        for (int it = 0; it < 4; ++it) {
            int i = it * 256 + t;
            int r = i >> 3, g = i & 7;
            int gr = row0 + r;
            nxt[it] = (gr < M) ? *(const short8v*)(Ab + (size_t)gr * 256 + g * 8)
                               : (short8v)(short)0;
        }
        __syncthreads();
#pragma unroll
        for (int it = 0; it < 4; ++it) {
            int i = it * 256 + t;
            int r = i >> 3, g = i & 7;
            int kb = g * 8;
            float4 s0 = *(const float4*)&scs[kb], s1 = *(const float4*)&scs[kb + 4];
            float4 h0 = *(const float4*)&shs[kb], h1 = *(const float4*)&shs[kb + 4];
            short8v v = nxt[it];
            short8v ov;
            ov[0] = (short)f2bf(fmaxf(bf2f((unsigned short)v[0]) * s0.x + h0.x, 0.f));
            ov[1] = (short)f2bf(fmaxf(bf2f((unsigned short)v[1]) * s0.y + h0.y, 0.f));
            ov[2] = (short)f2bf(fmaxf(bf2f((unsigned short)v[2]) * s0.z + h0.z, 0.f));
            ov[3] = (short)f2bf(fmaxf(bf2f((unsigned short)v[3]) * s0.w + h0.w, 0.f));
            ov[4] = (short)f2bf(fmaxf(bf2f((unsigned short)v[4]) * s1.x + h1.x, 0.f));
            ov[5] = (short)f2bf(fmaxf(bf2f((unsigned short)v[5]) * s1.y + h1.y, 0.f));
            ov[6] = (short)f2bf(fmaxf(bf2f((unsigned short)v[6]) * s1.z + h1.z, 0.f));
            ov[7] = (short)f2bf(fmaxf(bf2f((unsigned short)v[7]) * s1.w + h1.w, 0.f));
            *(short8v*)((char*)A_lds + r * 128 + ((g ^ (r & 7)) << 4)) = ov;
        }
    } else {
#pragma unroll
        for (int it = 0; it < 4; ++it) {
            int q = w * 4 + it;
            int i = q * 64 + l;
            int r = i >> 3;
            int cs = (i & 7) ^ (r & 7);
            gld16(ab + (size_t)r * 512 + cs * 16, (char*)A_lds + q * 1024);
        }
    }
    __syncthreads();

    const int rl = l & 15, kg = l >> 4;
    f32x4 acc0[4], acc1[4];
#pragma unroll
    for (int i = 0; i < 4; ++i) { acc0[i] = (f32x4)(0.f); acc1[i] = (f32x4)(0.f); }

    const int ar0 = w * 32 + rl, ar1 = ar0 + 16;
    const int aswz = (ar0 & 7) << 4;

    for (int c = 0; c < 4; ++c) {
        if (FUSEBN && c < 3) {
#pragma unroll
            for (int it = 0; it < 4; ++it) {
                int i = it * 256 + t;
                int r = i >> 3, g = i & 7;
                int gr = row0 + r;
                nxt[it] = (gr < M) ? *(const short8v*)(Ab + (size_t)gr * 256 + (c + 1) * 64 + g * 8)
                                   : (short8v)(short)0;
            }
        }
#pragma unroll
        for (int s = 0; s < 2; ++s) {
            short8v a0 = *(const short8v*)((const char*)A_lds +
                          ((ar0 * 128 + s * 64 + kg * 16) ^ aswz));
            short8v a1 = *(const short8v*)((const char*)A_lds +
                          ((ar1 * 128 + s * 64 + kg * 16) ^ aswz));
#pragma unroll
            for (int ct = 0; ct < 4; ++ct) {
                int br = ct * 16 + rl;
                short8v bfr = *(const short8v*)((const char*)B_lds +
                               ((br * 512 + c * 128 + s * 64 + kg * 16) ^ ((br & 7) << 4)));
                acc0[ct] = __builtin_amdgcn_mfma_f32_16x16x32_bf16(a0, bfr, acc0[ct], 0, 0, 0);
                acc1[ct] = __builtin_amdgcn_mfma_f32_16x16x32_bf16(a1, bfr, acc1[ct], 0, 0, 0);
            }
        }
        __syncthreads();
        if (c < 3) {
            if (FUSEBN) {
#pragma unroll
                for (int it = 0; it < 4; ++it) {
                    int i = it * 256 + t;
                    int r = i >> 3, g = i & 7;
                    int kb = (c + 1) * 64 + g * 8;
                    float4 s0 = *(const float4*)&scs[kb], s1 = *(const float4*)&scs[kb + 4];
                    float4 h0 = *(const float4*)&shs[kb], h1 = *(const float4*)&shs[kb + 4];
                    short8v v = nxt[it];
                    short8v ov;
                    ov[0] = (short)f2bf(fmaxf(bf2f((unsigned short)v[0]) * s0.x + h0.x, 0.f));
                    ov[1] = (short)f2bf(fmaxf(bf2f((unsigned short)v[1]) * s0.y + h0.y, 0.f));
                    ov[2] = (short)f2bf(fmaxf(bf2f((unsigned short)v[2]) * s0.z + h0.z, 0.f));
                    ov[3] = (short)f2bf(fmaxf(bf2f((unsigned short)v[3]) * s0.w + h0.w, 0.f));
                    ov[4] = (short)f2bf(fmaxf(bf2f((unsigned short)v[4]) * s1.x + h1.x, 0.f));
                    ov[5] = (short)f2bf(fmaxf(bf2f((unsigned short)v[5]) * s1.y + h1.y, 0.f));
                    ov[6] = (short)f2bf(fmaxf(bf2f((unsigned short)v[6]) * s1.z + h1.z, 0.f));
                    ov[7] = (short)f2bf(fmaxf(bf2f((unsigned short)v[7]) * s1.w + h1.w, 0.f));
                    *(short8v*)((char*)A_lds + r * 128 + ((g ^ (r & 7)) << 4)) = ov;
                }
            } else {
#pragma unroll
                for (int it = 0; it < 4; ++it) {
                    int q = w * 4 + it;
                    int i = q * 64 + l;
                    int r = i >> 3;
                    int cs = (i & 7) ^ (r & 7);
                    gld16(ab + (size_t)r * 512 + (c + 1) * 128 + cs * 16, (char*)A_lds + q * 1024);
                }
            }
            __syncthreads();
        }
    }

    // C store (bf16)
#pragma unroll
    for (int ct = 0; ct < 4; ++ct) {
#pragma unroll
        for (int r = 0; r < 4; ++r) {
            int gr0 = row0 + w * 32 + kg * 4 + r;
            if (gr0 < M) C[(long long)gr0 * NCOL + col0 + ct * 16 + rl] = f2bf(acc0[ct][r]);
            int gr1 = gr0 + 16;
            if (gr1 < M) C[(long long)gr1 * NCOL + col0 + ct * 16 + rl] = f2bf(acc1[ct][r]);
        }
    }

    // fused attention-coefficient partial dots (f32, pre-round acc)
    float asp0[4] = {}, adp0[4] = {}, asp1[4] = {}, adp1[4] = {};
#pragma unroll
    for (int ct = 0; ct < 4; ++ct) {
        int col = col0 + ct * 16 + rl;
        float vs = att_s[col], vd = att_d[col];
#pragma unroll
        for (int r = 0; r < 4; ++r) {
            asp0[r] += acc0[ct][r] * vs; adp0[r] += acc0[ct][r] * vd;
            asp1[r] += acc1[ct][r] * vs; adp1[r] += acc1[ct][r] * vd;
        }
    }
#pragma unroll
    for (int off = 1; off < 16; off <<= 1) {
#pragma unroll
        for (int r = 0; r < 4; ++r) {
            asp0[r] += __shfl_xor(asp0[r], off);
            adp0[r] += __shfl_xor(adp0[r], off);
            asp1[r] += __shfl_xor(asp1[r], off);
            adp1[r] += __shfl_xor(adp1[r], off);
        }
    }
    if (rl == 0) {
        int head = (NH == 2) ? (col0 >> 7) : 0;
#pragma unroll
        for (int r = 0; r < 4; ++r) {
            int gr0 = row0 + w * 32 + kg * 4 + r;
            if (gr0 < M) {
                atomicAdd(&a_s[gr0 * NH + head], asp0[r]);
                atomicAdd(&a_d[gr0 * NH + head], adp0[r]);
            }
            int gr1 = gr0 + 16;
            if (gr1 < M) {
                atomicAdd(&a_s[gr1 * NH + head], asp1[r]);
                atomicAdd(&a_d[gr1 * NH + head], adp1[r]);
            }
        }
    }
}

// ---------- softmax + aggregation: persistent waves, grid-stride over nodes ----------
// BN partials accumulate in registers across the wave's nodes; one LDS reduce +
// atomic set per block at the end (reuses sw_lds).
__global__ __launch_bounds__(256) void aggregate1_kernel(const unsigned short* __restrict__ h,
                                                         const int* __restrict__ rowptr,
                                                         const int* __restrict__ srcs,
                                                         const float* __restrict__ a_s,
                                                         const float* __restrict__ a_d,
                                                         const float* __restrict__ bias,
                                                         unsigned short* __restrict__ out,
                                                         float* __restrict__ bnsh, int Nn) {
    __shared__ float sw_lds[4][256];
    const int t = threadIdx.x;
    const int wid = t >> 6, lane = t & 63;
    const int hh = (lane >> 4) & 1;
    const int eb = lane >> 5;
    const int colb = (lane & 31) * 8;
    float* wbase = sw_lds[wid];
    float bnsum[8] = {}, bnsq[8] = {};
    const int stride = gridDim.x * 4;

    for (int n = blockIdx.x * 4 + wid; n < Nn; n += stride) {
        int beg = rowptr[n], end = rowptr[n + 1];
        float2 adv = *(const float2*)&a_d[(size_t)n * 2];
        float ad0 = adv.x, ad1 = adv.y;
        float acc[8] = {0.f, 0.f, 0.f, 0.f, 0.f, 0.f, 0.f, 0.f};
        float den = 0.f, m0 = -1e30f, m1 = -1e30f;

        for (int cb = beg; cb < end; cb += 64) {
            int cnt = end - cb; if (cnt > 64) cnt = 64;
            float e0 = -1e30f, e1 = -1e30f;
            int s_l = 0;
            if (lane < cnt) {
                s_l = srcs[cb + lane];
                float2 av = *(const float2*)&a_s[(size_t)s_l * 2];
                e0 = lrelu(av.x + ad0);
                e1 = lrelu(av.y + ad1);
            }
            float cm0 = e0, cm1 = e1;
            for (int off = 32; off >= 1; off >>= 1) {
                cm0 = fmaxf(cm0, __shfl_xor(cm0, off));
                cm1 = fmaxf(cm1, __shfl_xor(cm1, off));
            }
            if (cm0 > m0 || cm1 > m1) {  // wave-uniform rescale (skip when max stable)
                float f0 = (cm0 > m0) ? __expf(m0 - cm0) : 1.f;
                float f1 = (cm1 > m1) ? __expf(m1 - cm1) : 1.f;
                m0 = fmaxf(m0, cm0); m1 = fmaxf(m1, cm1);
                float fo = hh ? f1 : f0;
#pragma unroll
                for (int j = 0; j < 8; j++) acc[j] *= fo;
                den *= fo;
            }
            if (lane < cnt) {
                *(float2*)&wbase[lane * 2] = make_float2(__int_as_float(s_l), __expf(e0 - m0));
                *(float2*)&wbase[128 + lane * 2] = make_float2(__int_as_float(s_l), __expf(e1 - m1));
            }
            int c = 0;
            for (; c + 8 <= cnt; c += 8) {
                float2 sw0 = *(const float2*)&wbase[hh * 128 + (c + eb) * 2];
                float2 sw1 = *(const float2*)&wbase[hh * 128 + (c + 2 + eb) * 2];
                float2 sw2 = *(const float2*)&wbase[hh * 128 + (c + 4 + eb) * 2];
                float2 sw3 = *(const float2*)&wbase[hh * 128 + (c + 6 + eb) * 2];
                short8v p0 = *(const short8v*)(h + ((size_t)__float_as_int(sw0.x) << 8) + colb);
                short8v p1 = *(const short8v*)(h + ((size_t)__float_as_int(sw1.x) << 8) + colb);
                short8v p2 = *(const short8v*)(h + ((size_t)__float_as_int(sw2.x) << 8) + colb);
                short8v p3 = *(const short8v*)(h + ((size_t)__float_as_int(sw3.x) << 8) + colb);
                den += sw0.y + sw1.y + sw2.y + sw3.y;
#pragma unroll
                for (int j = 0; j < 8; j++)
                    acc[j] += sw0.y * bf2f((unsigned short)p0[j]) + sw1.y * bf2f((unsigned short)p1[j])
                            + sw2.y * bf2f((unsigned short)p2[j]) + sw3.y * bf2f((unsigned short)p3[j]);
            }
            for (; c + 4 <= cnt; c += 4) {
                float2 sw0 = *(const float2*)&wbase[hh * 128 + (c + eb) * 2];
                float2 sw1 = *(const float2*)&wbase[hh * 128 + (c + 2 + eb) * 2];
                short8v p0 = *(const short8v*)(h + ((size_t)__float_as_int(sw0.x) << 8) + colb);
                short8v p1 = *(const short8v*)(h + ((size_t)__float_as_int(sw1.x) << 8) + colb);
                den += sw0.y + sw1.y;
#pragma unroll
                for (int j = 0; j < 8; j++)
                    acc[j] += sw0.y * bf2f((unsigned short)p0[j]) + sw1.y * bf2f((unsigned short)p1[j]);
            }
            for (; c < cnt; c += 2) {
                int e = c + eb;
                if (e < cnt) {
                    float2 sw0 = *(const float2*)&wbase[hh * 128 + e * 2];
                    short8v p0 = *(const short8v*)(h + ((size_t)__float_as_int(sw0.x) << 8) + colb);
                    den += sw0.y;
#pragma unroll
                    for (int j = 0; j < 8; j++) acc[j] += sw0.y * bf2f((unsigned short)p0[j]);
                }
            }
        }
        den += __shfl_xor(den, 32);
#pragma unroll
        for (int j = 0; j < 8; j++) acc[j] += __shfl_xor(acc[j], 32);
        if (lane < 32) {
            float inv = 1.f / (den + 1e-16f);
            float4 b0 = *(const float4*)&bias[colb];
            float4 b1 = *(const float4*)&bias[colb + 4];
            float of[8];
            of[0] = acc[0] * inv + b0.x; of[1] = acc[1] * inv + b0.y;
            of[2] = acc[2] * inv + b0.z; of[3] = acc[3] * inv + b0.w;
            of[4] = acc[4] * inv + b1.x; of[5] = acc[5] * inv + b1.y;
            of[6] = acc[6] * inv + b1.z; of[7] = acc[7] * inv + b1.w;
            short8v o;
#pragma unroll
            for (int j = 0; j < 8; j++) {
                o[j] = (short)f2bf(of[j]);
                bnsum[j] += of[j];
                bnsq[j] += of[j] * of[j];
            }
            *(short8v*)(out + ((size_t)n << 8) + colb) = o;
        }
    }

    // once-per-block BN reduction (reuse sw_lds)
    __syncthreads();
    if (lane < 32) {
#pragma unroll
        for (int j = 0; j < 8; j++) wbase[colb + j] = bnsum[j];
    }
    __syncthreads();
    {
        int sh = (blockIdx.x & (NS - 1)) * 512;
        float s = sw_lds[0][t] + sw_lds[1][t] + sw_lds[2][t] + sw_lds[3][t];
        atomicAdd(&bnsh[sh + t], s);
    }
    __syncthreads();
    if (lane < 32) {
#pragma unroll
        for (int j = 0; j < 8; j++) wbase[colb + j] = bnsq[j];
    }
    __syncthreads();
    {
        int sh = (blockIdx.x & (NS - 1)) * 512;
        float q = sw_lds[0][t] + sw_lds[1][t] + sw_lds[2][t] + sw_lds[3][t];
        atomicAdd(&bnsh[sh + 256 + t], q);
    }
}

__global__ __launch_bounds__(256) void aggregate2_kernel(const unsigned short* __restrict__ h,
                                                         const int* __restrict__ rowptr,
                                                         const int* __restrict__ srcs,
                                                         const float* __restrict__ a_s,
                                                         const float* __restrict__ a_d,
                                                         const float* __restrict__ bias,
                                                         float* __restrict__ out,
                                                         float* __restrict__ bnsh, int Nn) {
    __shared__ float sw_lds[4][128];
    const int t = threadIdx.x;
    const int wid = t >> 6, lane = t & 63;
    const int eo = lane >> 4;
    const int colb = (lane & 15) * 8;
    float* wbase = sw_lds[wid];
    float bnsum[8] = {}, bnsq[8] = {};
    const int stride = gridDim.x * 4;

    for (int n = blockIdx.x * 4 + wid; n < Nn; n += stride) {
        int beg = rowptr[n], end = rowptr[n + 1];
        float ad = a_d[n];
        float acc[8] = {0.f, 0.f, 0.f, 0.f, 0.f, 0.f, 0.f, 0.f};
        float den = 0.f, m = -1e30f;

        for (int cb = beg; cb < end; cb += 64) {
            int cnt = end - cb; if (cnt > 64) cnt = 64;
            float e_ = -1e30f;
            int s_l = 0;
            if (lane < cnt) {
                s_l = srcs[cb + lane];
                e_ = lrelu(a_s[s_l] + ad);
            }
            float cm = e_;
            for (int off = 32; off >= 1; off >>= 1) cm = fmaxf(cm, __shfl_xor(cm, off));
            if (cm > m) {
                float f = __expf(m - cm);
                m = cm;
#pragma unroll
                for (int j = 0; j < 8; j++) acc[j] *= f;
                den *= f;
            }
            if (lane < cnt)
                *(float2*)&wbase[lane * 2] = make_float2(__int_as_float(s_l), __expf(e_ - m));
            int c = 0;
            for (; c + 16 <= cnt; c += 16) {
                float2 sw0 = *(const float2*)&wbase[(c + eo) * 2];
                float2 sw1 = *(const float2*)&wbase[(c + 4 + eo) * 2];
                float2 sw2 = *(const float2*)&wbase[(c + 8 + eo) * 2];
                float2 sw3 = *(const float2*)&wbase[(c + 12 + eo) * 2];
                short8v p0 = *(const short8v*)(h + ((size_t)__float_as_int(sw0.x) << 7) + colb);
                short8v p1 = *(const short8v*)(h + ((size_t)__float_as_int(sw1.x) << 7) + colb);
                short8v p2 = *(const short8v*)(h + ((size_t)__float_as_int(sw2.x) << 7) + colb);
                short8v p3 = *(const short8v*)(h + ((size_t)__float_as_int(sw3.x) << 7) + colb);
                den += sw0.y + sw1.y + sw2.y + sw3.y;
#pragma unroll
                for (int j = 0; j < 8; j++)
                    acc[j] += sw0.y * bf2f((unsigned short)p0[j]) + sw1.y * bf2f((unsigned short)p1[j])
                            + sw2.y * bf2f((unsigned short)p2[j]) + sw3.y * bf2f((unsigned short)p3[j]);
            }
            for (; c + 8 <= cnt; c += 8) {
                float2 sw0 = *(const float2*)&wbase[(c + eo) * 2];
                float2 sw1 = *(const float2*)&wbase[(c + 4 + eo) * 2];
                short8v p0 = *(const short8v*)(h + ((size_t)__float_as_int(sw0.x) << 7) + colb);
                short8v p1 = *(const short8v*)(h + ((size_t)__float_as_int(sw1.x) << 7) + colb);
                den += sw0.y + sw1.y;
#pragma unroll
                for (int j = 0; j < 8; j++)
                    acc[j] += sw0.y * bf2f((unsigned short)p0[j]) + sw1.y * bf2f((unsigned short)p1[j]);
            }
            for (; c < cnt; c += 4) {
                int e = c + eo;
                if (e < cnt) {
                    float2 sw0 = *(const float2*)&wbase[e * 2];
                    short8v p0 = *(const short8v*)(h + ((size_t)__float_as_int(sw0.x) << 7) + colb);
                    den += sw0.y;
#pragma unroll
                    for (int j = 0; j < 8; j++) acc[j] += sw0.y * bf2f((unsigned short)p0[j]);
                }
            }
        }
        den += __shfl_xor(den, 16);
        den += __shfl_xor(den, 32);
#pragma unroll
        for (int j = 0; j < 8; j++) {
            acc[j] += __shfl_xor(acc[j], 16);
            acc[j] += __shfl_xor(acc[j], 32);
        }
        if (lane < 16) {
            float inv = 1.f / (den + 1e-16f);
            float4 b0 = *(const float4*)&bias[colb];
            float4 b1 = *(const float4*)&bias[colb + 4];
            float of[8];
            of[0] = acc[0] * inv + b0.x; of[1] = acc[1] * inv + b0.y;
            of[2] = acc[2] * inv + b0.z; of[3] = acc[3] * inv + b0.w;
            of[4] = acc[4] * inv + b1.x; of[5] = acc[5] * inv + b1.y;
            of[6] = acc[6] * inv + b1.z; of[7] = acc[7] * inv + b1.w;
#pragma unroll
            for (int j = 0; j < 8; j++) {
                bnsum[j] += of[j];
                bnsq[j] += of[j] * of[j];
            }
            float* ob = out + (size_t)n * 128 + colb;
            *(float4*)ob = make_float4(of[0], of[1], of[2], of[3]);
            *(float4*)(ob + 4) = make_float4(of[4], of[5], of[6], of[7]);
        }
    }

    __syncthreads();
    if (lane < 16) {
#pragma unroll
        for (int j = 0; j < 8; j++) wbase[colb + j] = bnsum[j];
    }
    __syncthreads();
    if (t < 128) {
        int sh = (blockIdx.x & (NS - 1)) * 256;
        float s = sw_lds[0][t] + sw_lds[1][t] + sw_lds[2][t] + sw_lds[3][t];
        atomicAdd(&bnsh[sh + t], s);
    }
    __syncthreads();
    if (lane < 16) {
#pragma unroll
        for (int j = 0; j < 8; j++) wbase[colb + j] = bnsq[j];
    }
    __syncthreads();
    if (t < 128) {
        int sh = (blockIdx.x & (NS - 1)) * 256;
        float q = sw_lds[0][t] + sw_lds[1][t] + sw_lds[2][t] + sw_lds[3][t];
        atomicAdd(&bnsh[sh + 128 + t], q);
    }
}

// ---------- final BN+ReLU on f32 output, stats from shadows ----------
__global__ __launch_bounds__(256) void bn_apply_final_kernel(float* __restrict__ x,
                                                             const float* __restrict__ bnsh,
                                                             const float* __restrict__ gamma,
                                                             const float* __restrict__ beta,
                                                             int Nn) {
    int t = threadIdx.x;
    int col = t & 127;
    float s = 0.f, q = 0.f;
#pragma unroll
    for (int sh = 0; sh < NS; sh++) { s += bnsh[sh * 256 + col]; q += bnsh[sh * 256 + 128 + col]; }
    float mu = s / (float)Nn;
    float var = q / (float)Nn - mu * mu;
    float sc = rsqrtf(var + EPS_BN) * gamma[col];
    float sh_ = beta[col] - mu * sc;
    int r0 = blockIdx.x * 2 + (t >> 7);
    int rs = gridDim.x * 2;
    for (int r = r0; r < Nn; r += rs) {
        size_t idx = (size_t)r * 128 + col;
        x[idx] = fmaxf(x[idx] * sc + sh_, 0.f);
    }
}

extern "C" void kernel_launch(void* const* d_in, const int* in_sizes, int n_in,
                              void* d_out, int out_size, void* d_ws, size_t ws_size,
                              hipStream_t stream) {
    const float* x        = (const float*)d_in[0];
    const void*  ei       = d_in[1];
    const float* W1       = (const float*)d_in[2];
    const float* att_src1 = (const float*)d_in[3];
    const float* att_dst1 = (const float*)d_in[4];
    const float* b1       = (const float*)d_in[5];
    const float* g1       = (const float*)d_in[6];
    const float* be1      = (const float*)d_in[7];
    const float* W2       = (const float*)d_in[8];
    const float* att_src2 = (const float*)d_in[9];
    const float* att_dst2 = (const float*)d_in[10];
    const float* b2       = (const float*)d_in[11];
    const float* g2       = (const float*)d_in[12];
    const float* be2      = (const float*)d_in[13];

    const int Nn = in_sizes[0] / IN_DIM;  // 50000
    const int E_ = in_sizes[1] / 2;       // 800000
    const int gb = (Nn + 127) / 128;      // 391 row-blocks
    const int Mpad = gb * 128 + 128;

    char* ws = (char*)d_ws;
    size_t o = 0;
    auto alloc = [&](size_t bytes) {
        size_t r = o;
        o += (bytes + 255) & ~(size_t)255;
        return r;
    };
    int* flag = (int*)(ws + alloc(4));
    size_t z0 = o;
    int*   deg   = (int*)(ws + alloc((size_t)Nn * 4));
    float* as1   = (float*)(ws + alloc((size_t)Nn * 2 * 4));
    float* ad1   = (float*)(ws + alloc((size_t)Nn * 2 * 4));
    float* as2   = (float*)(ws + alloc((size_t)Nn * 4));
    float* ad2   = (float*)(ws + alloc((size_t)Nn * 4));
    float* bn1sh = (float*)(ws + alloc((size_t)NS * 512 * 4));
    float* bn2sh = (float*)(ws + alloc((size_t)NS * 256 * 4));
    size_t z1 = o;
    int*   rowptr = (int*)(ws + alloc((size_t)(Nn + 1) * 4));
    int*   ctr    = (int*)(ws + alloc((size_t)Nn * 4));
    int*   srcs   = (int*)(ws + alloc((size_t)E_ * 4));
    int*   bsum   = (int*)(ws + alloc(256 * 4));
    unsigned short* Wt1  = (unsigned short*)(ws + alloc((size_t)256 * 256 * 2));
    unsigned short* Wt2  = (unsigned short*)(ws + alloc((size_t)128 * 256 * 2));
    unsigned short* xb   = (unsigned short*)(ws + alloc((size_t)Mpad * 256 * 2));
    unsigned short* x2b0 = (unsigned short*)(ws + alloc((size_t)Nn * 256 * 2));
    unsigned short* h1b  = (unsigned short*)(ws + alloc((size_t)Nn * 256 * 2));
    unsigned short* h2b  = (unsigned short*)(ws + alloc((size_t)Nn * 128 * 2));
    float* outf = (float*)d_out;

    hipMemsetAsync(ws + z0, 0, z1 - z0, stream);

    {
        long long n8 = (long long)Nn * 256 / 8;
        long long grid = (n8 + 255) / 256 + 256 + 128 + 1;
        prep_kernel<<<(int)grid, 256, 0, stream>>>(x, xb, n8, W1, Wt1, W2, Wt2,
                                                   (const unsigned int*)ei, flag,
                                                   (long long)2 * E_);
    }

    int eb = (E_ + 255) / 256;
    int nsb = (Nn + 255) / 256;  // <= 256
    count_deg_kernel<<<eb, 256, 0, stream>>>(ei, flag, deg, E_);
    scan_partial_kernel<<<nsb, 256, 0, stream>>>(deg, bsum, Nn);
    scan_write_kernel<<<nsb, 256, 0, stream>>>(deg, bsum, rowptr, ctr, Nn, nsb);
    scatter_kernel<<<eb, 256, 0, stream>>>(ei, flag, ctr, srcs, E_);

    const int agg_blocks = 2048;  // 8 blocks/CU co-resident; persistent grid-stride

    // layer 1
    gemm_mfma_kernel<256, 2, false><<<dim3(gb, 4), 256, 0, stream>>>(
        xb, Wt1, h1b, att_src1, att_dst1, as1, ad1, Nn, nullptr, nullptr, nullptr);
    aggregate1_kernel<<<agg_blocks, 256, 0, stream>>>(h1b, rowptr, srcs, as1, ad1, b1, x2b0,
                                                      bn1sh, Nn);

    // layer 2 (BN1-apply+ReLU fused into GEMM2's A reg-staging)
    gemm_mfma_kernel<128, 1, true><<<dim3(gb, 2), 256, 0, stream>>>(
        x2b0, Wt2, h2b, att_src2, att_dst2, as2, ad2, Nn, bn1sh, g1, be1);
    aggregate2_kernel<<<agg_blocks, 256, 0, stream>>>(h2b, rowptr, srcs, as2, ad2, b2, outf,
                                                      bn2sh, Nn);
    bn_apply_final_kernel<<<512, 256, 0, stream>>>(outf, bn2sh, g2, be2, Nn);
}